// Round 1
// baseline (568.666 us; speedup 1.0000x reference)
//
#include <hip/hip_runtime.h>
#include <hip/hip_bf16.h>
#include <cstdint>

// ---------------------------------------------------------------------------
// GCN 3-layer forward. fp32 baseline, CSR-by-dst SpMM (no float atomics).
// ---------------------------------------------------------------------------

#define F_IN 256
#define HDIM 128
#define CDIM 40

// ---- preprocessing ---------------------------------------------------------

__global__ __launch_bounds__(256)
void degree_kernel(const int* __restrict__ src, const int* __restrict__ dst,
                   int* __restrict__ outc, int* __restrict__ inc, int E) {
    int i = blockIdx.x * 256 + threadIdx.x;
    if (i < E) {
        atomicAdd(&outc[src[i]], 1);
        atomicAdd(&inc[dst[i]], 1);
    }
}

// single-block exclusive scan of cnt[0..n) -> row_ptr[0..n], row_ptr[n]=total
__global__ __launch_bounds__(1024)
void scan_kernel(const int* __restrict__ cnt, int* __restrict__ row_ptr, int n) {
    __shared__ int sm[1024];
    __shared__ int carry_s;
    const int t = threadIdx.x;
    if (t == 0) carry_s = 0;
    __syncthreads();
    for (int base = 0; base < n; base += 1024) {
        int x = (base + t < n) ? cnt[base + t] : 0;
        sm[t] = x;
        __syncthreads();
        #pragma unroll
        for (int off = 1; off < 1024; off <<= 1) {
            int v = (t >= off) ? sm[t - off] : 0;
            __syncthreads();
            sm[t] += v;
            __syncthreads();
        }
        if (base + t < n) row_ptr[base + t] = carry_s + sm[t] - x;  // exclusive
        __syncthreads();
        if (t == 0) carry_s += sm[1023];
        __syncthreads();
    }
    if (t == 0) row_ptr[n] = carry_s;
}

__global__ __launch_bounds__(256)
void node_prep_kernel(const int* __restrict__ outc, const int* __restrict__ inc,
                      const int* __restrict__ row_ptr,
                      float* __restrict__ out_norm, float* __restrict__ in_norm,
                      int* __restrict__ cursor, int n) {
    int i = blockIdx.x * 256 + threadIdx.x;
    if (i < n) {
        out_norm[i] = rsqrtf((float)max(outc[i], 1));
        in_norm[i]  = rsqrtf((float)max(inc[i], 1));
        cursor[i]   = row_ptr[i];
    }
}

// counting-sort edges by dst; fold ew*out_norm[src] into edge weight
__global__ __launch_bounds__(256)
void scatter_kernel(const int* __restrict__ src, const int* __restrict__ dst,
                    const float* __restrict__ ew, const float* __restrict__ out_norm,
                    int* __restrict__ cursor, int* __restrict__ col,
                    float* __restrict__ wval, int E) {
    int i = blockIdx.x * 256 + threadIdx.x;
    if (i < E) {
        int s = src[i], d = dst[i];
        int pos = atomicAdd(&cursor[d], 1);
        col[pos]  = s;
        wval[pos] = ew[i] * out_norm[s];
    }
}

// ---- fp32 tiled GEMM: C[M x Nn] = A[M x K] @ B[K x Nn] --------------------
// BM=128 BN=64 BK=16, 256 threads, 8x4 per thread.
// MODE 0: plain store.  MODE 1: relu(acc*rownorm[row] + bias[col]).

template <int MODE>
__global__ __launch_bounds__(256)
void gemm_f32(const float* __restrict__ A, const float* __restrict__ B,
              float* __restrict__ C, int M, int Nn, int K,
              int lda, int ldb, int ldc,
              const float* __restrict__ rownorm, const float* __restrict__ bias) {
    constexpr int BM = 128, BN = 64, BK = 16;
    __shared__ float As[BK][BM];   // k-major (transposed on stage-in)
    __shared__ float Bs[BK][BN];

    const int t = threadIdx.x;
    const int row0 = blockIdx.x * BM;
    const int col0 = blockIdx.y * BN;
    const int rowbase = (t >> 4) * 8;
    const int colbase = (t & 15) * 4;
    // A stage-in mapping: thread -> (row ar, k-quad akq)
    const int ar  = t >> 1;
    const int akq = (t & 1) * 8;
    // B stage-in mapping
    const int bk  = t >> 4;
    const int bc4 = (t & 15) * 4;

    float acc[8][4];
    #pragma unroll
    for (int i = 0; i < 8; ++i)
        #pragma unroll
        for (int j = 0; j < 4; ++j) acc[i][j] = 0.f;

    for (int k0 = 0; k0 < K; k0 += BK) {
        float4 a0 = make_float4(0.f, 0.f, 0.f, 0.f), a1 = a0;
        if (row0 + ar < M) {
            const float* ap = A + (size_t)(row0 + ar) * lda + k0 + akq;
            a0 = *reinterpret_cast<const float4*>(ap);
            a1 = *reinterpret_cast<const float4*>(ap + 4);
        }
        float4 bv = make_float4(0.f, 0.f, 0.f, 0.f);
        if (col0 + bc4 < Nn) {
            bv = *reinterpret_cast<const float4*>(B + (size_t)(k0 + bk) * ldb + col0 + bc4);
        }
        __syncthreads();   // previous iter done reading LDS
        As[akq + 0][ar] = a0.x; As[akq + 1][ar] = a0.y;
        As[akq + 2][ar] = a0.z; As[akq + 3][ar] = a0.w;
        As[akq + 4][ar] = a1.x; As[akq + 5][ar] = a1.y;
        As[akq + 6][ar] = a1.z; As[akq + 7][ar] = a1.w;
        *reinterpret_cast<float4*>(&Bs[bk][bc4]) = bv;
        __syncthreads();

        #pragma unroll
        for (int kk = 0; kk < BK; ++kk) {
            float4 av0 = *reinterpret_cast<const float4*>(&As[kk][rowbase]);
            float4 av1 = *reinterpret_cast<const float4*>(&As[kk][rowbase + 4]);
            float4 bv2 = *reinterpret_cast<const float4*>(&Bs[kk][colbase]);
            float a[8] = {av0.x, av0.y, av0.z, av0.w, av1.x, av1.y, av1.z, av1.w};
            float b[4] = {bv2.x, bv2.y, bv2.z, bv2.w};
            #pragma unroll
            for (int i = 0; i < 8; ++i)
                #pragma unroll
                for (int j = 0; j < 4; ++j)
                    acc[i][j] = fmaf(a[i], b[j], acc[i][j]);
        }
    }

    if (col0 + colbase >= Nn) return;
    float4 bb = make_float4(0.f, 0.f, 0.f, 0.f);
    if (MODE == 1) bb = *reinterpret_cast<const float4*>(bias + col0 + colbase);
    #pragma unroll
    for (int i = 0; i < 8; ++i) {
        int row = row0 + rowbase + i;
        if (row >= M) break;
        float4 v = make_float4(acc[i][0], acc[i][1], acc[i][2], acc[i][3]);
        if (MODE == 1) {
            float rn = rownorm[row];
            v.x = fmaxf(fmaf(v.x, rn, bb.x), 0.f);
            v.y = fmaxf(fmaf(v.y, rn, bb.y), 0.f);
            v.z = fmaxf(fmaf(v.z, rn, bb.z), 0.f);
            v.w = fmaxf(fmaf(v.w, rn, bb.w), 0.f);
        }
        *reinterpret_cast<float4*>(C + (size_t)row * ldc + col0 + colbase) = v;
    }
}

// ---- SpMM (CSR by dst), 128 features: one wave per node, float2 per lane ---
// EPI 0: raw store. EPI 1: relu(acc*in_norm[n] + bias[f]).

template <int EPI>
__global__ __launch_bounds__(256)
void spmm128(const float* __restrict__ H, const int* __restrict__ row_ptr,
             const int* __restrict__ col, const float* __restrict__ wv,
             float* __restrict__ out, const float* __restrict__ in_norm,
             const float* __restrict__ bias, int n) {
    int wid  = (blockIdx.x * 256 + threadIdx.x) >> 6;
    int lane = threadIdx.x & 63;
    if (wid >= n) return;
    int e0 = row_ptr[wid], e1 = row_ptr[wid + 1];
    float2 acc = make_float2(0.f, 0.f);
    for (int e = e0; e < e1; ++e) {
        int s   = col[e];
        float w = wv[e];
        float2 v = *reinterpret_cast<const float2*>(H + (size_t)s * 128 + lane * 2);
        acc.x = fmaf(w, v.x, acc.x);
        acc.y = fmaf(w, v.y, acc.y);
    }
    if (EPI == 1) {
        float nn = in_norm[wid];
        float2 bb = *reinterpret_cast<const float2*>(bias + lane * 2);
        acc.x = fmaxf(fmaf(acc.x, nn, bb.x), 0.f);
        acc.y = fmaxf(fmaf(acc.y, nn, bb.y), 0.f);
    }
    *reinterpret_cast<float2*>(out + (size_t)wid * 128 + lane * 2) = acc;
}

// ---- SpMM 40 features (final layer): one wave per node, lanes 0..39 -------

__global__ __launch_bounds__(256)
void spmm40(const float* __restrict__ H, const int* __restrict__ row_ptr,
            const int* __restrict__ col, const float* __restrict__ wv,
            float* __restrict__ out, const float* __restrict__ in_norm,
            const float* __restrict__ bias, int n) {
    int wid  = (blockIdx.x * 256 + threadIdx.x) >> 6;
    int lane = threadIdx.x & 63;
    if (wid >= n || lane >= CDIM) return;
    int e0 = row_ptr[wid], e1 = row_ptr[wid + 1];
    float acc = 0.f;
    for (int e = e0; e < e1; ++e) {
        int s   = col[e];
        float w = wv[e];
        acc = fmaf(w, H[(size_t)s * CDIM + lane], acc);
    }
    out[(size_t)wid * CDIM + lane] = fmaf(acc, in_norm[wid], bias[lane]);
}

// ---------------------------------------------------------------------------

extern "C" void kernel_launch(void* const* d_in, const int* in_sizes, int n_in,
                              void* d_out, int out_size, void* d_ws, size_t ws_size,
                              hipStream_t stream) {
    const float* features = (const float*)d_in[0];
    const int*   src      = (const int*)d_in[1];
    const int*   dst      = (const int*)d_in[2];
    const float* ew       = (const float*)d_in[3];
    const float* W1       = (const float*)d_in[4];
    const float* b1       = (const float*)d_in[5];
    const float* W2       = (const float*)d_in[6];
    const float* b2       = (const float*)d_in[7];
    const float* W3       = (const float*)d_in[8];
    const float* b3       = (const float*)d_in[9];
    float* out = (float*)d_out;

    const int N = in_sizes[0] / F_IN;   // 50000
    const int E = in_sizes[1];          // 800000

    // ---- workspace carve-up ----
    char* ws = (char*)d_ws;
    size_t off = 0;
    auto alloc = [&](size_t bytes) -> void* {
        void* p = ws + off;
        off += (bytes + 255) & ~(size_t)255;
        return p;
    };
    int*   deg      = (int*)alloc((size_t)2 * N * 4);   // outc | inc (contiguous)
    int*   outc     = deg;
    int*   inc      = deg + N;
    int*   row_ptr  = (int*)alloc((size_t)(N + 1) * 4);
    int*   cursor   = (int*)alloc((size_t)N * 4);
    float* out_norm = (float*)alloc((size_t)N * 4);
    float* in_norm  = (float*)alloc((size_t)N * 4);
    int*   col      = (int*)alloc((size_t)E * 4);
    float* wval     = (float*)alloc((size_t)E * 4);
    float* B0       = (float*)alloc((size_t)N * HDIM * 4);  // T1, later H2
    float* B1       = (float*)alloc((size_t)N * HDIM * 4);  // H1, later T3
    float* B2       = (float*)alloc((size_t)N * HDIM * 4);  // A2
    (void)ws_size;

    // ---- preprocessing (per call; deterministic) ----
    hipMemsetAsync(deg, 0, (size_t)2 * N * 4, stream);

    int egrid = (E + 255) / 256;
    degree_kernel<<<egrid, 256, 0, stream>>>(src, dst, outc, inc, E);
    scan_kernel<<<1, 1024, 0, stream>>>(inc, row_ptr, N);
    int ngrid = (N + 255) / 256;
    node_prep_kernel<<<ngrid, 256, 0, stream>>>(outc, inc, row_ptr, out_norm, in_norm, cursor, N);
    scatter_kernel<<<egrid, 256, 0, stream>>>(src, dst, ew, out_norm, cursor, col, wval, E);

    const int spmm_grid = (N + 3) / 4;   // one wave per node, 4 waves/block

    // ---- layer 1: T1 = X @ W1 ; H1 = relu(SpMM(T1)*in_norm + b1) ----
    {
        dim3 grid((N + 127) / 128, (HDIM + 63) / 64);
        gemm_f32<0><<<grid, 256, 0, stream>>>(features, W1, B0, N, HDIM, F_IN,
                                              F_IN, HDIM, HDIM, nullptr, nullptr);
    }
    spmm128<1><<<spmm_grid, 256, 0, stream>>>(B0, row_ptr, col, wval, B1, in_norm, b1, N);

    // ---- layer 2: A2 = SpMM(H1) ; H2 = relu((A2 @ W2)*in_norm + b2) ----
    spmm128<0><<<spmm_grid, 256, 0, stream>>>(B1, row_ptr, col, wval, B2, nullptr, nullptr, N);
    {
        dim3 grid((N + 127) / 128, (HDIM + 63) / 64);
        gemm_f32<1><<<grid, 256, 0, stream>>>(B2, W2, B0, N, HDIM, HDIM,
                                              HDIM, HDIM, HDIM, in_norm, b2);
    }

    // ---- layer 3: T3 = H2 @ W3 ; OUT = SpMM(T3)*in_norm + b3 ----
    {
        dim3 grid((N + 127) / 128, (CDIM + 63) / 64);
        gemm_f32<0><<<grid, 256, 0, stream>>>(B0, W3, B1, N, CDIM, HDIM,
                                              HDIM, CDIM, CDIM, nullptr, nullptr);
    }
    spmm40<<<spmm_grid, 256, 0, stream>>>(B1, row_ptr, col, wval, out, in_norm, b3, N);
}

// Round 2
// 483.539 us; speedup vs baseline: 1.1760x; 1.1760x over previous
//
#include <hip/hip_runtime.h>
#include <hip/hip_bf16.h>
#include <cstdint>

// ---------------------------------------------------------------------------
// GCN 3-layer forward. fp32, CSR-by-dst SpMM (no float atomics).
// Round 2: multi-block scan (was 90us single-block -> ~4us).
// ---------------------------------------------------------------------------

#define F_IN 256
#define HDIM 128
#define CDIM 40

// ---- preprocessing ---------------------------------------------------------

__global__ __launch_bounds__(256)
void degree_kernel(const int* __restrict__ src, const int* __restrict__ dst,
                   int* __restrict__ outc, int* __restrict__ inc, int E) {
    int i = blockIdx.x * 256 + threadIdx.x;
    if (i < E) {
        atomicAdd(&outc[src[i]], 1);
        atomicAdd(&inc[dst[i]], 1);
    }
}

// stage 1: per-block (1024 elems) exclusive scan + block sums
__global__ __launch_bounds__(256)
void scan_blocks(const int* __restrict__ cnt, int* __restrict__ out,
                 int* __restrict__ bsums, int n) {
    const int t = threadIdx.x;
    const int idx = blockIdx.x * 1024 + t * 4;
    int4 v = make_int4(0, 0, 0, 0);
    if (idx + 3 < n) {
        v = *reinterpret_cast<const int4*>(cnt + idx);
    } else {
        if (idx     < n) v.x = cnt[idx];
        if (idx + 1 < n) v.y = cnt[idx + 1];
        if (idx + 2 < n) v.z = cnt[idx + 2];
        if (idx + 3 < n) v.w = cnt[idx + 3];
    }
    const int s = v.x + v.y + v.z + v.w;
    const int lane = t & 63;
    int incl = s;
    #pragma unroll
    for (int off = 1; off < 64; off <<= 1) {
        int u = __shfl_up(incl, off);
        if (lane >= off) incl += u;
    }
    __shared__ int wsum[4];
    if (lane == 63) wsum[t >> 6] = incl;
    __syncthreads();
    const int w = t >> 6;
    int woff = 0;
    if (w > 0) woff += wsum[0];
    if (w > 1) woff += wsum[1];
    if (w > 2) woff += wsum[2];
    const int excl = woff + incl - s;
    if (idx + 3 < n) {
        *reinterpret_cast<int4*>(out + idx) =
            make_int4(excl, excl + v.x, excl + v.x + v.y, excl + v.x + v.y + v.z);
    } else {
        if (idx     < n) out[idx]     = excl;
        if (idx + 1 < n) out[idx + 1] = excl + v.x;
        if (idx + 2 < n) out[idx + 2] = excl + v.x + v.y;
        if (idx + 3 < n) out[idx + 3] = excl + v.x + v.y + v.z;
    }
    if (t == 255) bsums[blockIdx.x] = woff + incl;
}

// stage 2: one wave scans the block sums (exclusive, in place)
__global__ __launch_bounds__(64)
void scan_sums(int* __restrict__ bsums, int nb) {
    const int lane = threadIdx.x & 63;
    int carry = 0;
    for (int base = 0; base < nb; base += 64) {
        int v = (base + lane < nb) ? bsums[base + lane] : 0;
        int incl = v;
        #pragma unroll
        for (int off = 1; off < 64; off <<= 1) {
            int u = __shfl_up(incl, off);
            if (lane >= off) incl += u;
        }
        if (base + lane < nb) bsums[base + lane] = carry + incl - v;
        carry += __shfl(incl, 63);
    }
}

// stage 3 folded in: finalize row_ptr (+block offset), norms, cursor
__global__ __launch_bounds__(256)
void node_prep_kernel(const int* __restrict__ outc, const int* __restrict__ inc,
                      int* __restrict__ row_ptr, const int* __restrict__ bsums,
                      float* __restrict__ out_norm, float* __restrict__ in_norm,
                      int* __restrict__ cursor, int n, int E) {
    int i = blockIdx.x * 256 + threadIdx.x;
    if (i < n) {
        int rp = row_ptr[i] + bsums[i >> 10];
        row_ptr[i] = rp;
        cursor[i]  = rp;
        out_norm[i] = rsqrtf((float)max(outc[i], 1));
        in_norm[i]  = rsqrtf((float)max(inc[i], 1));
    }
    if (i == 0) row_ptr[n] = E;   // in-degrees sum to E
}

// counting-sort edges by dst; fold ew*out_norm[src] into edge weight
__global__ __launch_bounds__(256)
void scatter_kernel(const int* __restrict__ src, const int* __restrict__ dst,
                    const float* __restrict__ ew, const float* __restrict__ out_norm,
                    int* __restrict__ cursor, int* __restrict__ col,
                    float* __restrict__ wval, int E) {
    int i = blockIdx.x * 256 + threadIdx.x;
    if (i < E) {
        int s = src[i], d = dst[i];
        int pos = atomicAdd(&cursor[d], 1);
        col[pos]  = s;
        wval[pos] = ew[i] * out_norm[s];
    }
}

// ---- fp32 tiled GEMM: C[M x Nn] = A[M x K] @ B[K x Nn] --------------------
// BM=128 BN=64 BK=16, 256 threads, 8x4 per thread.
// MODE 0: plain store.  MODE 1: relu(acc*rownorm[row] + bias[col]).

template <int MODE>
__global__ __launch_bounds__(256)
void gemm_f32(const float* __restrict__ A, const float* __restrict__ B,
              float* __restrict__ C, int M, int Nn, int K,
              int lda, int ldb, int ldc,
              const float* __restrict__ rownorm, const float* __restrict__ bias) {
    constexpr int BM = 128, BN = 64, BK = 16;
    __shared__ float As[BK][BM];   // k-major (transposed on stage-in)
    __shared__ float Bs[BK][BN];

    const int t = threadIdx.x;
    const int row0 = blockIdx.x * BM;
    const int col0 = blockIdx.y * BN;
    const int rowbase = (t >> 4) * 8;
    const int colbase = (t & 15) * 4;
    const int ar  = t >> 1;
    const int akq = (t & 1) * 8;
    const int bk  = t >> 4;
    const int bc4 = (t & 15) * 4;

    float acc[8][4];
    #pragma unroll
    for (int i = 0; i < 8; ++i)
        #pragma unroll
        for (int j = 0; j < 4; ++j) acc[i][j] = 0.f;

    for (int k0 = 0; k0 < K; k0 += BK) {
        float4 a0 = make_float4(0.f, 0.f, 0.f, 0.f), a1 = a0;
        if (row0 + ar < M) {
            const float* ap = A + (size_t)(row0 + ar) * lda + k0 + akq;
            a0 = *reinterpret_cast<const float4*>(ap);
            a1 = *reinterpret_cast<const float4*>(ap + 4);
        }
        float4 bv = make_float4(0.f, 0.f, 0.f, 0.f);
        if (col0 + bc4 < Nn) {
            bv = *reinterpret_cast<const float4*>(B + (size_t)(k0 + bk) * ldb + col0 + bc4);
        }
        __syncthreads();   // previous iter done reading LDS
        As[akq + 0][ar] = a0.x; As[akq + 1][ar] = a0.y;
        As[akq + 2][ar] = a0.z; As[akq + 3][ar] = a0.w;
        As[akq + 4][ar] = a1.x; As[akq + 5][ar] = a1.y;
        As[akq + 6][ar] = a1.z; As[akq + 7][ar] = a1.w;
        *reinterpret_cast<float4*>(&Bs[bk][bc4]) = bv;
        __syncthreads();

        #pragma unroll
        for (int kk = 0; kk < BK; ++kk) {
            float4 av0 = *reinterpret_cast<const float4*>(&As[kk][rowbase]);
            float4 av1 = *reinterpret_cast<const float4*>(&As[kk][rowbase + 4]);
            float4 bv2 = *reinterpret_cast<const float4*>(&Bs[kk][colbase]);
            float a[8] = {av0.x, av0.y, av0.z, av0.w, av1.x, av1.y, av1.z, av1.w};
            float b[4] = {bv2.x, bv2.y, bv2.z, bv2.w};
            #pragma unroll
            for (int i = 0; i < 8; ++i)
                #pragma unroll
                for (int j = 0; j < 4; ++j)
                    acc[i][j] = fmaf(a[i], b[j], acc[i][j]);
        }
    }

    if (col0 + colbase >= Nn) return;
    float4 bb = make_float4(0.f, 0.f, 0.f, 0.f);
    if (MODE == 1) bb = *reinterpret_cast<const float4*>(bias + col0 + colbase);
    #pragma unroll
    for (int i = 0; i < 8; ++i) {
        int row = row0 + rowbase + i;
        if (row >= M) break;
        float4 v = make_float4(acc[i][0], acc[i][1], acc[i][2], acc[i][3]);
        if (MODE == 1) {
            float rn = rownorm[row];
            v.x = fmaxf(fmaf(v.x, rn, bb.x), 0.f);
            v.y = fmaxf(fmaf(v.y, rn, bb.y), 0.f);
            v.z = fmaxf(fmaf(v.z, rn, bb.z), 0.f);
            v.w = fmaxf(fmaf(v.w, rn, bb.w), 0.f);
        }
        *reinterpret_cast<float4*>(C + (size_t)row * ldc + col0 + colbase) = v;
    }
}

// ---- SpMM (CSR by dst), 128 features: one wave per node, float2 per lane ---

template <int EPI>
__global__ __launch_bounds__(256)
void spmm128(const float* __restrict__ H, const int* __restrict__ row_ptr,
             const int* __restrict__ col, const float* __restrict__ wv,
             float* __restrict__ out, const float* __restrict__ in_norm,
             const float* __restrict__ bias, int n) {
    int wid  = (blockIdx.x * 256 + threadIdx.x) >> 6;
    int lane = threadIdx.x & 63;
    if (wid >= n) return;
    int e0 = row_ptr[wid], e1 = row_ptr[wid + 1];
    float2 acc = make_float2(0.f, 0.f);
    for (int e = e0; e < e1; ++e) {
        int s   = col[e];
        float w = wv[e];
        float2 v = *reinterpret_cast<const float2*>(H + (size_t)s * 128 + lane * 2);
        acc.x = fmaf(w, v.x, acc.x);
        acc.y = fmaf(w, v.y, acc.y);
    }
    if (EPI == 1) {
        float nn = in_norm[wid];
        float2 bb = *reinterpret_cast<const float2*>(bias + lane * 2);
        acc.x = fmaxf(fmaf(acc.x, nn, bb.x), 0.f);
        acc.y = fmaxf(fmaf(acc.y, nn, bb.y), 0.f);
    }
    *reinterpret_cast<float2*>(out + (size_t)wid * 128 + lane * 2) = acc;
}

// ---- SpMM 40 features (final layer) ---------------------------------------

__global__ __launch_bounds__(256)
void spmm40(const float* __restrict__ H, const int* __restrict__ row_ptr,
            const int* __restrict__ col, const float* __restrict__ wv,
            float* __restrict__ out, const float* __restrict__ in_norm,
            const float* __restrict__ bias, int n) {
    int wid  = (blockIdx.x * 256 + threadIdx.x) >> 6;
    int lane = threadIdx.x & 63;
    if (wid >= n || lane >= CDIM) return;
    int e0 = row_ptr[wid], e1 = row_ptr[wid + 1];
    float acc = 0.f;
    for (int e = e0; e < e1; ++e) {
        int s   = col[e];
        float w = wv[e];
        acc = fmaf(w, H[(size_t)s * CDIM + lane], acc);
    }
    out[(size_t)wid * CDIM + lane] = fmaf(acc, in_norm[wid], bias[lane]);
}

// ---------------------------------------------------------------------------

extern "C" void kernel_launch(void* const* d_in, const int* in_sizes, int n_in,
                              void* d_out, int out_size, void* d_ws, size_t ws_size,
                              hipStream_t stream) {
    const float* features = (const float*)d_in[0];
    const int*   src      = (const int*)d_in[1];
    const int*   dst      = (const int*)d_in[2];
    const float* ew       = (const float*)d_in[3];
    const float* W1       = (const float*)d_in[4];
    const float* b1       = (const float*)d_in[5];
    const float* W2       = (const float*)d_in[6];
    const float* b2       = (const float*)d_in[7];
    const float* W3       = (const float*)d_in[8];
    const float* b3       = (const float*)d_in[9];
    float* out = (float*)d_out;

    const int N = in_sizes[0] / F_IN;   // 50000
    const int E = in_sizes[1];          // 800000

    // ---- workspace carve-up ----
    char* ws = (char*)d_ws;
    size_t off = 0;
    auto alloc = [&](size_t bytes) -> void* {
        void* p = ws + off;
        off += (bytes + 255) & ~(size_t)255;
        return p;
    };
    int*   deg      = (int*)alloc((size_t)2 * N * 4);   // outc | inc (contiguous)
    int*   outc     = deg;
    int*   inc      = deg + N;
    int*   row_ptr  = (int*)alloc((size_t)(N + 1) * 4);
    int*   cursor   = (int*)alloc((size_t)N * 4);
    float* out_norm = (float*)alloc((size_t)N * 4);
    float* in_norm  = (float*)alloc((size_t)N * 4);
    int*   col      = (int*)alloc((size_t)E * 4);
    float* wval     = (float*)alloc((size_t)E * 4);
    float* B0       = (float*)alloc((size_t)N * HDIM * 4);  // T1, later H2
    float* B1       = (float*)alloc((size_t)N * HDIM * 4);  // H1, later T3
    float* B2       = (float*)alloc((size_t)N * HDIM * 4);  // A2
    const int nb    = (N + 1023) / 1024;
    int*   bsums    = (int*)alloc((size_t)nb * 4);
    (void)ws_size;

    // ---- preprocessing ----
    hipMemsetAsync(deg, 0, (size_t)2 * N * 4, stream);

    int egrid = (E + 255) / 256;
    degree_kernel<<<egrid, 256, 0, stream>>>(src, dst, outc, inc, E);
    scan_blocks<<<nb, 256, 0, stream>>>(inc, row_ptr, bsums, N);
    scan_sums<<<1, 64, 0, stream>>>(bsums, nb);
    int ngrid = (N + 255) / 256;
    node_prep_kernel<<<ngrid, 256, 0, stream>>>(outc, inc, row_ptr, bsums,
                                                out_norm, in_norm, cursor, N, E);
    scatter_kernel<<<egrid, 256, 0, stream>>>(src, dst, ew, out_norm, cursor, col, wval, E);

    const int spmm_grid = (N + 3) / 4;   // one wave per node, 4 waves/block

    // ---- layer 1: T1 = X @ W1 ; H1 = relu(SpMM(T1)*in_norm + b1) ----
    {
        dim3 grid((N + 127) / 128, (HDIM + 63) / 64);
        gemm_f32<0><<<grid, 256, 0, stream>>>(features, W1, B0, N, HDIM, F_IN,
                                              F_IN, HDIM, HDIM, nullptr, nullptr);
    }
    spmm128<1><<<spmm_grid, 256, 0, stream>>>(B0, row_ptr, col, wval, B1, in_norm, b1, N);

    // ---- layer 2: A2 = SpMM(H1) ; H2 = relu((A2 @ W2)*in_norm + b2) ----
    spmm128<0><<<spmm_grid, 256, 0, stream>>>(B1, row_ptr, col, wval, B2, nullptr, nullptr, N);
    {
        dim3 grid((N + 127) / 128, (HDIM + 63) / 64);
        gemm_f32<1><<<grid, 256, 0, stream>>>(B2, W2, B0, N, HDIM, HDIM,
                                              HDIM, HDIM, HDIM, in_norm, b2);
    }

    // ---- layer 3: T3 = H2 @ W3 ; OUT = SpMM(T3)*in_norm + b3 ----
    {
        dim3 grid((N + 127) / 128, (CDIM + 63) / 64);
        gemm_f32<0><<<grid, 256, 0, stream>>>(B0, W3, B1, N, CDIM, HDIM,
                                              HDIM, CDIM, CDIM, nullptr, nullptr);
    }
    spmm40<<<spmm_grid, 256, 0, stream>>>(B1, row_ptr, col, wval, out, in_norm, b3, N);
}

// Round 3
// 433.592 us; speedup vs baseline: 1.3115x; 1.1152x over previous
//
#include <hip/hip_runtime.h>
#include <hip/hip_bf16.h>
#include <cstdint>

// ---------------------------------------------------------------------------
// GCN 3-layer forward. fp32, CSR-by-dst SpMM (no float atomics).
// Round 3: SpMM float4 + 2-edge/wave MLP; 128x128 8x8 GEMM for layers 1-2.
// ---------------------------------------------------------------------------

#define F_IN 256
#define HDIM 128
#define CDIM 40

// ---- preprocessing ---------------------------------------------------------

__global__ __launch_bounds__(256)
void degree_kernel(const int* __restrict__ src, const int* __restrict__ dst,
                   int* __restrict__ outc, int* __restrict__ inc, int E) {
    int i = blockIdx.x * 256 + threadIdx.x;
    if (i < E) {
        atomicAdd(&outc[src[i]], 1);
        atomicAdd(&inc[dst[i]], 1);
    }
}

// stage 1: per-block (1024 elems) exclusive scan + block sums
__global__ __launch_bounds__(256)
void scan_blocks(const int* __restrict__ cnt, int* __restrict__ out,
                 int* __restrict__ bsums, int n) {
    const int t = threadIdx.x;
    const int idx = blockIdx.x * 1024 + t * 4;
    int4 v = make_int4(0, 0, 0, 0);
    if (idx + 3 < n) {
        v = *reinterpret_cast<const int4*>(cnt + idx);
    } else {
        if (idx     < n) v.x = cnt[idx];
        if (idx + 1 < n) v.y = cnt[idx + 1];
        if (idx + 2 < n) v.z = cnt[idx + 2];
        if (idx + 3 < n) v.w = cnt[idx + 3];
    }
    const int s = v.x + v.y + v.z + v.w;
    const int lane = t & 63;
    int incl = s;
    #pragma unroll
    for (int off = 1; off < 64; off <<= 1) {
        int u = __shfl_up(incl, off);
        if (lane >= off) incl += u;
    }
    __shared__ int wsum[4];
    if (lane == 63) wsum[t >> 6] = incl;
    __syncthreads();
    const int w = t >> 6;
    int woff = 0;
    if (w > 0) woff += wsum[0];
    if (w > 1) woff += wsum[1];
    if (w > 2) woff += wsum[2];
    const int excl = woff + incl - s;
    if (idx + 3 < n) {
        *reinterpret_cast<int4*>(out + idx) =
            make_int4(excl, excl + v.x, excl + v.x + v.y, excl + v.x + v.y + v.z);
    } else {
        if (idx     < n) out[idx]     = excl;
        if (idx + 1 < n) out[idx + 1] = excl + v.x;
        if (idx + 2 < n) out[idx + 2] = excl + v.x + v.y;
        if (idx + 3 < n) out[idx + 3] = excl + v.x + v.y + v.z;
    }
    if (t == 255) bsums[blockIdx.x] = woff + incl;
}

// stage 2: one wave scans the block sums (exclusive, in place)
__global__ __launch_bounds__(64)
void scan_sums(int* __restrict__ bsums, int nb) {
    const int lane = threadIdx.x & 63;
    int carry = 0;
    for (int base = 0; base < nb; base += 64) {
        int v = (base + lane < nb) ? bsums[base + lane] : 0;
        int incl = v;
        #pragma unroll
        for (int off = 1; off < 64; off <<= 1) {
            int u = __shfl_up(incl, off);
            if (lane >= off) incl += u;
        }
        if (base + lane < nb) bsums[base + lane] = carry + incl - v;
        carry += __shfl(incl, 63);
    }
}

// stage 3 folded in: finalize row_ptr (+block offset), norms, cursor
__global__ __launch_bounds__(256)
void node_prep_kernel(const int* __restrict__ outc, const int* __restrict__ inc,
                      int* __restrict__ row_ptr, const int* __restrict__ bsums,
                      float* __restrict__ out_norm, float* __restrict__ in_norm,
                      int* __restrict__ cursor, int n, int E) {
    int i = blockIdx.x * 256 + threadIdx.x;
    if (i < n) {
        int rp = row_ptr[i] + bsums[i >> 10];
        row_ptr[i] = rp;
        cursor[i]  = rp;
        out_norm[i] = rsqrtf((float)max(outc[i], 1));
        in_norm[i]  = rsqrtf((float)max(inc[i], 1));
    }
    if (i == 0) row_ptr[n] = E;   // in-degrees sum to E
}

// counting-sort edges by dst; fold ew*out_norm[src] into edge weight
__global__ __launch_bounds__(256)
void scatter_kernel(const int* __restrict__ src, const int* __restrict__ dst,
                    const float* __restrict__ ew, const float* __restrict__ out_norm,
                    int* __restrict__ cursor, int* __restrict__ col,
                    float* __restrict__ wval, int E) {
    int i = blockIdx.x * 256 + threadIdx.x;
    if (i < E) {
        int s = src[i], d = dst[i];
        int pos = atomicAdd(&cursor[d], 1);
        col[pos]  = s;
        wval[pos] = ew[i] * out_norm[s];
    }
}

// ---- fp32 GEMM, Nn == 128 exactly: C[M x 128] = A[M x K] @ B[K x 128] -----
// BM=128 BN=128 BK=16, 256 threads, 8x8 per thread.
// MODE 0: plain store.  MODE 1: relu(acc*rownorm[row] + bias[col]).

template <int MODE>
__global__ __launch_bounds__(256)
void gemm128_f32(const float* __restrict__ A, const float* __restrict__ B,
                 float* __restrict__ C, int M, int K,
                 const float* __restrict__ rownorm, const float* __restrict__ bias) {
    constexpr int BM = 128, BK = 16;
    __shared__ float As[BK][BM];   // k-major (transposed on stage-in)
    __shared__ float Bs[BK][128];

    const int t = threadIdx.x;
    const int row0 = blockIdx.x * BM;
    const int rowbase = (t >> 4) * 8;
    const int colbase = (t & 15) * 8;
    const int ar  = t >> 1;          // A stage-in: row in tile
    const int akq = (t & 1) * 8;     // A stage-in: k offset (8 floats)
    const int bk  = t >> 4;          // B stage-in: k row
    const int bc8 = (t & 15) * 8;    // B stage-in: col offset (8 floats)

    float acc[8][8];
    #pragma unroll
    for (int i = 0; i < 8; ++i)
        #pragma unroll
        for (int j = 0; j < 8; ++j) acc[i][j] = 0.f;

    for (int k0 = 0; k0 < K; k0 += BK) {
        float4 a0 = make_float4(0.f, 0.f, 0.f, 0.f), a1 = a0;
        if (row0 + ar < M) {
            const float* ap = A + (size_t)(row0 + ar) * K + k0 + akq;
            a0 = *reinterpret_cast<const float4*>(ap);
            a1 = *reinterpret_cast<const float4*>(ap + 4);
        }
        const float* bp = B + (size_t)(k0 + bk) * 128 + bc8;
        float4 b0 = *reinterpret_cast<const float4*>(bp);
        float4 b1 = *reinterpret_cast<const float4*>(bp + 4);
        __syncthreads();   // previous iter done reading LDS
        As[akq + 0][ar] = a0.x; As[akq + 1][ar] = a0.y;
        As[akq + 2][ar] = a0.z; As[akq + 3][ar] = a0.w;
        As[akq + 4][ar] = a1.x; As[akq + 5][ar] = a1.y;
        As[akq + 6][ar] = a1.z; As[akq + 7][ar] = a1.w;
        *reinterpret_cast<float4*>(&Bs[bk][bc8])     = b0;
        *reinterpret_cast<float4*>(&Bs[bk][bc8 + 4]) = b1;
        __syncthreads();

        #pragma unroll
        for (int kk = 0; kk < BK; ++kk) {
            float4 av0 = *reinterpret_cast<const float4*>(&As[kk][rowbase]);
            float4 av1 = *reinterpret_cast<const float4*>(&As[kk][rowbase + 4]);
            float4 bv0 = *reinterpret_cast<const float4*>(&Bs[kk][colbase]);
            float4 bv1 = *reinterpret_cast<const float4*>(&Bs[kk][colbase + 4]);
            float a[8] = {av0.x, av0.y, av0.z, av0.w, av1.x, av1.y, av1.z, av1.w};
            float b[8] = {bv0.x, bv0.y, bv0.z, bv0.w, bv1.x, bv1.y, bv1.z, bv1.w};
            #pragma unroll
            for (int i = 0; i < 8; ++i)
                #pragma unroll
                for (int j = 0; j < 8; ++j)
                    acc[i][j] = fmaf(a[i], b[j], acc[i][j]);
        }
    }

    float bb[8];
    if (MODE == 1) {
        float4 b0 = *reinterpret_cast<const float4*>(bias + colbase);
        float4 b1 = *reinterpret_cast<const float4*>(bias + colbase + 4);
        bb[0] = b0.x; bb[1] = b0.y; bb[2] = b0.z; bb[3] = b0.w;
        bb[4] = b1.x; bb[5] = b1.y; bb[6] = b1.z; bb[7] = b1.w;
    }
    #pragma unroll
    for (int i = 0; i < 8; ++i) {
        int row = row0 + rowbase + i;
        if (row >= M) break;
        float v[8];
        #pragma unroll
        for (int j = 0; j < 8; ++j) v[j] = acc[i][j];
        if (MODE == 1) {
            float rn = rownorm[row];
            #pragma unroll
            for (int j = 0; j < 8; ++j) v[j] = fmaxf(fmaf(v[j], rn, bb[j]), 0.f);
        }
        float* cp = C + (size_t)row * 128 + colbase;
        *reinterpret_cast<float4*>(cp)     = make_float4(v[0], v[1], v[2], v[3]);
        *reinterpret_cast<float4*>(cp + 4) = make_float4(v[4], v[5], v[6], v[7]);
    }
}

// ---- fp32 tiled GEMM (generic Nn, used for layer 3): BM=128 BN=64 BK=16 ---

template <int MODE>
__global__ __launch_bounds__(256)
void gemm_f32(const float* __restrict__ A, const float* __restrict__ B,
              float* __restrict__ C, int M, int Nn, int K,
              int lda, int ldb, int ldc,
              const float* __restrict__ rownorm, const float* __restrict__ bias) {
    constexpr int BM = 128, BN = 64, BK = 16;
    __shared__ float As[BK][BM];
    __shared__ float Bs[BK][BN];

    const int t = threadIdx.x;
    const int row0 = blockIdx.x * BM;
    const int col0 = blockIdx.y * BN;
    const int rowbase = (t >> 4) * 8;
    const int colbase = (t & 15) * 4;
    const int ar  = t >> 1;
    const int akq = (t & 1) * 8;
    const int bk  = t >> 4;
    const int bc4 = (t & 15) * 4;

    float acc[8][4];
    #pragma unroll
    for (int i = 0; i < 8; ++i)
        #pragma unroll
        for (int j = 0; j < 4; ++j) acc[i][j] = 0.f;

    for (int k0 = 0; k0 < K; k0 += BK) {
        float4 a0 = make_float4(0.f, 0.f, 0.f, 0.f), a1 = a0;
        if (row0 + ar < M) {
            const float* ap = A + (size_t)(row0 + ar) * lda + k0 + akq;
            a0 = *reinterpret_cast<const float4*>(ap);
            a1 = *reinterpret_cast<const float4*>(ap + 4);
        }
        float4 bv = make_float4(0.f, 0.f, 0.f, 0.f);
        if (col0 + bc4 < Nn) {
            bv = *reinterpret_cast<const float4*>(B + (size_t)(k0 + bk) * ldb + col0 + bc4);
        }
        __syncthreads();
        As[akq + 0][ar] = a0.x; As[akq + 1][ar] = a0.y;
        As[akq + 2][ar] = a0.z; As[akq + 3][ar] = a0.w;
        As[akq + 4][ar] = a1.x; As[akq + 5][ar] = a1.y;
        As[akq + 6][ar] = a1.z; As[akq + 7][ar] = a1.w;
        *reinterpret_cast<float4*>(&Bs[bk][bc4]) = bv;
        __syncthreads();

        #pragma unroll
        for (int kk = 0; kk < BK; ++kk) {
            float4 av0 = *reinterpret_cast<const float4*>(&As[kk][rowbase]);
            float4 av1 = *reinterpret_cast<const float4*>(&As[kk][rowbase + 4]);
            float4 bv2 = *reinterpret_cast<const float4*>(&Bs[kk][colbase]);
            float a[8] = {av0.x, av0.y, av0.z, av0.w, av1.x, av1.y, av1.z, av1.w};
            float b[4] = {bv2.x, bv2.y, bv2.z, bv2.w};
            #pragma unroll
            for (int i = 0; i < 8; ++i)
                #pragma unroll
                for (int j = 0; j < 4; ++j)
                    acc[i][j] = fmaf(a[i], b[j], acc[i][j]);
        }
    }

    if (col0 + colbase >= Nn) return;
    float4 bb = make_float4(0.f, 0.f, 0.f, 0.f);
    if (MODE == 1) bb = *reinterpret_cast<const float4*>(bias + col0 + colbase);
    #pragma unroll
    for (int i = 0; i < 8; ++i) {
        int row = row0 + rowbase + i;
        if (row >= M) break;
        float4 v = make_float4(acc[i][0], acc[i][1], acc[i][2], acc[i][3]);
        if (MODE == 1) {
            float rn = rownorm[row];
            v.x = fmaxf(fmaf(v.x, rn, bb.x), 0.f);
            v.y = fmaxf(fmaf(v.y, rn, bb.y), 0.f);
            v.z = fmaxf(fmaf(v.z, rn, bb.z), 0.f);
            v.w = fmaxf(fmaf(v.w, rn, bb.w), 0.f);
        }
        *reinterpret_cast<float4*>(C + (size_t)row * ldc + col0 + colbase) = v;
    }
}

// ---- SpMM (CSR by dst), 128 features ---------------------------------------
// One wave per node; two 32-lane halves process alternate edges (2 gather
// streams in flight), float4 per lane (16B), __shfl_xor combine at the end.

template <int EPI>
__global__ __launch_bounds__(256)
void spmm128(const float* __restrict__ H, const int* __restrict__ row_ptr,
             const int* __restrict__ col, const float* __restrict__ wv,
             float* __restrict__ out, const float* __restrict__ in_norm,
             const float* __restrict__ bias, int n) {
    int wid  = (blockIdx.x * 256 + threadIdx.x) >> 6;
    int lane = threadIdx.x & 63;
    if (wid >= n) return;
    const int half = lane >> 5;
    const int q    = lane & 31;
    int e0 = row_ptr[wid], e1 = row_ptr[wid + 1];
    float4 acc = make_float4(0.f, 0.f, 0.f, 0.f);
    for (int e = e0 + half; e < e1; e += 2) {
        int s   = col[e];
        float w = wv[e];
        float4 v = *reinterpret_cast<const float4*>(H + (size_t)s * 128 + q * 4);
        acc.x = fmaf(w, v.x, acc.x);
        acc.y = fmaf(w, v.y, acc.y);
        acc.z = fmaf(w, v.z, acc.z);
        acc.w = fmaf(w, v.w, acc.w);
    }
    acc.x += __shfl_xor(acc.x, 32);
    acc.y += __shfl_xor(acc.y, 32);
    acc.z += __shfl_xor(acc.z, 32);
    acc.w += __shfl_xor(acc.w, 32);
    if (half == 0) {
        if (EPI == 1) {
            float nn = in_norm[wid];
            float4 bb = *reinterpret_cast<const float4*>(bias + q * 4);
            acc.x = fmaxf(fmaf(acc.x, nn, bb.x), 0.f);
            acc.y = fmaxf(fmaf(acc.y, nn, bb.y), 0.f);
            acc.z = fmaxf(fmaf(acc.z, nn, bb.z), 0.f);
            acc.w = fmaxf(fmaf(acc.w, nn, bb.w), 0.f);
        }
        *reinterpret_cast<float4*>(out + (size_t)wid * 128 + q * 4) = acc;
    }
}

// ---- SpMM 40 features (final layer) ---------------------------------------

__global__ __launch_bounds__(256)
void spmm40(const float* __restrict__ H, const int* __restrict__ row_ptr,
            const int* __restrict__ col, const float* __restrict__ wv,
            float* __restrict__ out, const float* __restrict__ in_norm,
            const float* __restrict__ bias, int n) {
    int wid  = (blockIdx.x * 256 + threadIdx.x) >> 6;
    int lane = threadIdx.x & 63;
    if (wid >= n || lane >= CDIM) return;
    int e0 = row_ptr[wid], e1 = row_ptr[wid + 1];
    float acc = 0.f;
    for (int e = e0; e < e1; ++e) {
        int s   = col[e];
        float w = wv[e];
        acc = fmaf(w, H[(size_t)s * CDIM + lane], acc);
    }
    out[(size_t)wid * CDIM + lane] = fmaf(acc, in_norm[wid], bias[lane]);
}

// ---------------------------------------------------------------------------

extern "C" void kernel_launch(void* const* d_in, const int* in_sizes, int n_in,
                              void* d_out, int out_size, void* d_ws, size_t ws_size,
                              hipStream_t stream) {
    const float* features = (const float*)d_in[0];
    const int*   src      = (const int*)d_in[1];
    const int*   dst      = (const int*)d_in[2];
    const float* ew       = (const float*)d_in[3];
    const float* W1       = (const float*)d_in[4];
    const float* b1       = (const float*)d_in[5];
    const float* W2       = (const float*)d_in[6];
    const float* b2       = (const float*)d_in[7];
    const float* W3       = (const float*)d_in[8];
    const float* b3       = (const float*)d_in[9];
    float* out = (float*)d_out;

    const int N = in_sizes[0] / F_IN;   // 50000
    const int E = in_sizes[1];          // 800000

    // ---- workspace carve-up ----
    char* ws = (char*)d_ws;
    size_t off = 0;
    auto alloc = [&](size_t bytes) -> void* {
        void* p = ws + off;
        off += (bytes + 255) & ~(size_t)255;
        return p;
    };
    int*   deg      = (int*)alloc((size_t)2 * N * 4);   // outc | inc (contiguous)
    int*   outc     = deg;
    int*   inc      = deg + N;
    int*   row_ptr  = (int*)alloc((size_t)(N + 1) * 4);
    int*   cursor   = (int*)alloc((size_t)N * 4);
    float* out_norm = (float*)alloc((size_t)N * 4);
    float* in_norm  = (float*)alloc((size_t)N * 4);
    int*   col      = (int*)alloc((size_t)E * 4);
    float* wval     = (float*)alloc((size_t)E * 4);
    float* B0       = (float*)alloc((size_t)N * HDIM * 4);  // T1, later H2
    float* B1       = (float*)alloc((size_t)N * HDIM * 4);  // H1, later T3
    float* B2       = (float*)alloc((size_t)N * HDIM * 4);  // A2
    const int nb    = (N + 1023) / 1024;
    int*   bsums    = (int*)alloc((size_t)nb * 4);
    (void)ws_size;

    // ---- preprocessing ----
    hipMemsetAsync(deg, 0, (size_t)2 * N * 4, stream);

    int egrid = (E + 255) / 256;
    degree_kernel<<<egrid, 256, 0, stream>>>(src, dst, outc, inc, E);
    scan_blocks<<<nb, 256, 0, stream>>>(inc, row_ptr, bsums, N);
    scan_sums<<<1, 64, 0, stream>>>(bsums, nb);
    int ngrid = (N + 255) / 256;
    node_prep_kernel<<<ngrid, 256, 0, stream>>>(outc, inc, row_ptr, bsums,
                                                out_norm, in_norm, cursor, N, E);
    scatter_kernel<<<egrid, 256, 0, stream>>>(src, dst, ew, out_norm, cursor, col, wval, E);

    const int spmm_grid = (N + 3) / 4;   // one wave per node, 4 waves/block

    // ---- layer 1: T1 = X @ W1 ; H1 = relu(SpMM(T1)*in_norm + b1) ----
    {
        dim3 grid((N + 127) / 128);
        gemm128_f32<0><<<grid, 256, 0, stream>>>(features, W1, B0, N, F_IN,
                                                 nullptr, nullptr);
    }
    spmm128<1><<<spmm_grid, 256, 0, stream>>>(B0, row_ptr, col, wval, B1, in_norm, b1, N);

    // ---- layer 2: A2 = SpMM(H1) ; H2 = relu((A2 @ W2)*in_norm + b2) ----
    spmm128<0><<<spmm_grid, 256, 0, stream>>>(B1, row_ptr, col, wval, B2, nullptr, nullptr, N);
    {
        dim3 grid((N + 127) / 128);
        gemm128_f32<1><<<grid, 256, 0, stream>>>(B2, W2, B0, N, HDIM, in_norm, b2);
    }

    // ---- layer 3: T3 = H2 @ W3 ; OUT = SpMM(T3)*in_norm + b3 ----
    {
        dim3 grid((N + 127) / 128, 1);
        gemm_f32<0><<<grid, 256, 0, stream>>>(B0, W3, B1, N, CDIM, HDIM,
                                              HDIM, CDIM, CDIM, nullptr, nullptr);
    }
    spmm40<<<spmm_grid, 256, 0, stream>>>(B1, row_ptr, col, wval, out, in_norm, b3, N);
}

// Round 4
// 380.901 us; speedup vs baseline: 1.4929x; 1.1383x over previous
//
#include <hip/hip_runtime.h>
#include <hip/hip_bf16.h>
#include <cstdint>

// ---------------------------------------------------------------------------
// GCN 3-layer forward. fp32, CSR-by-dst SpMM (no float atomics).
// Round 4: 4-edge-stream SpMMs (16 lanes x float4 per edge), padded-64 T3.
// ---------------------------------------------------------------------------

#define F_IN 256
#define HDIM 128
#define CDIM 40

// ---- preprocessing ---------------------------------------------------------

__global__ __launch_bounds__(256)
void degree_kernel(const int* __restrict__ src, const int* __restrict__ dst,
                   int* __restrict__ outc, int* __restrict__ inc, int E) {
    int i = blockIdx.x * 256 + threadIdx.x;
    if (i < E) {
        atomicAdd(&outc[src[i]], 1);
        atomicAdd(&inc[dst[i]], 1);
    }
}

// stage 1: per-block (1024 elems) exclusive scan + block sums
__global__ __launch_bounds__(256)
void scan_blocks(const int* __restrict__ cnt, int* __restrict__ out,
                 int* __restrict__ bsums, int n) {
    const int t = threadIdx.x;
    const int idx = blockIdx.x * 1024 + t * 4;
    int4 v = make_int4(0, 0, 0, 0);
    if (idx + 3 < n) {
        v = *reinterpret_cast<const int4*>(cnt + idx);
    } else {
        if (idx     < n) v.x = cnt[idx];
        if (idx + 1 < n) v.y = cnt[idx + 1];
        if (idx + 2 < n) v.z = cnt[idx + 2];
        if (idx + 3 < n) v.w = cnt[idx + 3];
    }
    const int s = v.x + v.y + v.z + v.w;
    const int lane = t & 63;
    int incl = s;
    #pragma unroll
    for (int off = 1; off < 64; off <<= 1) {
        int u = __shfl_up(incl, off);
        if (lane >= off) incl += u;
    }
    __shared__ int wsum[4];
    if (lane == 63) wsum[t >> 6] = incl;
    __syncthreads();
    const int w = t >> 6;
    int woff = 0;
    if (w > 0) woff += wsum[0];
    if (w > 1) woff += wsum[1];
    if (w > 2) woff += wsum[2];
    const int excl = woff + incl - s;
    if (idx + 3 < n) {
        *reinterpret_cast<int4*>(out + idx) =
            make_int4(excl, excl + v.x, excl + v.x + v.y, excl + v.x + v.y + v.z);
    } else {
        if (idx     < n) out[idx]     = excl;
        if (idx + 1 < n) out[idx + 1] = excl + v.x;
        if (idx + 2 < n) out[idx + 2] = excl + v.x + v.y;
        if (idx + 3 < n) out[idx + 3] = excl + v.x + v.y + v.z;
    }
    if (t == 255) bsums[blockIdx.x] = woff + incl;
}

// stage 2: one wave scans the block sums (exclusive, in place)
__global__ __launch_bounds__(64)
void scan_sums(int* __restrict__ bsums, int nb) {
    const int lane = threadIdx.x & 63;
    int carry = 0;
    for (int base = 0; base < nb; base += 64) {
        int v = (base + lane < nb) ? bsums[base + lane] : 0;
        int incl = v;
        #pragma unroll
        for (int off = 1; off < 64; off <<= 1) {
            int u = __shfl_up(incl, off);
            if (lane >= off) incl += u;
        }
        if (base + lane < nb) bsums[base + lane] = carry + incl - v;
        carry += __shfl(incl, 63);
    }
}

// stage 3 folded in: finalize row_ptr (+block offset), norms, cursor
__global__ __launch_bounds__(256)
void node_prep_kernel(const int* __restrict__ outc, const int* __restrict__ inc,
                      int* __restrict__ row_ptr, const int* __restrict__ bsums,
                      float* __restrict__ out_norm, float* __restrict__ in_norm,
                      int* __restrict__ cursor, int n, int E) {
    int i = blockIdx.x * 256 + threadIdx.x;
    if (i < n) {
        int rp = row_ptr[i] + bsums[i >> 10];
        row_ptr[i] = rp;
        cursor[i]  = rp;
        out_norm[i] = rsqrtf((float)max(outc[i], 1));
        in_norm[i]  = rsqrtf((float)max(inc[i], 1));
    }
    if (i == 0) row_ptr[n] = E;   // in-degrees sum to E
}

// counting-sort edges by dst; fold ew*out_norm[src] into edge weight
__global__ __launch_bounds__(256)
void scatter_kernel(const int* __restrict__ src, const int* __restrict__ dst,
                    const float* __restrict__ ew, const float* __restrict__ out_norm,
                    int* __restrict__ cursor, int* __restrict__ col,
                    float* __restrict__ wval, int E) {
    int i = blockIdx.x * 256 + threadIdx.x;
    if (i < E) {
        int s = src[i], d = dst[i];
        int pos = atomicAdd(&cursor[d], 1);
        col[pos]  = s;
        wval[pos] = ew[i] * out_norm[s];
    }
}

// ---- fp32 GEMM, Nn == 128 exactly: C[M x 128] = A[M x K] @ B[K x 128] -----
// BM=128 BN=128 BK=16, 256 threads, 8x8 per thread.
// MODE 0: plain store.  MODE 1: relu(acc*rownorm[row] + bias[col]).

template <int MODE>
__global__ __launch_bounds__(256)
void gemm128_f32(const float* __restrict__ A, const float* __restrict__ B,
                 float* __restrict__ C, int M, int K,
                 const float* __restrict__ rownorm, const float* __restrict__ bias) {
    constexpr int BM = 128, BK = 16;
    __shared__ float As[BK][BM];   // k-major (transposed on stage-in)
    __shared__ float Bs[BK][128];

    const int t = threadIdx.x;
    const int row0 = blockIdx.x * BM;
    const int rowbase = (t >> 4) * 8;
    const int colbase = (t & 15) * 8;
    const int ar  = t >> 1;          // A stage-in: row in tile
    const int akq = (t & 1) * 8;     // A stage-in: k offset (8 floats)
    const int bk  = t >> 4;          // B stage-in: k row
    const int bc8 = (t & 15) * 8;    // B stage-in: col offset (8 floats)

    float acc[8][8];
    #pragma unroll
    for (int i = 0; i < 8; ++i)
        #pragma unroll
        for (int j = 0; j < 8; ++j) acc[i][j] = 0.f;

    for (int k0 = 0; k0 < K; k0 += BK) {
        float4 a0 = make_float4(0.f, 0.f, 0.f, 0.f), a1 = a0;
        if (row0 + ar < M) {
            const float* ap = A + (size_t)(row0 + ar) * K + k0 + akq;
            a0 = *reinterpret_cast<const float4*>(ap);
            a1 = *reinterpret_cast<const float4*>(ap + 4);
        }
        const float* bp = B + (size_t)(k0 + bk) * 128 + bc8;
        float4 b0 = *reinterpret_cast<const float4*>(bp);
        float4 b1 = *reinterpret_cast<const float4*>(bp + 4);
        __syncthreads();   // previous iter done reading LDS
        As[akq + 0][ar] = a0.x; As[akq + 1][ar] = a0.y;
        As[akq + 2][ar] = a0.z; As[akq + 3][ar] = a0.w;
        As[akq + 4][ar] = a1.x; As[akq + 5][ar] = a1.y;
        As[akq + 6][ar] = a1.z; As[akq + 7][ar] = a1.w;
        *reinterpret_cast<float4*>(&Bs[bk][bc8])     = b0;
        *reinterpret_cast<float4*>(&Bs[bk][bc8 + 4]) = b1;
        __syncthreads();

        #pragma unroll
        for (int kk = 0; kk < BK; ++kk) {
            float4 av0 = *reinterpret_cast<const float4*>(&As[kk][rowbase]);
            float4 av1 = *reinterpret_cast<const float4*>(&As[kk][rowbase + 4]);
            float4 bv0 = *reinterpret_cast<const float4*>(&Bs[kk][colbase]);
            float4 bv1 = *reinterpret_cast<const float4*>(&Bs[kk][colbase + 4]);
            float a[8] = {av0.x, av0.y, av0.z, av0.w, av1.x, av1.y, av1.z, av1.w};
            float b[8] = {bv0.x, bv0.y, bv0.z, bv0.w, bv1.x, bv1.y, bv1.z, bv1.w};
            #pragma unroll
            for (int i = 0; i < 8; ++i)
                #pragma unroll
                for (int j = 0; j < 8; ++j)
                    acc[i][j] = fmaf(a[i], b[j], acc[i][j]);
        }
    }

    float bb[8];
    if (MODE == 1) {
        float4 b0 = *reinterpret_cast<const float4*>(bias + colbase);
        float4 b1 = *reinterpret_cast<const float4*>(bias + colbase + 4);
        bb[0] = b0.x; bb[1] = b0.y; bb[2] = b0.z; bb[3] = b0.w;
        bb[4] = b1.x; bb[5] = b1.y; bb[6] = b1.z; bb[7] = b1.w;
    }
    #pragma unroll
    for (int i = 0; i < 8; ++i) {
        int row = row0 + rowbase + i;
        if (row >= M) break;
        float v[8];
        #pragma unroll
        for (int j = 0; j < 8; ++j) v[j] = acc[i][j];
        if (MODE == 1) {
            float rn = rownorm[row];
            #pragma unroll
            for (int j = 0; j < 8; ++j) v[j] = fmaxf(fmaf(v[j], rn, bb[j]), 0.f);
        }
        float* cp = C + (size_t)row * 128 + colbase;
        *reinterpret_cast<float4*>(cp)     = make_float4(v[0], v[1], v[2], v[3]);
        *reinterpret_cast<float4*>(cp + 4) = make_float4(v[4], v[5], v[6], v[7]);
    }
}

// ---- fp32 tiled GEMM (generic Nn, layer 3; ldc padded): BM=128 BN=64 BK=16

template <int MODE>
__global__ __launch_bounds__(256)
void gemm_f32(const float* __restrict__ A, const float* __restrict__ B,
              float* __restrict__ C, int M, int Nn, int K,
              int lda, int ldb, int ldc,
              const float* __restrict__ rownorm, const float* __restrict__ bias) {
    constexpr int BM = 128, BN = 64, BK = 16;
    __shared__ float As[BK][BM];
    __shared__ float Bs[BK][BN];

    const int t = threadIdx.x;
    const int row0 = blockIdx.x * BM;
    const int col0 = blockIdx.y * BN;
    const int rowbase = (t >> 4) * 8;
    const int colbase = (t & 15) * 4;
    const int ar  = t >> 1;
    const int akq = (t & 1) * 8;
    const int bk  = t >> 4;
    const int bc4 = (t & 15) * 4;

    float acc[8][4];
    #pragma unroll
    for (int i = 0; i < 8; ++i)
        #pragma unroll
        for (int j = 0; j < 4; ++j) acc[i][j] = 0.f;

    for (int k0 = 0; k0 < K; k0 += BK) {
        float4 a0 = make_float4(0.f, 0.f, 0.f, 0.f), a1 = a0;
        if (row0 + ar < M) {
            const float* ap = A + (size_t)(row0 + ar) * lda + k0 + akq;
            a0 = *reinterpret_cast<const float4*>(ap);
            a1 = *reinterpret_cast<const float4*>(ap + 4);
        }
        float4 bv = make_float4(0.f, 0.f, 0.f, 0.f);
        if (col0 + bc4 < Nn) {
            bv = *reinterpret_cast<const float4*>(B + (size_t)(k0 + bk) * ldb + col0 + bc4);
        }
        __syncthreads();
        As[akq + 0][ar] = a0.x; As[akq + 1][ar] = a0.y;
        As[akq + 2][ar] = a0.z; As[akq + 3][ar] = a0.w;
        As[akq + 4][ar] = a1.x; As[akq + 5][ar] = a1.y;
        As[akq + 6][ar] = a1.z; As[akq + 7][ar] = a1.w;
        *reinterpret_cast<float4*>(&Bs[bk][bc4]) = bv;
        __syncthreads();

        #pragma unroll
        for (int kk = 0; kk < BK; ++kk) {
            float4 av0 = *reinterpret_cast<const float4*>(&As[kk][rowbase]);
            float4 av1 = *reinterpret_cast<const float4*>(&As[kk][rowbase + 4]);
            float4 bv2 = *reinterpret_cast<const float4*>(&Bs[kk][colbase]);
            float a[8] = {av0.x, av0.y, av0.z, av0.w, av1.x, av1.y, av1.z, av1.w};
            float b[4] = {bv2.x, bv2.y, bv2.z, bv2.w};
            #pragma unroll
            for (int i = 0; i < 8; ++i)
                #pragma unroll
                for (int j = 0; j < 4; ++j)
                    acc[i][j] = fmaf(a[i], b[j], acc[i][j]);
        }
    }

    if (col0 + colbase >= Nn) return;
    float4 bb = make_float4(0.f, 0.f, 0.f, 0.f);
    if (MODE == 1) bb = *reinterpret_cast<const float4*>(bias + col0 + colbase);
    #pragma unroll
    for (int i = 0; i < 8; ++i) {
        int row = row0 + rowbase + i;
        if (row >= M) break;
        float4 v = make_float4(acc[i][0], acc[i][1], acc[i][2], acc[i][3]);
        if (MODE == 1) {
            float rn = rownorm[row];
            v.x = fmaxf(fmaf(v.x, rn, bb.x), 0.f);
            v.y = fmaxf(fmaf(v.y, rn, bb.y), 0.f);
            v.z = fmaxf(fmaf(v.z, rn, bb.z), 0.f);
            v.w = fmaxf(fmaf(v.w, rn, bb.w), 0.f);
        }
        *reinterpret_cast<float4*>(C + (size_t)row * ldc + col0 + colbase) = v;
    }
}

// ---- SpMM (CSR by dst), 128 features ---------------------------------------
// One wave per node; FOUR 16-lane quarters process alternate edges (4 gather
// streams, 2 float4 loads each = 8 outstanding per wave). Two-step shuffle
// combine; quarter 0 stores.

template <int EPI>
__global__ __launch_bounds__(256)
void spmm128(const float* __restrict__ H, const int* __restrict__ row_ptr,
             const int* __restrict__ col, const float* __restrict__ wv,
             float* __restrict__ out, const float* __restrict__ in_norm,
             const float* __restrict__ bias, int n) {
    int wid  = (blockIdx.x * 256 + threadIdx.x) >> 6;
    int lane = threadIdx.x & 63;
    if (wid >= n) return;
    const int quarter = lane >> 4;
    const int q       = lane & 15;
    int e0 = row_ptr[wid], e1 = row_ptr[wid + 1];
    float4 acc0 = make_float4(0.f, 0.f, 0.f, 0.f);
    float4 acc1 = make_float4(0.f, 0.f, 0.f, 0.f);
    for (int e = e0 + quarter; e < e1; e += 4) {
        int s   = col[e];
        float w = wv[e];
        const float* hp = H + (size_t)s * 128 + q * 4;
        float4 v0 = *reinterpret_cast<const float4*>(hp);
        float4 v1 = *reinterpret_cast<const float4*>(hp + 64);
        acc0.x = fmaf(w, v0.x, acc0.x); acc0.y = fmaf(w, v0.y, acc0.y);
        acc0.z = fmaf(w, v0.z, acc0.z); acc0.w = fmaf(w, v0.w, acc0.w);
        acc1.x = fmaf(w, v1.x, acc1.x); acc1.y = fmaf(w, v1.y, acc1.y);
        acc1.z = fmaf(w, v1.z, acc1.z); acc1.w = fmaf(w, v1.w, acc1.w);
    }
    #pragma unroll
    for (int d = 16; d <= 32; d <<= 1) {
        acc0.x += __shfl_xor(acc0.x, d); acc0.y += __shfl_xor(acc0.y, d);
        acc0.z += __shfl_xor(acc0.z, d); acc0.w += __shfl_xor(acc0.w, d);
        acc1.x += __shfl_xor(acc1.x, d); acc1.y += __shfl_xor(acc1.y, d);
        acc1.z += __shfl_xor(acc1.z, d); acc1.w += __shfl_xor(acc1.w, d);
    }
    if (quarter == 0) {
        if (EPI == 1) {
            float nn = in_norm[wid];
            float4 bb0 = *reinterpret_cast<const float4*>(bias + q * 4);
            float4 bb1 = *reinterpret_cast<const float4*>(bias + 64 + q * 4);
            acc0.x = fmaxf(fmaf(acc0.x, nn, bb0.x), 0.f);
            acc0.y = fmaxf(fmaf(acc0.y, nn, bb0.y), 0.f);
            acc0.z = fmaxf(fmaf(acc0.z, nn, bb0.z), 0.f);
            acc0.w = fmaxf(fmaf(acc0.w, nn, bb0.w), 0.f);
            acc1.x = fmaxf(fmaf(acc1.x, nn, bb1.x), 0.f);
            acc1.y = fmaxf(fmaf(acc1.y, nn, bb1.y), 0.f);
            acc1.z = fmaxf(fmaf(acc1.z, nn, bb1.z), 0.f);
            acc1.w = fmaxf(fmaf(acc1.w, nn, bb1.w), 0.f);
        }
        float* op = out + (size_t)wid * 128 + q * 4;
        *reinterpret_cast<float4*>(op)      = acc0;
        *reinterpret_cast<float4*>(op + 64) = acc1;
    }
}

// ---- SpMM final layer: T3 padded to 64 cols; out is N x 40 -----------------
// 4 edge streams of 16 lanes; lane loads float4 (16 lanes cover the 256B row).

__global__ __launch_bounds__(256)
void spmm40(const float* __restrict__ H, const int* __restrict__ row_ptr,
            const int* __restrict__ col, const float* __restrict__ wv,
            float* __restrict__ out, const float* __restrict__ in_norm,
            const float* __restrict__ bias, int n) {
    int wid  = (blockIdx.x * 256 + threadIdx.x) >> 6;
    int lane = threadIdx.x & 63;
    if (wid >= n) return;
    const int quarter = lane >> 4;
    const int q       = lane & 15;
    int e0 = row_ptr[wid], e1 = row_ptr[wid + 1];
    float4 acc = make_float4(0.f, 0.f, 0.f, 0.f);
    for (int e = e0 + quarter; e < e1; e += 4) {
        int s   = col[e];
        float w = wv[e];
        float4 v = *reinterpret_cast<const float4*>(H + (size_t)s * 64 + q * 4);
        acc.x = fmaf(w, v.x, acc.x);
        acc.y = fmaf(w, v.y, acc.y);
        acc.z = fmaf(w, v.z, acc.z);
        acc.w = fmaf(w, v.w, acc.w);
    }
    #pragma unroll
    for (int d = 16; d <= 32; d <<= 1) {
        acc.x += __shfl_xor(acc.x, d);
        acc.y += __shfl_xor(acc.y, d);
        acc.z += __shfl_xor(acc.z, d);
        acc.w += __shfl_xor(acc.w, d);
    }
    if (quarter == 0 && q * 4 < CDIM) {
        float nn = in_norm[wid];
        float4 bb = *reinterpret_cast<const float4*>(bias + q * 4);
        acc.x = fmaf(acc.x, nn, bb.x);
        acc.y = fmaf(acc.y, nn, bb.y);
        acc.z = fmaf(acc.z, nn, bb.z);
        acc.w = fmaf(acc.w, nn, bb.w);
        *reinterpret_cast<float4*>(out + (size_t)wid * CDIM + q * 4) = acc;
    }
}

// ---------------------------------------------------------------------------

extern "C" void kernel_launch(void* const* d_in, const int* in_sizes, int n_in,
                              void* d_out, int out_size, void* d_ws, size_t ws_size,
                              hipStream_t stream) {
    const float* features = (const float*)d_in[0];
    const int*   src      = (const int*)d_in[1];
    const int*   dst      = (const int*)d_in[2];
    const float* ew       = (const float*)d_in[3];
    const float* W1       = (const float*)d_in[4];
    const float* b1       = (const float*)d_in[5];
    const float* W2       = (const float*)d_in[6];
    const float* b2       = (const float*)d_in[7];
    const float* W3       = (const float*)d_in[8];
    const float* b3       = (const float*)d_in[9];
    float* out = (float*)d_out;

    const int N = in_sizes[0] / F_IN;   // 50000
    const int E = in_sizes[1];          // 800000

    // ---- workspace carve-up ----
    char* ws = (char*)d_ws;
    size_t off = 0;
    auto alloc = [&](size_t bytes) -> void* {
        void* p = ws + off;
        off += (bytes + 255) & ~(size_t)255;
        return p;
    };
    int*   deg      = (int*)alloc((size_t)2 * N * 4);   // outc | inc (contiguous)
    int*   outc     = deg;
    int*   inc      = deg + N;
    int*   row_ptr  = (int*)alloc((size_t)(N + 1) * 4);
    int*   cursor   = (int*)alloc((size_t)N * 4);
    float* out_norm = (float*)alloc((size_t)N * 4);
    float* in_norm  = (float*)alloc((size_t)N * 4);
    int*   col      = (int*)alloc((size_t)E * 4);
    float* wval     = (float*)alloc((size_t)E * 4);
    float* B0       = (float*)alloc((size_t)N * HDIM * 4);  // T1, later H2
    float* B1       = (float*)alloc((size_t)N * HDIM * 4);  // H1, later padded T3
    float* B2       = (float*)alloc((size_t)N * HDIM * 4);  // A2
    const int nb    = (N + 1023) / 1024;
    int*   bsums    = (int*)alloc((size_t)nb * 4);
    (void)ws_size;

    // ---- preprocessing ----
    hipMemsetAsync(deg, 0, (size_t)2 * N * 4, stream);

    int egrid = (E + 255) / 256;
    degree_kernel<<<egrid, 256, 0, stream>>>(src, dst, outc, inc, E);
    scan_blocks<<<nb, 256, 0, stream>>>(inc, row_ptr, bsums, N);
    scan_sums<<<1, 64, 0, stream>>>(bsums, nb);
    int ngrid = (N + 255) / 256;
    node_prep_kernel<<<ngrid, 256, 0, stream>>>(outc, inc, row_ptr, bsums,
                                                out_norm, in_norm, cursor, N, E);
    scatter_kernel<<<egrid, 256, 0, stream>>>(src, dst, ew, out_norm, cursor, col, wval, E);

    const int spmm_grid = (N + 3) / 4;   // one wave per node, 4 waves/block

    // ---- layer 1: T1 = X @ W1 ; H1 = relu(SpMM(T1)*in_norm + b1) ----
    {
        dim3 grid((N + 127) / 128);
        gemm128_f32<0><<<grid, 256, 0, stream>>>(features, W1, B0, N, F_IN,
                                                 nullptr, nullptr);
    }
    spmm128<1><<<spmm_grid, 256, 0, stream>>>(B0, row_ptr, col, wval, B1, in_norm, b1, N);

    // ---- layer 2: A2 = SpMM(H1) ; H2 = relu((A2 @ W2)*in_norm + b2) ----
    spmm128<0><<<spmm_grid, 256, 0, stream>>>(B1, row_ptr, col, wval, B2, nullptr, nullptr, N);
    {
        dim3 grid((N + 127) / 128);
        gemm128_f32<1><<<grid, 256, 0, stream>>>(B2, W2, B0, N, HDIM, in_norm, b2);
    }

    // ---- layer 3: T3 = H2 @ W3 (ldc=64 padded) ; OUT = SpMM(T3)*in_norm+b3 -
    {
        dim3 grid((N + 127) / 128, 1);
        gemm_f32<0><<<grid, 256, 0, stream>>>(B0, W3, B1, N, CDIM, HDIM,
                                              HDIM, CDIM, 64, nullptr, nullptr);
    }
    spmm40<<<spmm_grid, 256, 0, stream>>>(B1, row_ptr, col, wval, out, in_norm, b3, N);
}

// Round 5
// 367.774 us; speedup vs baseline: 1.5462x; 1.0357x over previous
//
#include <hip/hip_runtime.h>
#include <hip/hip_bf16.h>
#include <cstdint>

// ---------------------------------------------------------------------------
// GCN 3-layer forward. fp32, CSR-by-dst SpMM (no float atomics).
// Round 5: packed int2 edge records (src, weight-bits) -> half the scatter
// write amplification; single 8B edge load in SpMMs.
// ---------------------------------------------------------------------------

#define F_IN 256
#define HDIM 128
#define CDIM 40

// ---- preprocessing ---------------------------------------------------------

__global__ __launch_bounds__(256)
void degree_kernel(const int* __restrict__ src, const int* __restrict__ dst,
                   int* __restrict__ outc, int* __restrict__ inc, int E) {
    int i = blockIdx.x * 256 + threadIdx.x;
    if (i < E) {
        atomicAdd(&outc[src[i]], 1);
        atomicAdd(&inc[dst[i]], 1);
    }
}

// stage 1: per-block (1024 elems) exclusive scan + block sums
__global__ __launch_bounds__(256)
void scan_blocks(const int* __restrict__ cnt, int* __restrict__ out,
                 int* __restrict__ bsums, int n) {
    const int t = threadIdx.x;
    const int idx = blockIdx.x * 1024 + t * 4;
    int4 v = make_int4(0, 0, 0, 0);
    if (idx + 3 < n) {
        v = *reinterpret_cast<const int4*>(cnt + idx);
    } else {
        if (idx     < n) v.x = cnt[idx];
        if (idx + 1 < n) v.y = cnt[idx + 1];
        if (idx + 2 < n) v.z = cnt[idx + 2];
        if (idx + 3 < n) v.w = cnt[idx + 3];
    }
    const int s = v.x + v.y + v.z + v.w;
    const int lane = t & 63;
    int incl = s;
    #pragma unroll
    for (int off = 1; off < 64; off <<= 1) {
        int u = __shfl_up(incl, off);
        if (lane >= off) incl += u;
    }
    __shared__ int wsum[4];
    if (lane == 63) wsum[t >> 6] = incl;
    __syncthreads();
    const int w = t >> 6;
    int woff = 0;
    if (w > 0) woff += wsum[0];
    if (w > 1) woff += wsum[1];
    if (w > 2) woff += wsum[2];
    const int excl = woff + incl - s;
    if (idx + 3 < n) {
        *reinterpret_cast<int4*>(out + idx) =
            make_int4(excl, excl + v.x, excl + v.x + v.y, excl + v.x + v.y + v.z);
    } else {
        if (idx     < n) out[idx]     = excl;
        if (idx + 1 < n) out[idx + 1] = excl + v.x;
        if (idx + 2 < n) out[idx + 2] = excl + v.x + v.y;
        if (idx + 3 < n) out[idx + 3] = excl + v.x + v.y + v.z;
    }
    if (t == 255) bsums[blockIdx.x] = woff + incl;
}

// stage 2: one wave scans the block sums (exclusive, in place)
__global__ __launch_bounds__(64)
void scan_sums(int* __restrict__ bsums, int nb) {
    const int lane = threadIdx.x & 63;
    int carry = 0;
    for (int base = 0; base < nb; base += 64) {
        int v = (base + lane < nb) ? bsums[base + lane] : 0;
        int incl = v;
        #pragma unroll
        for (int off = 1; off < 64; off <<= 1) {
            int u = __shfl_up(incl, off);
            if (lane >= off) incl += u;
        }
        if (base + lane < nb) bsums[base + lane] = carry + incl - v;
        carry += __shfl(incl, 63);
    }
}

// stage 3 folded in: finalize row_ptr (+block offset), norms, cursor
__global__ __launch_bounds__(256)
void node_prep_kernel(const int* __restrict__ outc, const int* __restrict__ inc,
                      int* __restrict__ row_ptr, const int* __restrict__ bsums,
                      float* __restrict__ out_norm, float* __restrict__ in_norm,
                      int* __restrict__ cursor, int n, int E) {
    int i = blockIdx.x * 256 + threadIdx.x;
    if (i < n) {
        int rp = row_ptr[i] + bsums[i >> 10];
        row_ptr[i] = rp;
        cursor[i]  = rp;
        out_norm[i] = rsqrtf((float)max(outc[i], 1));
        in_norm[i]  = rsqrtf((float)max(inc[i], 1));
    }
    if (i == 0) row_ptr[n] = E;   // in-degrees sum to E
}

// counting-sort edges by dst; packed record (src, ew*out_norm[src])
__global__ __launch_bounds__(256)
void scatter_kernel(const int* __restrict__ src, const int* __restrict__ dst,
                    const float* __restrict__ ew, const float* __restrict__ out_norm,
                    int* __restrict__ cursor, int2* __restrict__ edges, int E) {
    int i = blockIdx.x * 256 + threadIdx.x;
    if (i < E) {
        int s = src[i], d = dst[i];
        int pos = atomicAdd(&cursor[d], 1);
        edges[pos] = make_int2(s, __float_as_int(ew[i] * out_norm[s]));
    }
}

// ---- fp32 GEMM, Nn == 128 exactly: C[M x 128] = A[M x K] @ B[K x 128] -----
// BM=128 BN=128 BK=16, 256 threads, 8x8 per thread.
// MODE 0: plain store.  MODE 1: relu(acc*rownorm[row] + bias[col]).

template <int MODE>
__global__ __launch_bounds__(256)
void gemm128_f32(const float* __restrict__ A, const float* __restrict__ B,
                 float* __restrict__ C, int M, int K,
                 const float* __restrict__ rownorm, const float* __restrict__ bias) {
    constexpr int BM = 128, BK = 16;
    __shared__ float As[BK][BM];   // k-major (transposed on stage-in)
    __shared__ float Bs[BK][128];

    const int t = threadIdx.x;
    const int row0 = blockIdx.x * BM;
    const int rowbase = (t >> 4) * 8;
    const int colbase = (t & 15) * 8;
    const int ar  = t >> 1;          // A stage-in: row in tile
    const int akq = (t & 1) * 8;     // A stage-in: k offset (8 floats)
    const int bk  = t >> 4;          // B stage-in: k row
    const int bc8 = (t & 15) * 8;    // B stage-in: col offset (8 floats)

    float acc[8][8];
    #pragma unroll
    for (int i = 0; i < 8; ++i)
        #pragma unroll
        for (int j = 0; j < 8; ++j) acc[i][j] = 0.f;

    for (int k0 = 0; k0 < K; k0 += BK) {
        float4 a0 = make_float4(0.f, 0.f, 0.f, 0.f), a1 = a0;
        if (row0 + ar < M) {
            const float* ap = A + (size_t)(row0 + ar) * K + k0 + akq;
            a0 = *reinterpret_cast<const float4*>(ap);
            a1 = *reinterpret_cast<const float4*>(ap + 4);
        }
        const float* bp = B + (size_t)(k0 + bk) * 128 + bc8;
        float4 b0 = *reinterpret_cast<const float4*>(bp);
        float4 b1 = *reinterpret_cast<const float4*>(bp + 4);
        __syncthreads();   // previous iter done reading LDS
        As[akq + 0][ar] = a0.x; As[akq + 1][ar] = a0.y;
        As[akq + 2][ar] = a0.z; As[akq + 3][ar] = a0.w;
        As[akq + 4][ar] = a1.x; As[akq + 5][ar] = a1.y;
        As[akq + 6][ar] = a1.z; As[akq + 7][ar] = a1.w;
        *reinterpret_cast<float4*>(&Bs[bk][bc8])     = b0;
        *reinterpret_cast<float4*>(&Bs[bk][bc8 + 4]) = b1;
        __syncthreads();

        #pragma unroll
        for (int kk = 0; kk < BK; ++kk) {
            float4 av0 = *reinterpret_cast<const float4*>(&As[kk][rowbase]);
            float4 av1 = *reinterpret_cast<const float4*>(&As[kk][rowbase + 4]);
            float4 bv0 = *reinterpret_cast<const float4*>(&Bs[kk][colbase]);
            float4 bv1 = *reinterpret_cast<const float4*>(&Bs[kk][colbase + 4]);
            float a[8] = {av0.x, av0.y, av0.z, av0.w, av1.x, av1.y, av1.z, av1.w};
            float b[8] = {bv0.x, bv0.y, bv0.z, bv0.w, bv1.x, bv1.y, bv1.z, bv1.w};
            #pragma unroll
            for (int i = 0; i < 8; ++i)
                #pragma unroll
                for (int j = 0; j < 8; ++j)
                    acc[i][j] = fmaf(a[i], b[j], acc[i][j]);
        }
    }

    float bb[8];
    if (MODE == 1) {
        float4 b0 = *reinterpret_cast<const float4*>(bias + colbase);
        float4 b1 = *reinterpret_cast<const float4*>(bias + colbase + 4);
        bb[0] = b0.x; bb[1] = b0.y; bb[2] = b0.z; bb[3] = b0.w;
        bb[4] = b1.x; bb[5] = b1.y; bb[6] = b1.z; bb[7] = b1.w;
    }
    #pragma unroll
    for (int i = 0; i < 8; ++i) {
        int row = row0 + rowbase + i;
        if (row >= M) break;
        float v[8];
        #pragma unroll
        for (int j = 0; j < 8; ++j) v[j] = acc[i][j];
        if (MODE == 1) {
            float rn = rownorm[row];
            #pragma unroll
            for (int j = 0; j < 8; ++j) v[j] = fmaxf(fmaf(v[j], rn, bb[j]), 0.f);
        }
        float* cp = C + (size_t)row * 128 + colbase;
        *reinterpret_cast<float4*>(cp)     = make_float4(v[0], v[1], v[2], v[3]);
        *reinterpret_cast<float4*>(cp + 4) = make_float4(v[4], v[5], v[6], v[7]);
    }
}

// ---- fp32 tiled GEMM (generic Nn, layer 3; ldc padded): BM=128 BN=64 BK=16

template <int MODE>
__global__ __launch_bounds__(256)
void gemm_f32(const float* __restrict__ A, const float* __restrict__ B,
              float* __restrict__ C, int M, int Nn, int K,
              int lda, int ldb, int ldc,
              const float* __restrict__ rownorm, const float* __restrict__ bias) {
    constexpr int BM = 128, BN = 64, BK = 16;
    __shared__ float As[BK][BM];
    __shared__ float Bs[BK][BN];

    const int t = threadIdx.x;
    const int row0 = blockIdx.x * BM;
    const int col0 = blockIdx.y * BN;
    const int rowbase = (t >> 4) * 8;
    const int colbase = (t & 15) * 4;
    const int ar  = t >> 1;
    const int akq = (t & 1) * 8;
    const int bk  = t >> 4;
    const int bc4 = (t & 15) * 4;

    float acc[8][4];
    #pragma unroll
    for (int i = 0; i < 8; ++i)
        #pragma unroll
        for (int j = 0; j < 4; ++j) acc[i][j] = 0.f;

    for (int k0 = 0; k0 < K; k0 += BK) {
        float4 a0 = make_float4(0.f, 0.f, 0.f, 0.f), a1 = a0;
        if (row0 + ar < M) {
            const float* ap = A + (size_t)(row0 + ar) * lda + k0 + akq;
            a0 = *reinterpret_cast<const float4*>(ap);
            a1 = *reinterpret_cast<const float4*>(ap + 4);
        }
        float4 bv = make_float4(0.f, 0.f, 0.f, 0.f);
        if (col0 + bc4 < Nn) {
            bv = *reinterpret_cast<const float4*>(B + (size_t)(k0 + bk) * ldb + col0 + bc4);
        }
        __syncthreads();
        As[akq + 0][ar] = a0.x; As[akq + 1][ar] = a0.y;
        As[akq + 2][ar] = a0.z; As[akq + 3][ar] = a0.w;
        As[akq + 4][ar] = a1.x; As[akq + 5][ar] = a1.y;
        As[akq + 6][ar] = a1.z; As[akq + 7][ar] = a1.w;
        *reinterpret_cast<float4*>(&Bs[bk][bc4]) = bv;
        __syncthreads();

        #pragma unroll
        for (int kk = 0; kk < BK; ++kk) {
            float4 av0 = *reinterpret_cast<const float4*>(&As[kk][rowbase]);
            float4 av1 = *reinterpret_cast<const float4*>(&As[kk][rowbase + 4]);
            float4 bv2 = *reinterpret_cast<const float4*>(&Bs[kk][colbase]);
            float a[8] = {av0.x, av0.y, av0.z, av0.w, av1.x, av1.y, av1.z, av1.w};
            float b[4] = {bv2.x, bv2.y, bv2.z, bv2.w};
            #pragma unroll
            for (int i = 0; i < 8; ++i)
                #pragma unroll
                for (int j = 0; j < 4; ++j)
                    acc[i][j] = fmaf(a[i], b[j], acc[i][j]);
        }
    }

    if (col0 + colbase >= Nn) return;
    float4 bb = make_float4(0.f, 0.f, 0.f, 0.f);
    if (MODE == 1) bb = *reinterpret_cast<const float4*>(bias + col0 + colbase);
    #pragma unroll
    for (int i = 0; i < 8; ++i) {
        int row = row0 + rowbase + i;
        if (row >= M) break;
        float4 v = make_float4(acc[i][0], acc[i][1], acc[i][2], acc[i][3]);
        if (MODE == 1) {
            float rn = rownorm[row];
            v.x = fmaxf(fmaf(v.x, rn, bb.x), 0.f);
            v.y = fmaxf(fmaf(v.y, rn, bb.y), 0.f);
            v.z = fmaxf(fmaf(v.z, rn, bb.z), 0.f);
            v.w = fmaxf(fmaf(v.w, rn, bb.w), 0.f);
        }
        *reinterpret_cast<float4*>(C + (size_t)row * ldc + col0 + colbase) = v;
    }
}

// ---- SpMM (CSR by dst), 128 features ---------------------------------------
// One wave per node; FOUR 16-lane quarters process alternate edges (4 gather
// streams, 2 float4 loads each). Packed int2 edge record = single 8B load.

template <int EPI>
__global__ __launch_bounds__(256)
void spmm128(const float* __restrict__ H, const int* __restrict__ row_ptr,
             const int2* __restrict__ edges,
             float* __restrict__ out, const float* __restrict__ in_norm,
             const float* __restrict__ bias, int n) {
    int wid  = (blockIdx.x * 256 + threadIdx.x) >> 6;
    int lane = threadIdx.x & 63;
    if (wid >= n) return;
    const int quarter = lane >> 4;
    const int q       = lane & 15;
    int e0 = row_ptr[wid], e1 = row_ptr[wid + 1];
    float4 acc0 = make_float4(0.f, 0.f, 0.f, 0.f);
    float4 acc1 = make_float4(0.f, 0.f, 0.f, 0.f);
    #pragma unroll 2
    for (int e = e0 + quarter; e < e1; e += 4) {
        int2 er = edges[e];
        int   s = er.x;
        float w = __int_as_float(er.y);
        const float* hp = H + (size_t)s * 128 + q * 4;
        float4 v0 = *reinterpret_cast<const float4*>(hp);
        float4 v1 = *reinterpret_cast<const float4*>(hp + 64);
        acc0.x = fmaf(w, v0.x, acc0.x); acc0.y = fmaf(w, v0.y, acc0.y);
        acc0.z = fmaf(w, v0.z, acc0.z); acc0.w = fmaf(w, v0.w, acc0.w);
        acc1.x = fmaf(w, v1.x, acc1.x); acc1.y = fmaf(w, v1.y, acc1.y);
        acc1.z = fmaf(w, v1.z, acc1.z); acc1.w = fmaf(w, v1.w, acc1.w);
    }
    #pragma unroll
    for (int d = 16; d <= 32; d <<= 1) {
        acc0.x += __shfl_xor(acc0.x, d); acc0.y += __shfl_xor(acc0.y, d);
        acc0.z += __shfl_xor(acc0.z, d); acc0.w += __shfl_xor(acc0.w, d);
        acc1.x += __shfl_xor(acc1.x, d); acc1.y += __shfl_xor(acc1.y, d);
        acc1.z += __shfl_xor(acc1.z, d); acc1.w += __shfl_xor(acc1.w, d);
    }
    if (quarter == 0) {
        if (EPI == 1) {
            float nn = in_norm[wid];
            float4 bb0 = *reinterpret_cast<const float4*>(bias + q * 4);
            float4 bb1 = *reinterpret_cast<const float4*>(bias + 64 + q * 4);
            acc0.x = fmaxf(fmaf(acc0.x, nn, bb0.x), 0.f);
            acc0.y = fmaxf(fmaf(acc0.y, nn, bb0.y), 0.f);
            acc0.z = fmaxf(fmaf(acc0.z, nn, bb0.z), 0.f);
            acc0.w = fmaxf(fmaf(acc0.w, nn, bb0.w), 0.f);
            acc1.x = fmaxf(fmaf(acc1.x, nn, bb1.x), 0.f);
            acc1.y = fmaxf(fmaf(acc1.y, nn, bb1.y), 0.f);
            acc1.z = fmaxf(fmaf(acc1.z, nn, bb1.z), 0.f);
            acc1.w = fmaxf(fmaf(acc1.w, nn, bb1.w), 0.f);
        }
        float* op = out + (size_t)wid * 128 + q * 4;
        *reinterpret_cast<float4*>(op)      = acc0;
        *reinterpret_cast<float4*>(op + 64) = acc1;
    }
}

// ---- SpMM final layer: T3 padded to 64 cols; out is N x 40 -----------------

__global__ __launch_bounds__(256)
void spmm40(const float* __restrict__ H, const int* __restrict__ row_ptr,
            const int2* __restrict__ edges,
            float* __restrict__ out, const float* __restrict__ in_norm,
            const float* __restrict__ bias, int n) {
    int wid  = (blockIdx.x * 256 + threadIdx.x) >> 6;
    int lane = threadIdx.x & 63;
    if (wid >= n) return;
    const int quarter = lane >> 4;
    const int q       = lane & 15;
    int e0 = row_ptr[wid], e1 = row_ptr[wid + 1];
    float4 acc = make_float4(0.f, 0.f, 0.f, 0.f);
    #pragma unroll 2
    for (int e = e0 + quarter; e < e1; e += 4) {
        int2 er = edges[e];
        int   s = er.x;
        float w = __int_as_float(er.y);
        float4 v = *reinterpret_cast<const float4*>(H + (size_t)s * 64 + q * 4);
        acc.x = fmaf(w, v.x, acc.x);
        acc.y = fmaf(w, v.y, acc.y);
        acc.z = fmaf(w, v.z, acc.z);
        acc.w = fmaf(w, v.w, acc.w);
    }
    #pragma unroll
    for (int d = 16; d <= 32; d <<= 1) {
        acc.x += __shfl_xor(acc.x, d);
        acc.y += __shfl_xor(acc.y, d);
        acc.z += __shfl_xor(acc.z, d);
        acc.w += __shfl_xor(acc.w, d);
    }
    if (quarter == 0 && q * 4 < CDIM) {
        float nn = in_norm[wid];
        float4 bb = *reinterpret_cast<const float4*>(bias + q * 4);
        acc.x = fmaf(acc.x, nn, bb.x);
        acc.y = fmaf(acc.y, nn, bb.y);
        acc.z = fmaf(acc.z, nn, bb.z);
        acc.w = fmaf(acc.w, nn, bb.w);
        *reinterpret_cast<float4*>(out + (size_t)wid * CDIM + q * 4) = acc;
    }
}

// ---------------------------------------------------------------------------

extern "C" void kernel_launch(void* const* d_in, const int* in_sizes, int n_in,
                              void* d_out, int out_size, void* d_ws, size_t ws_size,
                              hipStream_t stream) {
    const float* features = (const float*)d_in[0];
    const int*   src      = (const int*)d_in[1];
    const int*   dst      = (const int*)d_in[2];
    const float* ew       = (const float*)d_in[3];
    const float* W1       = (const float*)d_in[4];
    const float* b1       = (const float*)d_in[5];
    const float* W2       = (const float*)d_in[6];
    const float* b2       = (const float*)d_in[7];
    const float* W3       = (const float*)d_in[8];
    const float* b3       = (const float*)d_in[9];
    float* out = (float*)d_out;

    const int N = in_sizes[0] / F_IN;   // 50000
    const int E = in_sizes[1];          // 800000

    // ---- workspace carve-up ----
    char* ws = (char*)d_ws;
    size_t off = 0;
    auto alloc = [&](size_t bytes) -> void* {
        void* p = ws + off;
        off += (bytes + 255) & ~(size_t)255;
        return p;
    };
    int*   deg      = (int*)alloc((size_t)2 * N * 4);   // outc | inc (contiguous)
    int*   outc     = deg;
    int*   inc      = deg + N;
    int*   row_ptr  = (int*)alloc((size_t)(N + 1) * 4);
    int*   cursor   = (int*)alloc((size_t)N * 4);
    float* out_norm = (float*)alloc((size_t)N * 4);
    float* in_norm  = (float*)alloc((size_t)N * 4);
    int2*  edges    = (int2*)alloc((size_t)E * 8);
    float* B0       = (float*)alloc((size_t)N * HDIM * 4);  // T1, later H2
    float* B1       = (float*)alloc((size_t)N * HDIM * 4);  // H1, later padded T3
    float* B2       = (float*)alloc((size_t)N * HDIM * 4);  // A2
    const int nb    = (N + 1023) / 1024;
    int*   bsums    = (int*)alloc((size_t)nb * 4);
    (void)ws_size;

    // ---- preprocessing ----
    hipMemsetAsync(deg, 0, (size_t)2 * N * 4, stream);

    int egrid = (E + 255) / 256;
    degree_kernel<<<egrid, 256, 0, stream>>>(src, dst, outc, inc, E);
    scan_blocks<<<nb, 256, 0, stream>>>(inc, row_ptr, bsums, N);
    scan_sums<<<1, 64, 0, stream>>>(bsums, nb);
    int ngrid = (N + 255) / 256;
    node_prep_kernel<<<ngrid, 256, 0, stream>>>(outc, inc, row_ptr, bsums,
                                                out_norm, in_norm, cursor, N, E);
    scatter_kernel<<<egrid, 256, 0, stream>>>(src, dst, ew, out_norm, cursor, edges, E);

    const int spmm_grid = (N + 3) / 4;   // one wave per node, 4 waves/block

    // ---- layer 1: T1 = X @ W1 ; H1 = relu(SpMM(T1)*in_norm + b1) ----
    {
        dim3 grid((N + 127) / 128);
        gemm128_f32<0><<<grid, 256, 0, stream>>>(features, W1, B0, N, F_IN,
                                                 nullptr, nullptr);
    }
    spmm128<1><<<spmm_grid, 256, 0, stream>>>(B0, row_ptr, edges, B1, in_norm, b1, N);

    // ---- layer 2: A2 = SpMM(H1) ; H2 = relu((A2 @ W2)*in_norm + b2) ----
    spmm128<0><<<spmm_grid, 256, 0, stream>>>(B1, row_ptr, edges, B2, nullptr, nullptr, N);
    {
        dim3 grid((N + 127) / 128);
        gemm128_f32<1><<<grid, 256, 0, stream>>>(B2, W2, B0, N, HDIM, in_norm, b2);
    }

    // ---- layer 3: T3 = H2 @ W3 (ldc=64 padded) ; OUT = SpMM(T3)*in_norm+b3 -
    {
        dim3 grid((N + 127) / 128, 1);
        gemm_f32<0><<<grid, 256, 0, stream>>>(B0, W3, B1, N, CDIM, HDIM,
                                              HDIM, CDIM, 64, nullptr, nullptr);
    }
    spmm40<<<spmm_grid, 256, 0, stream>>>(B1, row_ptr, edges, out, in_norm, b3, N);
}

// Round 6
// 357.471 us; speedup vs baseline: 1.5908x; 1.0288x over previous
//
#include <hip/hip_runtime.h>
#include <hip/hip_bf16.h>
#include <cstdint>

// ---------------------------------------------------------------------------
// GCN 3-layer forward. fp32, CSR-by-dst SpMM (no float atomics).
// Round 6: XCD-localized atomics — 8-way replicated degree counters and
// 8-way split scatter cursors (copy = blockIdx & 7, matching round-robin
// XCD dispatch). Kills cross-XCD cache-line ping-pong on both atomic sites.
// ---------------------------------------------------------------------------

#define F_IN 256
#define HDIM 128
#define CDIM 40
#define NCPY 8

// ---- preprocessing ---------------------------------------------------------

// 8-way replicated histogram: copy c = blockIdx & 7 stays XCD-local.
__global__ __launch_bounds__(256)
void degree_kernel(const int* __restrict__ src, const int* __restrict__ dst,
                   int* __restrict__ outc8, int* __restrict__ inc8,
                   int E, int N) {
    const int copy = blockIdx.x & (NCPY - 1);
    int* oc = outc8 + (size_t)copy * N;
    int* ic = inc8  + (size_t)copy * N;
    int i = blockIdx.x * 256 + threadIdx.x;
    if (i < E) {
        atomicAdd(&oc[src[i]], 1);
        atomicAdd(&ic[dst[i]], 1);
    }
}

// stage 1: per-block (1024 elems) exclusive scan of summed inc copies
__global__ __launch_bounds__(256)
void scan_blocks(const int* __restrict__ inc8, int* __restrict__ out,
                 int* __restrict__ bsums, int n) {
    const int t = threadIdx.x;
    const int idx = blockIdx.x * 1024 + t * 4;
    int4 v = make_int4(0, 0, 0, 0);
    if (idx + 3 < n) {
        #pragma unroll
        for (int c = 0; c < NCPY; ++c) {
            int4 u = *reinterpret_cast<const int4*>(inc8 + (size_t)c * n + idx);
            v.x += u.x; v.y += u.y; v.z += u.z; v.w += u.w;
        }
    } else {
        for (int j = 0; j < 4; ++j) {
            if (idx + j < n) {
                int s = 0;
                #pragma unroll
                for (int c = 0; c < NCPY; ++c) s += inc8[(size_t)c * n + idx + j];
                (&v.x)[j] = s;
            }
        }
    }
    const int s = v.x + v.y + v.z + v.w;
    const int lane = t & 63;
    int incl = s;
    #pragma unroll
    for (int off = 1; off < 64; off <<= 1) {
        int u = __shfl_up(incl, off);
        if (lane >= off) incl += u;
    }
    __shared__ int wsum[4];
    if (lane == 63) wsum[t >> 6] = incl;
    __syncthreads();
    const int w = t >> 6;
    int woff = 0;
    if (w > 0) woff += wsum[0];
    if (w > 1) woff += wsum[1];
    if (w > 2) woff += wsum[2];
    const int excl = woff + incl - s;
    if (idx + 3 < n) {
        *reinterpret_cast<int4*>(out + idx) =
            make_int4(excl, excl + v.x, excl + v.x + v.y, excl + v.x + v.y + v.z);
    } else {
        if (idx     < n) out[idx]     = excl;
        if (idx + 1 < n) out[idx + 1] = excl + v.x;
        if (idx + 2 < n) out[idx + 2] = excl + v.x + v.y;
        if (idx + 3 < n) out[idx + 3] = excl + v.x + v.y + v.z;
    }
    if (t == 255) bsums[blockIdx.x] = woff + incl;
}

// stage 2: one wave scans the block sums (exclusive, in place)
__global__ __launch_bounds__(64)
void scan_sums(int* __restrict__ bsums, int nb) {
    const int lane = threadIdx.x & 63;
    int carry = 0;
    for (int base = 0; base < nb; base += 64) {
        int v = (base + lane < nb) ? bsums[base + lane] : 0;
        int incl = v;
        #pragma unroll
        for (int off = 1; off < 64; off <<= 1) {
            int u = __shfl_up(incl, off);
            if (lane >= off) incl += u;
        }
        if (base + lane < nb) bsums[base + lane] = carry + incl - v;
        carry += __shfl(incl, 63);
    }
}

// stage 3: finalize row_ptr, norms, and 8 per-copy cursors
// cursor8[c][i] = row_ptr[i] + sum_{c'<c} inc8[c'][i]
__global__ __launch_bounds__(256)
void node_prep_kernel(const int* __restrict__ outc8, const int* __restrict__ inc8,
                      int* __restrict__ row_ptr, const int* __restrict__ bsums,
                      float* __restrict__ out_norm, float* __restrict__ in_norm,
                      int* __restrict__ cursor8, int n, int E) {
    int i = blockIdx.x * 256 + threadIdx.x;
    if (i < n) {
        int od = 0;
        #pragma unroll
        for (int c = 0; c < NCPY; ++c) od += outc8[(size_t)c * n + i];
        int ia[NCPY];
        int id = 0;
        #pragma unroll
        for (int c = 0; c < NCPY; ++c) { ia[c] = inc8[(size_t)c * n + i]; id += ia[c]; }
        int rp = row_ptr[i] + bsums[i >> 10];
        row_ptr[i] = rp;
        int cur = rp;
        #pragma unroll
        for (int c = 0; c < NCPY; ++c) { cursor8[(size_t)c * n + i] = cur; cur += ia[c]; }
        out_norm[i] = rsqrtf((float)max(od, 1));
        in_norm[i]  = rsqrtf((float)max(id, 1));
    }
    if (i == 0) row_ptr[n] = E;   // in-degrees sum to E
}

// counting-sort edges by dst via XCD-local cursor copy
__global__ __launch_bounds__(256)
void scatter_kernel(const int* __restrict__ src, const int* __restrict__ dst,
                    const float* __restrict__ ew, const float* __restrict__ out_norm,
                    int* __restrict__ cursor8, int2* __restrict__ edges,
                    int E, int N) {
    const int copy = blockIdx.x & (NCPY - 1);
    int* cur = cursor8 + (size_t)copy * N;
    int i = blockIdx.x * 256 + threadIdx.x;
    if (i < E) {
        int s = src[i], d = dst[i];
        int pos = atomicAdd(&cur[d], 1);
        edges[pos] = make_int2(s, __float_as_int(ew[i] * out_norm[s]));
    }
}

// ---- fp32 GEMM, Nn == 128 exactly: C[M x 128] = A[M x K] @ B[K x 128] -----
// BM=128 BN=128 BK=16, 256 threads, 8x8 per thread.
// MODE 0: plain store.  MODE 1: relu(acc*rownorm[row] + bias[col]).

template <int MODE>
__global__ __launch_bounds__(256)
void gemm128_f32(const float* __restrict__ A, const float* __restrict__ B,
                 float* __restrict__ C, int M, int K,
                 const float* __restrict__ rownorm, const float* __restrict__ bias) {
    constexpr int BM = 128, BK = 16;
    __shared__ float As[BK][BM];   // k-major (transposed on stage-in)
    __shared__ float Bs[BK][128];

    const int t = threadIdx.x;
    const int row0 = blockIdx.x * BM;
    const int rowbase = (t >> 4) * 8;
    const int colbase = (t & 15) * 8;
    const int ar  = t >> 1;          // A stage-in: row in tile
    const int akq = (t & 1) * 8;     // A stage-in: k offset (8 floats)
    const int bk  = t >> 4;          // B stage-in: k row
    const int bc8 = (t & 15) * 8;    // B stage-in: col offset (8 floats)

    float acc[8][8];
    #pragma unroll
    for (int i = 0; i < 8; ++i)
        #pragma unroll
        for (int j = 0; j < 8; ++j) acc[i][j] = 0.f;

    for (int k0 = 0; k0 < K; k0 += BK) {
        float4 a0 = make_float4(0.f, 0.f, 0.f, 0.f), a1 = a0;
        if (row0 + ar < M) {
            const float* ap = A + (size_t)(row0 + ar) * K + k0 + akq;
            a0 = *reinterpret_cast<const float4*>(ap);
            a1 = *reinterpret_cast<const float4*>(ap + 4);
        }
        const float* bp = B + (size_t)(k0 + bk) * 128 + bc8;
        float4 b0 = *reinterpret_cast<const float4*>(bp);
        float4 b1 = *reinterpret_cast<const float4*>(bp + 4);
        __syncthreads();   // previous iter done reading LDS
        As[akq + 0][ar] = a0.x; As[akq + 1][ar] = a0.y;
        As[akq + 2][ar] = a0.z; As[akq + 3][ar] = a0.w;
        As[akq + 4][ar] = a1.x; As[akq + 5][ar] = a1.y;
        As[akq + 6][ar] = a1.z; As[akq + 7][ar] = a1.w;
        *reinterpret_cast<float4*>(&Bs[bk][bc8])     = b0;
        *reinterpret_cast<float4*>(&Bs[bk][bc8 + 4]) = b1;
        __syncthreads();

        #pragma unroll
        for (int kk = 0; kk < BK; ++kk) {
            float4 av0 = *reinterpret_cast<const float4*>(&As[kk][rowbase]);
            float4 av1 = *reinterpret_cast<const float4*>(&As[kk][rowbase + 4]);
            float4 bv0 = *reinterpret_cast<const float4*>(&Bs[kk][colbase]);
            float4 bv1 = *reinterpret_cast<const float4*>(&Bs[kk][colbase + 4]);
            float a[8] = {av0.x, av0.y, av0.z, av0.w, av1.x, av1.y, av1.z, av1.w};
            float b[8] = {bv0.x, bv0.y, bv0.z, bv0.w, bv1.x, bv1.y, bv1.z, bv1.w};
            #pragma unroll
            for (int i = 0; i < 8; ++i)
                #pragma unroll
                for (int j = 0; j < 8; ++j)
                    acc[i][j] = fmaf(a[i], b[j], acc[i][j]);
        }
    }

    float bb[8];
    if (MODE == 1) {
        float4 b0 = *reinterpret_cast<const float4*>(bias + colbase);
        float4 b1 = *reinterpret_cast<const float4*>(bias + colbase + 4);
        bb[0] = b0.x; bb[1] = b0.y; bb[2] = b0.z; bb[3] = b0.w;
        bb[4] = b1.x; bb[5] = b1.y; bb[6] = b1.z; bb[7] = b1.w;
    }
    #pragma unroll
    for (int i = 0; i < 8; ++i) {
        int row = row0 + rowbase + i;
        if (row >= M) break;
        float v[8];
        #pragma unroll
        for (int j = 0; j < 8; ++j) v[j] = acc[i][j];
        if (MODE == 1) {
            float rn = rownorm[row];
            #pragma unroll
            for (int j = 0; j < 8; ++j) v[j] = fmaxf(fmaf(v[j], rn, bb[j]), 0.f);
        }
        float* cp = C + (size_t)row * 128 + colbase;
        *reinterpret_cast<float4*>(cp)     = make_float4(v[0], v[1], v[2], v[3]);
        *reinterpret_cast<float4*>(cp + 4) = make_float4(v[4], v[5], v[6], v[7]);
    }
}

// ---- fp32 tiled GEMM (generic Nn, layer 3; ldc padded): BM=128 BN=64 BK=16

template <int MODE>
__global__ __launch_bounds__(256)
void gemm_f32(const float* __restrict__ A, const float* __restrict__ B,
              float* __restrict__ C, int M, int Nn, int K,
              int lda, int ldb, int ldc,
              const float* __restrict__ rownorm, const float* __restrict__ bias) {
    constexpr int BM = 128, BN = 64, BK = 16;
    __shared__ float As[BK][BM];
    __shared__ float Bs[BK][BN];

    const int t = threadIdx.x;
    const int row0 = blockIdx.x * BM;
    const int col0 = blockIdx.y * BN;
    const int rowbase = (t >> 4) * 8;
    const int colbase = (t & 15) * 4;
    const int ar  = t >> 1;
    const int akq = (t & 1) * 8;
    const int bk  = t >> 4;
    const int bc4 = (t & 15) * 4;

    float acc[8][4];
    #pragma unroll
    for (int i = 0; i < 8; ++i)
        #pragma unroll
        for (int j = 0; j < 4; ++j) acc[i][j] = 0.f;

    for (int k0 = 0; k0 < K; k0 += BK) {
        float4 a0 = make_float4(0.f, 0.f, 0.f, 0.f), a1 = a0;
        if (row0 + ar < M) {
            const float* ap = A + (size_t)(row0 + ar) * lda + k0 + akq;
            a0 = *reinterpret_cast<const float4*>(ap);
            a1 = *reinterpret_cast<const float4*>(ap + 4);
        }
        float4 bv = make_float4(0.f, 0.f, 0.f, 0.f);
        if (col0 + bc4 < Nn) {
            bv = *reinterpret_cast<const float4*>(B + (size_t)(k0 + bk) * ldb + col0 + bc4);
        }
        __syncthreads();
        As[akq + 0][ar] = a0.x; As[akq + 1][ar] = a0.y;
        As[akq + 2][ar] = a0.z; As[akq + 3][ar] = a0.w;
        As[akq + 4][ar] = a1.x; As[akq + 5][ar] = a1.y;
        As[akq + 6][ar] = a1.z; As[akq + 7][ar] = a1.w;
        *reinterpret_cast<float4*>(&Bs[bk][bc4]) = bv;
        __syncthreads();

        #pragma unroll
        for (int kk = 0; kk < BK; ++kk) {
            float4 av0 = *reinterpret_cast<const float4*>(&As[kk][rowbase]);
            float4 av1 = *reinterpret_cast<const float4*>(&As[kk][rowbase + 4]);
            float4 bv2 = *reinterpret_cast<const float4*>(&Bs[kk][colbase]);
            float a[8] = {av0.x, av0.y, av0.z, av0.w, av1.x, av1.y, av1.z, av1.w};
            float b[4] = {bv2.x, bv2.y, bv2.z, bv2.w};
            #pragma unroll
            for (int i = 0; i < 8; ++i)
                #pragma unroll
                for (int j = 0; j < 4; ++j)
                    acc[i][j] = fmaf(a[i], b[j], acc[i][j]);
        }
    }

    if (col0 + colbase >= Nn) return;
    float4 bb = make_float4(0.f, 0.f, 0.f, 0.f);
    if (MODE == 1) bb = *reinterpret_cast<const float4*>(bias + col0 + colbase);
    #pragma unroll
    for (int i = 0; i < 8; ++i) {
        int row = row0 + rowbase + i;
        if (row >= M) break;
        float4 v = make_float4(acc[i][0], acc[i][1], acc[i][2], acc[i][3]);
        if (MODE == 1) {
            float rn = rownorm[row];
            v.x = fmaxf(fmaf(v.x, rn, bb.x), 0.f);
            v.y = fmaxf(fmaf(v.y, rn, bb.y), 0.f);
            v.z = fmaxf(fmaf(v.z, rn, bb.z), 0.f);
            v.w = fmaxf(fmaf(v.w, rn, bb.w), 0.f);
        }
        *reinterpret_cast<float4*>(C + (size_t)row * ldc + col0 + colbase) = v;
    }
}

// ---- SpMM (CSR by dst), 128 features ---------------------------------------
// One wave per node; FOUR 16-lane quarters process alternate edges (4 gather
// streams, 2 float4 loads each). Packed int2 edge record = single 8B load.

template <int EPI>
__global__ __launch_bounds__(256)
void spmm128(const float* __restrict__ H, const int* __restrict__ row_ptr,
             const int2* __restrict__ edges,
             float* __restrict__ out, const float* __restrict__ in_norm,
             const float* __restrict__ bias, int n) {
    int wid  = (blockIdx.x * 256 + threadIdx.x) >> 6;
    int lane = threadIdx.x & 63;
    if (wid >= n) return;
    const int quarter = lane >> 4;
    const int q       = lane & 15;
    int e0 = row_ptr[wid], e1 = row_ptr[wid + 1];
    float4 acc0 = make_float4(0.f, 0.f, 0.f, 0.f);
    float4 acc1 = make_float4(0.f, 0.f, 0.f, 0.f);
    #pragma unroll 2
    for (int e = e0 + quarter; e < e1; e += 4) {
        int2 er = edges[e];
        int   s = er.x;
        float w = __int_as_float(er.y);
        const float* hp = H + (size_t)s * 128 + q * 4;
        float4 v0 = *reinterpret_cast<const float4*>(hp);
        float4 v1 = *reinterpret_cast<const float4*>(hp + 64);
        acc0.x = fmaf(w, v0.x, acc0.x); acc0.y = fmaf(w, v0.y, acc0.y);
        acc0.z = fmaf(w, v0.z, acc0.z); acc0.w = fmaf(w, v0.w, acc0.w);
        acc1.x = fmaf(w, v1.x, acc1.x); acc1.y = fmaf(w, v1.y, acc1.y);
        acc1.z = fmaf(w, v1.z, acc1.z); acc1.w = fmaf(w, v1.w, acc1.w);
    }
    #pragma unroll
    for (int d = 16; d <= 32; d <<= 1) {
        acc0.x += __shfl_xor(acc0.x, d); acc0.y += __shfl_xor(acc0.y, d);
        acc0.z += __shfl_xor(acc0.z, d); acc0.w += __shfl_xor(acc0.w, d);
        acc1.x += __shfl_xor(acc1.x, d); acc1.y += __shfl_xor(acc1.y, d);
        acc1.z += __shfl_xor(acc1.z, d); acc1.w += __shfl_xor(acc1.w, d);
    }
    if (quarter == 0) {
        if (EPI == 1) {
            float nn = in_norm[wid];
            float4 bb0 = *reinterpret_cast<const float4*>(bias + q * 4);
            float4 bb1 = *reinterpret_cast<const float4*>(bias + 64 + q * 4);
            acc0.x = fmaxf(fmaf(acc0.x, nn, bb0.x), 0.f);
            acc0.y = fmaxf(fmaf(acc0.y, nn, bb0.y), 0.f);
            acc0.z = fmaxf(fmaf(acc0.z, nn, bb0.z), 0.f);
            acc0.w = fmaxf(fmaf(acc0.w, nn, bb0.w), 0.f);
            acc1.x = fmaxf(fmaf(acc1.x, nn, bb1.x), 0.f);
            acc1.y = fmaxf(fmaf(acc1.y, nn, bb1.y), 0.f);
            acc1.z = fmaxf(fmaf(acc1.z, nn, bb1.z), 0.f);
            acc1.w = fmaxf(fmaf(acc1.w, nn, bb1.w), 0.f);
        }
        float* op = out + (size_t)wid * 128 + q * 4;
        *reinterpret_cast<float4*>(op)      = acc0;
        *reinterpret_cast<float4*>(op + 64) = acc1;
    }
}

// ---- SpMM final layer: T3 padded to 64 cols; out is N x 40 -----------------

__global__ __launch_bounds__(256)
void spmm40(const float* __restrict__ H, const int* __restrict__ row_ptr,
            const int2* __restrict__ edges,
            float* __restrict__ out, const float* __restrict__ in_norm,
            const float* __restrict__ bias, int n) {
    int wid  = (blockIdx.x * 256 + threadIdx.x) >> 6;
    int lane = threadIdx.x & 63;
    if (wid >= n) return;
    const int quarter = lane >> 4;
    const int q       = lane & 15;
    int e0 = row_ptr[wid], e1 = row_ptr[wid + 1];
    float4 acc = make_float4(0.f, 0.f, 0.f, 0.f);
    #pragma unroll 2
    for (int e = e0 + quarter; e < e1; e += 4) {
        int2 er = edges[e];
        int   s = er.x;
        float w = __int_as_float(er.y);
        float4 v = *reinterpret_cast<const float4*>(H + (size_t)s * 64 + q * 4);
        acc.x = fmaf(w, v.x, acc.x);
        acc.y = fmaf(w, v.y, acc.y);
        acc.z = fmaf(w, v.z, acc.z);
        acc.w = fmaf(w, v.w, acc.w);
    }
    #pragma unroll
    for (int d = 16; d <= 32; d <<= 1) {
        acc.x += __shfl_xor(acc.x, d);
        acc.y += __shfl_xor(acc.y, d);
        acc.z += __shfl_xor(acc.z, d);
        acc.w += __shfl_xor(acc.w, d);
    }
    if (quarter == 0 && q * 4 < CDIM) {
        float nn = in_norm[wid];
        float4 bb = *reinterpret_cast<const float4*>(bias + q * 4);
        acc.x = fmaf(acc.x, nn, bb.x);
        acc.y = fmaf(acc.y, nn, bb.y);
        acc.z = fmaf(acc.z, nn, bb.z);
        acc.w = fmaf(acc.w, nn, bb.w);
        *reinterpret_cast<float4*>(out + (size_t)wid * CDIM + q * 4) = acc;
    }
}

// ---------------------------------------------------------------------------

extern "C" void kernel_launch(void* const* d_in, const int* in_sizes, int n_in,
                              void* d_out, int out_size, void* d_ws, size_t ws_size,
                              hipStream_t stream) {
    const float* features = (const float*)d_in[0];
    const int*   src      = (const int*)d_in[1];
    const int*   dst      = (const int*)d_in[2];
    const float* ew       = (const float*)d_in[3];
    const float* W1       = (const float*)d_in[4];
    const float* b1       = (const float*)d_in[5];
    const float* W2       = (const float*)d_in[6];
    const float* b2       = (const float*)d_in[7];
    const float* W3       = (const float*)d_in[8];
    const float* b3       = (const float*)d_in[9];
    float* out = (float*)d_out;

    const int N = in_sizes[0] / F_IN;   // 50000
    const int E = in_sizes[1];          // 800000

    // ---- workspace carve-up ----
    char* ws = (char*)d_ws;
    size_t off = 0;
    auto alloc = [&](size_t bytes) -> void* {
        void* p = ws + off;
        off += (bytes + 255) & ~(size_t)255;
        return p;
    };
    int*   deg8     = (int*)alloc((size_t)2 * NCPY * N * 4);  // outc8 | inc8
    int*   outc8    = deg8;
    int*   inc8     = deg8 + (size_t)NCPY * N;
    int*   row_ptr  = (int*)alloc((size_t)(N + 1) * 4);
    int*   cursor8  = (int*)alloc((size_t)NCPY * N * 4);
    float* out_norm = (float*)alloc((size_t)N * 4);
    float* in_norm  = (float*)alloc((size_t)N * 4);
    int2*  edges    = (int2*)alloc((size_t)E * 8);
    float* B0       = (float*)alloc((size_t)N * HDIM * 4);  // T1, later H2
    float* B1       = (float*)alloc((size_t)N * HDIM * 4);  // H1, later padded T3
    float* B2       = (float*)alloc((size_t)N * HDIM * 4);  // A2
    const int nb    = (N + 1023) / 1024;
    int*   bsums    = (int*)alloc((size_t)nb * 4);
    (void)ws_size;

    // ---- preprocessing ----
    hipMemsetAsync(deg8, 0, (size_t)2 * NCPY * N * 4, stream);

    int egrid = (E + 255) / 256;
    degree_kernel<<<egrid, 256, 0, stream>>>(src, dst, outc8, inc8, E, N);
    scan_blocks<<<nb, 256, 0, stream>>>(inc8, row_ptr, bsums, N);
    scan_sums<<<1, 64, 0, stream>>>(bsums, nb);
    int ngrid = (N + 255) / 256;
    node_prep_kernel<<<ngrid, 256, 0, stream>>>(outc8, inc8, row_ptr, bsums,
                                                out_norm, in_norm, cursor8, N, E);
    scatter_kernel<<<egrid, 256, 0, stream>>>(src, dst, ew, out_norm, cursor8,
                                              edges, E, N);

    const int spmm_grid = (N + 3) / 4;   // one wave per node, 4 waves/block

    // ---- layer 1: T1 = X @ W1 ; H1 = relu(SpMM(T1)*in_norm + b1) ----
    {
        dim3 grid((N + 127) / 128);
        gemm128_f32<0><<<grid, 256, 0, stream>>>(features, W1, B0, N, F_IN,
                                                 nullptr, nullptr);
    }
    spmm128<1><<<spmm_grid, 256, 0, stream>>>(B0, row_ptr, edges, B1, in_norm, b1, N);

    // ---- layer 2: A2 = SpMM(H1) ; H2 = relu((A2 @ W2)*in_norm + b2) ----
    spmm128<0><<<spmm_grid, 256, 0, stream>>>(B1, row_ptr, edges, B2, nullptr, nullptr, N);
    {
        dim3 grid((N + 127) / 128);
        gemm128_f32<1><<<grid, 256, 0, stream>>>(B2, W2, B0, N, HDIM, in_norm, b2);
    }

    // ---- layer 3: T3 = H2 @ W3 (ldc=64 padded) ; OUT = SpMM(T3)*in_norm+b3 -
    {
        dim3 grid((N + 127) / 128, 1);
        gemm_f32<0><<<grid, 256, 0, stream>>>(B0, W3, B1, N, CDIM, HDIM,
                                              HDIM, CDIM, 64, nullptr, nullptr);
    }
    spmm40<<<spmm_grid, 256, 0, stream>>>(B1, row_ptr, edges, out, in_norm, b3, N);
}

// Round 7
// 354.375 us; speedup vs baseline: 1.6047x; 1.0087x over previous
//
#include <hip/hip_runtime.h>
#include <hip/hip_bf16.h>
#include <cstdint>

// ---------------------------------------------------------------------------
// GCN 3-layer forward. fp32, CSR-by-dst SpMM (no float atomics).
// Round 7: gemm128 Bs column split 4+4 (colbase, 64+colbase) — kills the
// 4-way LDS bank conflict (was 4.0M conflict cycles/dispatch, LDS-bound).
// ---------------------------------------------------------------------------

#define F_IN 256
#define HDIM 128
#define CDIM 40
#define NCPY 8

// ---- preprocessing ---------------------------------------------------------

// 8-way replicated histogram: copy c = blockIdx & 7 stays XCD-local.
__global__ __launch_bounds__(256)
void degree_kernel(const int* __restrict__ src, const int* __restrict__ dst,
                   int* __restrict__ outc8, int* __restrict__ inc8,
                   int E, int N) {
    const int copy = blockIdx.x & (NCPY - 1);
    int* oc = outc8 + (size_t)copy * N;
    int* ic = inc8  + (size_t)copy * N;
    int i = blockIdx.x * 256 + threadIdx.x;
    if (i < E) {
        atomicAdd(&oc[src[i]], 1);
        atomicAdd(&ic[dst[i]], 1);
    }
}

// stage 1: per-block (1024 elems) exclusive scan of summed inc copies
__global__ __launch_bounds__(256)
void scan_blocks(const int* __restrict__ inc8, int* __restrict__ out,
                 int* __restrict__ bsums, int n) {
    const int t = threadIdx.x;
    const int idx = blockIdx.x * 1024 + t * 4;
    int4 v = make_int4(0, 0, 0, 0);
    if (idx + 3 < n) {
        #pragma unroll
        for (int c = 0; c < NCPY; ++c) {
            int4 u = *reinterpret_cast<const int4*>(inc8 + (size_t)c * n + idx);
            v.x += u.x; v.y += u.y; v.z += u.z; v.w += u.w;
        }
    } else {
        for (int j = 0; j < 4; ++j) {
            if (idx + j < n) {
                int s = 0;
                #pragma unroll
                for (int c = 0; c < NCPY; ++c) s += inc8[(size_t)c * n + idx + j];
                (&v.x)[j] = s;
            }
        }
    }
    const int s = v.x + v.y + v.z + v.w;
    const int lane = t & 63;
    int incl = s;
    #pragma unroll
    for (int off = 1; off < 64; off <<= 1) {
        int u = __shfl_up(incl, off);
        if (lane >= off) incl += u;
    }
    __shared__ int wsum[4];
    if (lane == 63) wsum[t >> 6] = incl;
    __syncthreads();
    const int w = t >> 6;
    int woff = 0;
    if (w > 0) woff += wsum[0];
    if (w > 1) woff += wsum[1];
    if (w > 2) woff += wsum[2];
    const int excl = woff + incl - s;
    if (idx + 3 < n) {
        *reinterpret_cast<int4*>(out + idx) =
            make_int4(excl, excl + v.x, excl + v.x + v.y, excl + v.x + v.y + v.z);
    } else {
        if (idx     < n) out[idx]     = excl;
        if (idx + 1 < n) out[idx + 1] = excl + v.x;
        if (idx + 2 < n) out[idx + 2] = excl + v.x + v.y;
        if (idx + 3 < n) out[idx + 3] = excl + v.x + v.y + v.z;
    }
    if (t == 255) bsums[blockIdx.x] = woff + incl;
}

// stage 2: one wave scans the block sums (exclusive, in place)
__global__ __launch_bounds__(64)
void scan_sums(int* __restrict__ bsums, int nb) {
    const int lane = threadIdx.x & 63;
    int carry = 0;
    for (int base = 0; base < nb; base += 64) {
        int v = (base + lane < nb) ? bsums[base + lane] : 0;
        int incl = v;
        #pragma unroll
        for (int off = 1; off < 64; off <<= 1) {
            int u = __shfl_up(incl, off);
            if (lane >= off) incl += u;
        }
        if (base + lane < nb) bsums[base + lane] = carry + incl - v;
        carry += __shfl(incl, 63);
    }
}

// stage 3: finalize row_ptr, norms, and 8 per-copy cursors
// cursor8[c][i] = row_ptr[i] + sum_{c'<c} inc8[c'][i]
__global__ __launch_bounds__(256)
void node_prep_kernel(const int* __restrict__ outc8, const int* __restrict__ inc8,
                      int* __restrict__ row_ptr, const int* __restrict__ bsums,
                      float* __restrict__ out_norm, float* __restrict__ in_norm,
                      int* __restrict__ cursor8, int n, int E) {
    int i = blockIdx.x * 256 + threadIdx.x;
    if (i < n) {
        int od = 0;
        #pragma unroll
        for (int c = 0; c < NCPY; ++c) od += outc8[(size_t)c * n + i];
        int ia[NCPY];
        int id = 0;
        #pragma unroll
        for (int c = 0; c < NCPY; ++c) { ia[c] = inc8[(size_t)c * n + i]; id += ia[c]; }
        int rp = row_ptr[i] + bsums[i >> 10];
        row_ptr[i] = rp;
        int cur = rp;
        #pragma unroll
        for (int c = 0; c < NCPY; ++c) { cursor8[(size_t)c * n + i] = cur; cur += ia[c]; }
        out_norm[i] = rsqrtf((float)max(od, 1));
        in_norm[i]  = rsqrtf((float)max(id, 1));
    }
    if (i == 0) row_ptr[n] = E;   // in-degrees sum to E
}

// counting-sort edges by dst via XCD-local cursor copy
__global__ __launch_bounds__(256)
void scatter_kernel(const int* __restrict__ src, const int* __restrict__ dst,
                    const float* __restrict__ ew, const float* __restrict__ out_norm,
                    int* __restrict__ cursor8, int2* __restrict__ edges,
                    int E, int N) {
    const int copy = blockIdx.x & (NCPY - 1);
    int* cur = cursor8 + (size_t)copy * N;
    int i = blockIdx.x * 256 + threadIdx.x;
    if (i < E) {
        int s = src[i], d = dst[i];
        int pos = atomicAdd(&cur[d], 1);
        edges[pos] = make_int2(s, __float_as_int(ew[i] * out_norm[s]));
    }
}

// ---- fp32 GEMM, Nn == 128 exactly: C[M x 128] = A[M x K] @ B[K x 128] -----
// BM=128 BN=128 BK=16, 256 threads, 8 rows x (4+4) cols per thread.
// Column blocks at colbase=(t&15)*4 and 64+colbase: each Bs ds_read_b128 has
// 16 lanes covering 256 contiguous bytes -> 2-way bank aliasing (free).
// MODE 0: plain store.  MODE 1: relu(acc*rownorm[row] + bias[col]).

template <int MODE>
__global__ __launch_bounds__(256)
void gemm128_f32(const float* __restrict__ A, const float* __restrict__ B,
                 float* __restrict__ C, int M, int K,
                 const float* __restrict__ rownorm, const float* __restrict__ bias) {
    constexpr int BM = 128, BK = 16;
    __shared__ float As[BK][BM];   // k-major (transposed on stage-in)
    __shared__ float Bs[BK][128];

    const int t = threadIdx.x;
    const int row0 = blockIdx.x * BM;
    const int rowbase = (t >> 4) * 8;
    const int colbase = (t & 15) * 4;     // + second block at 64+colbase
    const int ar  = t >> 1;          // A stage-in: row in tile
    const int akq = (t & 1) * 8;     // A stage-in: k offset (8 floats)
    const int bk  = t >> 4;          // B stage-in: k row
    const int bc8 = (t & 15) * 8;    // B stage-in: col offset (8 floats)

    float acc0[8][4], acc1[8][4];
    #pragma unroll
    for (int i = 0; i < 8; ++i)
        #pragma unroll
        for (int j = 0; j < 4; ++j) { acc0[i][j] = 0.f; acc1[i][j] = 0.f; }

    for (int k0 = 0; k0 < K; k0 += BK) {
        float4 a0 = make_float4(0.f, 0.f, 0.f, 0.f), a1 = a0;
        if (row0 + ar < M) {
            const float* ap = A + (size_t)(row0 + ar) * K + k0 + akq;
            a0 = *reinterpret_cast<const float4*>(ap);
            a1 = *reinterpret_cast<const float4*>(ap + 4);
        }
        const float* bp = B + (size_t)(k0 + bk) * 128 + bc8;
        float4 b0 = *reinterpret_cast<const float4*>(bp);
        float4 b1 = *reinterpret_cast<const float4*>(bp + 4);
        __syncthreads();   // previous iter done reading LDS
        As[akq + 0][ar] = a0.x; As[akq + 1][ar] = a0.y;
        As[akq + 2][ar] = a0.z; As[akq + 3][ar] = a0.w;
        As[akq + 4][ar] = a1.x; As[akq + 5][ar] = a1.y;
        As[akq + 6][ar] = a1.z; As[akq + 7][ar] = a1.w;
        *reinterpret_cast<float4*>(&Bs[bk][bc8])     = b0;
        *reinterpret_cast<float4*>(&Bs[bk][bc8 + 4]) = b1;
        __syncthreads();

        #pragma unroll
        for (int kk = 0; kk < BK; ++kk) {
            float4 av0 = *reinterpret_cast<const float4*>(&As[kk][rowbase]);
            float4 av1 = *reinterpret_cast<const float4*>(&As[kk][rowbase + 4]);
            float4 bv0 = *reinterpret_cast<const float4*>(&Bs[kk][colbase]);
            float4 bv1 = *reinterpret_cast<const float4*>(&Bs[kk][64 + colbase]);
            float a[8] = {av0.x, av0.y, av0.z, av0.w, av1.x, av1.y, av1.z, av1.w};
            float b0a[4] = {bv0.x, bv0.y, bv0.z, bv0.w};
            float b1a[4] = {bv1.x, bv1.y, bv1.z, bv1.w};
            #pragma unroll
            for (int i = 0; i < 8; ++i) {
                #pragma unroll
                for (int j = 0; j < 4; ++j) {
                    acc0[i][j] = fmaf(a[i], b0a[j], acc0[i][j]);
                    acc1[i][j] = fmaf(a[i], b1a[j], acc1[i][j]);
                }
            }
        }
    }

    float4 bb0 = make_float4(0.f, 0.f, 0.f, 0.f), bb1 = bb0;
    if (MODE == 1) {
        bb0 = *reinterpret_cast<const float4*>(bias + colbase);
        bb1 = *reinterpret_cast<const float4*>(bias + 64 + colbase);
    }
    #pragma unroll
    for (int i = 0; i < 8; ++i) {
        int row = row0 + rowbase + i;
        if (row >= M) break;
        float4 v0 = make_float4(acc0[i][0], acc0[i][1], acc0[i][2], acc0[i][3]);
        float4 v1 = make_float4(acc1[i][0], acc1[i][1], acc1[i][2], acc1[i][3]);
        if (MODE == 1) {
            float rn = rownorm[row];
            v0.x = fmaxf(fmaf(v0.x, rn, bb0.x), 0.f);
            v0.y = fmaxf(fmaf(v0.y, rn, bb0.y), 0.f);
            v0.z = fmaxf(fmaf(v0.z, rn, bb0.z), 0.f);
            v0.w = fmaxf(fmaf(v0.w, rn, bb0.w), 0.f);
            v1.x = fmaxf(fmaf(v1.x, rn, bb1.x), 0.f);
            v1.y = fmaxf(fmaf(v1.y, rn, bb1.y), 0.f);
            v1.z = fmaxf(fmaf(v1.z, rn, bb1.z), 0.f);
            v1.w = fmaxf(fmaf(v1.w, rn, bb1.w), 0.f);
        }
        float* cp = C + (size_t)row * 128 + colbase;
        *reinterpret_cast<float4*>(cp)      = v0;
        *reinterpret_cast<float4*>(cp + 64) = v1;
    }
}

// ---- fp32 tiled GEMM (generic Nn, layer 3; ldc padded): BM=128 BN=64 BK=16

template <int MODE>
__global__ __launch_bounds__(256)
void gemm_f32(const float* __restrict__ A, const float* __restrict__ B,
              float* __restrict__ C, int M, int Nn, int K,
              int lda, int ldb, int ldc,
              const float* __restrict__ rownorm, const float* __restrict__ bias) {
    constexpr int BM = 128, BN = 64, BK = 16;
    __shared__ float As[BK][BM];
    __shared__ float Bs[BK][BN];

    const int t = threadIdx.x;
    const int row0 = blockIdx.x * BM;
    const int col0 = blockIdx.y * BN;
    const int rowbase = (t >> 4) * 8;
    const int colbase = (t & 15) * 4;
    const int ar  = t >> 1;
    const int akq = (t & 1) * 8;
    const int bk  = t >> 4;
    const int bc4 = (t & 15) * 4;

    float acc[8][4];
    #pragma unroll
    for (int i = 0; i < 8; ++i)
        #pragma unroll
        for (int j = 0; j < 4; ++j) acc[i][j] = 0.f;

    for (int k0 = 0; k0 < K; k0 += BK) {
        float4 a0 = make_float4(0.f, 0.f, 0.f, 0.f), a1 = a0;
        if (row0 + ar < M) {
            const float* ap = A + (size_t)(row0 + ar) * lda + k0 + akq;
            a0 = *reinterpret_cast<const float4*>(ap);
            a1 = *reinterpret_cast<const float4*>(ap + 4);
        }
        float4 bv = make_float4(0.f, 0.f, 0.f, 0.f);
        if (col0 + bc4 < Nn) {
            bv = *reinterpret_cast<const float4*>(B + (size_t)(k0 + bk) * ldb + col0 + bc4);
        }
        __syncthreads();
        As[akq + 0][ar] = a0.x; As[akq + 1][ar] = a0.y;
        As[akq + 2][ar] = a0.z; As[akq + 3][ar] = a0.w;
        As[akq + 4][ar] = a1.x; As[akq + 5][ar] = a1.y;
        As[akq + 6][ar] = a1.z; As[akq + 7][ar] = a1.w;
        *reinterpret_cast<float4*>(&Bs[bk][bc4]) = bv;
        __syncthreads();

        #pragma unroll
        for (int kk = 0; kk < BK; ++kk) {
            float4 av0 = *reinterpret_cast<const float4*>(&As[kk][rowbase]);
            float4 av1 = *reinterpret_cast<const float4*>(&As[kk][rowbase + 4]);
            float4 bv2 = *reinterpret_cast<const float4*>(&Bs[kk][colbase]);
            float a[8] = {av0.x, av0.y, av0.z, av0.w, av1.x, av1.y, av1.z, av1.w};
            float b[4] = {bv2.x, bv2.y, bv2.z, bv2.w};
            #pragma unroll
            for (int i = 0; i < 8; ++i)
                #pragma unroll
                for (int j = 0; j < 4; ++j)
                    acc[i][j] = fmaf(a[i], b[j], acc[i][j]);
        }
    }

    if (col0 + colbase >= Nn) return;
    float4 bb = make_float4(0.f, 0.f, 0.f, 0.f);
    if (MODE == 1) bb = *reinterpret_cast<const float4*>(bias + col0 + colbase);
    #pragma unroll
    for (int i = 0; i < 8; ++i) {
        int row = row0 + rowbase + i;
        if (row >= M) break;
        float4 v = make_float4(acc[i][0], acc[i][1], acc[i][2], acc[i][3]);
        if (MODE == 1) {
            float rn = rownorm[row];
            v.x = fmaxf(fmaf(v.x, rn, bb.x), 0.f);
            v.y = fmaxf(fmaf(v.y, rn, bb.y), 0.f);
            v.z = fmaxf(fmaf(v.z, rn, bb.z), 0.f);
            v.w = fmaxf(fmaf(v.w, rn, bb.w), 0.f);
        }
        *reinterpret_cast<float4*>(C + (size_t)row * ldc + col0 + colbase) = v;
    }
}

// ---- SpMM (CSR by dst), 128 features ---------------------------------------
// One wave per node; FOUR 16-lane quarters process alternate edges (4 gather
// streams, 2 float4 loads each). Packed int2 edge record = single 8B load.

template <int EPI>
__global__ __launch_bounds__(256)
void spmm128(const float* __restrict__ H, const int* __restrict__ row_ptr,
             const int2* __restrict__ edges,
             float* __restrict__ out, const float* __restrict__ in_norm,
             const float* __restrict__ bias, int n) {
    int wid  = (blockIdx.x * 256 + threadIdx.x) >> 6;
    int lane = threadIdx.x & 63;
    if (wid >= n) return;
    const int quarter = lane >> 4;
    const int q       = lane & 15;
    int e0 = row_ptr[wid], e1 = row_ptr[wid + 1];
    float4 acc0 = make_float4(0.f, 0.f, 0.f, 0.f);
    float4 acc1 = make_float4(0.f, 0.f, 0.f, 0.f);
    #pragma unroll 2
    for (int e = e0 + quarter; e < e1; e += 4) {
        int2 er = edges[e];
        int   s = er.x;
        float w = __int_as_float(er.y);
        const float* hp = H + (size_t)s * 128 + q * 4;
        float4 v0 = *reinterpret_cast<const float4*>(hp);
        float4 v1 = *reinterpret_cast<const float4*>(hp + 64);
        acc0.x = fmaf(w, v0.x, acc0.x); acc0.y = fmaf(w, v0.y, acc0.y);
        acc0.z = fmaf(w, v0.z, acc0.z); acc0.w = fmaf(w, v0.w, acc0.w);
        acc1.x = fmaf(w, v1.x, acc1.x); acc1.y = fmaf(w, v1.y, acc1.y);
        acc1.z = fmaf(w, v1.z, acc1.z); acc1.w = fmaf(w, v1.w, acc1.w);
    }
    #pragma unroll
    for (int d = 16; d <= 32; d <<= 1) {
        acc0.x += __shfl_xor(acc0.x, d); acc0.y += __shfl_xor(acc0.y, d);
        acc0.z += __shfl_xor(acc0.z, d); acc0.w += __shfl_xor(acc0.w, d);
        acc1.x += __shfl_xor(acc1.x, d); acc1.y += __shfl_xor(acc1.y, d);
        acc1.z += __shfl_xor(acc1.z, d); acc1.w += __shfl_xor(acc1.w, d);
    }
    if (quarter == 0) {
        if (EPI == 1) {
            float nn = in_norm[wid];
            float4 bb0 = *reinterpret_cast<const float4*>(bias + q * 4);
            float4 bb1 = *reinterpret_cast<const float4*>(bias + 64 + q * 4);
            acc0.x = fmaxf(fmaf(acc0.x, nn, bb0.x), 0.f);
            acc0.y = fmaxf(fmaf(acc0.y, nn, bb0.y), 0.f);
            acc0.z = fmaxf(fmaf(acc0.z, nn, bb0.z), 0.f);
            acc0.w = fmaxf(fmaf(acc0.w, nn, bb0.w), 0.f);
            acc1.x = fmaxf(fmaf(acc1.x, nn, bb1.x), 0.f);
            acc1.y = fmaxf(fmaf(acc1.y, nn, bb1.y), 0.f);
            acc1.z = fmaxf(fmaf(acc1.z, nn, bb1.z), 0.f);
            acc1.w = fmaxf(fmaf(acc1.w, nn, bb1.w), 0.f);
        }
        float* op = out + (size_t)wid * 128 + q * 4;
        *reinterpret_cast<float4*>(op)      = acc0;
        *reinterpret_cast<float4*>(op + 64) = acc1;
    }
}

// ---- SpMM final layer: T3 padded to 64 cols; out is N x 40 -----------------

__global__ __launch_bounds__(256)
void spmm40(const float* __restrict__ H, const int* __restrict__ row_ptr,
            const int2* __restrict__ edges,
            float* __restrict__ out, const float* __restrict__ in_norm,
            const float* __restrict__ bias, int n) {
    int wid  = (blockIdx.x * 256 + threadIdx.x) >> 6;
    int lane = threadIdx.x & 63;
    if (wid >= n) return;
    const int quarter = lane >> 4;
    const int q       = lane & 15;
    int e0 = row_ptr[wid], e1 = row_ptr[wid + 1];
    float4 acc = make_float4(0.f, 0.f, 0.f, 0.f);
    #pragma unroll 2
    for (int e = e0 + quarter; e < e1; e += 4) {
        int2 er = edges[e];
        int   s = er.x;
        float w = __int_as_float(er.y);
        float4 v = *reinterpret_cast<const float4*>(H + (size_t)s * 64 + q * 4);
        acc.x = fmaf(w, v.x, acc.x);
        acc.y = fmaf(w, v.y, acc.y);
        acc.z = fmaf(w, v.z, acc.z);
        acc.w = fmaf(w, v.w, acc.w);
    }
    #pragma unroll
    for (int d = 16; d <= 32; d <<= 1) {
        acc.x += __shfl_xor(acc.x, d);
        acc.y += __shfl_xor(acc.y, d);
        acc.z += __shfl_xor(acc.z, d);
        acc.w += __shfl_xor(acc.w, d);
    }
    if (quarter == 0 && q * 4 < CDIM) {
        float nn = in_norm[wid];
        float4 bb = *reinterpret_cast<const float4*>(bias + q * 4);
        acc.x = fmaf(acc.x, nn, bb.x);
        acc.y = fmaf(acc.y, nn, bb.y);
        acc.z = fmaf(acc.z, nn, bb.z);
        acc.w = fmaf(acc.w, nn, bb.w);
        *reinterpret_cast<float4*>(out + (size_t)wid * CDIM + q * 4) = acc;
    }
}

// ---------------------------------------------------------------------------

extern "C" void kernel_launch(void* const* d_in, const int* in_sizes, int n_in,
                              void* d_out, int out_size, void* d_ws, size_t ws_size,
                              hipStream_t stream) {
    const float* features = (const float*)d_in[0];
    const int*   src      = (const int*)d_in[1];
    const int*   dst      = (const int*)d_in[2];
    const float* ew       = (const float*)d_in[3];
    const float* W1       = (const float*)d_in[4];
    const float* b1       = (const float*)d_in[5];
    const float* W2       = (const float*)d_in[6];
    const float* b2       = (const float*)d_in[7];
    const float* W3       = (const float*)d_in[8];
    const float* b3       = (const float*)d_in[9];
    float* out = (float*)d_out;

    const int N = in_sizes[0] / F_IN;   // 50000
    const int E = in_sizes[1];          // 800000

    // ---- workspace carve-up ----
    char* ws = (char*)d_ws;
    size_t off = 0;
    auto alloc = [&](size_t bytes) -> void* {
        void* p = ws + off;
        off += (bytes + 255) & ~(size_t)255;
        return p;
    };
    int*   deg8     = (int*)alloc((size_t)2 * NCPY * N * 4);  // outc8 | inc8
    int*   outc8    = deg8;
    int*   inc8     = deg8 + (size_t)NCPY * N;
    int*   row_ptr  = (int*)alloc((size_t)(N + 1) * 4);
    int*   cursor8  = (int*)alloc((size_t)NCPY * N * 4);
    float* out_norm = (float*)alloc((size_t)N * 4);
    float* in_norm  = (float*)alloc((size_t)N * 4);
    int2*  edges    = (int2*)alloc((size_t)E * 8);
    float* B0       = (float*)alloc((size_t)N * HDIM * 4);  // T1, later H2
    float* B1       = (float*)alloc((size_t)N * HDIM * 4);  // H1, later padded T3
    float* B2       = (float*)alloc((size_t)N * HDIM * 4);  // A2
    const int nb    = (N + 1023) / 1024;
    int*   bsums    = (int*)alloc((size_t)nb * 4);
    (void)ws_size;

    // ---- preprocessing ----
    hipMemsetAsync(deg8, 0, (size_t)2 * NCPY * N * 4, stream);

    int egrid = (E + 255) / 256;
    degree_kernel<<<egrid, 256, 0, stream>>>(src, dst, outc8, inc8, E, N);
    scan_blocks<<<nb, 256, 0, stream>>>(inc8, row_ptr, bsums, N);
    scan_sums<<<1, 64, 0, stream>>>(bsums, nb);
    int ngrid = (N + 255) / 256;
    node_prep_kernel<<<ngrid, 256, 0, stream>>>(outc8, inc8, row_ptr, bsums,
                                                out_norm, in_norm, cursor8, N, E);
    scatter_kernel<<<egrid, 256, 0, stream>>>(src, dst, ew, out_norm, cursor8,
                                              edges, E, N);

    const int spmm_grid = (N + 3) / 4;   // one wave per node, 4 waves/block

    // ---- layer 1: T1 = X @ W1 ; H1 = relu(SpMM(T1)*in_norm + b1) ----
    {
        dim3 grid((N + 127) / 128);
        gemm128_f32<0><<<grid, 256, 0, stream>>>(features, W1, B0, N, F_IN,
                                                 nullptr, nullptr);
    }
    spmm128<1><<<spmm_grid, 256, 0, stream>>>(B0, row_ptr, edges, B1, in_norm, b1, N);

    // ---- layer 2: A2 = SpMM(H1) ; H2 = relu((A2 @ W2)*in_norm + b2) ----
    spmm128<0><<<spmm_grid, 256, 0, stream>>>(B1, row_ptr, edges, B2, nullptr, nullptr, N);
    {
        dim3 grid((N + 127) / 128);
        gemm128_f32<1><<<grid, 256, 0, stream>>>(B2, W2, B0, N, HDIM, in_norm, b2);
    }

    // ---- layer 3: T3 = H2 @ W3 (ldc=64 padded) ; OUT = SpMM(T3)*in_norm+b3 -
    {
        dim3 grid((N + 127) / 128, 1);
        gemm_f32<0><<<grid, 256, 0, stream>>>(B0, W3, B1, N, CDIM, HDIM,
                                              HDIM, CDIM, 64, nullptr, nullptr);
    }
    spmm40<<<spmm_grid, 256, 0, stream>>>(B1, row_ptr, edges, out, in_norm, b3, N);
}

// Round 8
// 320.132 us; speedup vs baseline: 1.7763x; 1.1070x over previous
//
#include <hip/hip_runtime.h>
#include <hip/hip_bf16.h>
#include <cstdint>

// ---------------------------------------------------------------------------
// GCN 3-layer forward. fp32, CSR-by-dst SpMM.
// Round 8: preprocessing with ZERO global atomics. Device-scope atomics on
// gfx950 execute memory-side (~32B write each; r6/r7 counters: WRITE_SIZE
// tracks atomic count, not footprint). Replaced with node-range partitioned
// LDS histograms + per-(range,subset) cursor blocks.
// ---------------------------------------------------------------------------

#define F_IN 256
#define HDIM 128
#define CDIM 40
#define RBITS 12
#define RSIZE 4096          // nodes per range (16KB LDS of int)
#define NSUB 16             // edge-chunk subsets

// ---- stage 1: per-(range,subset) LDS histograms of src and dst -------------
__global__ __launch_bounds__(256)
void histo_range(const int* __restrict__ src, const int* __restrict__ dst,
                 int* __restrict__ pcin, int* __restrict__ pcout, int E) {
    __shared__ int hin[RSIZE];
    __shared__ int hout[RSIZE];
    const int s = blockIdx.x;          // subset
    const int r = blockIdx.y;          // node range
    const int base = r << RBITS;
    const int t = threadIdx.x;
    for (int j = t; j < RSIZE; j += 256) { hin[j] = 0; hout[j] = 0; }
    __syncthreads();

    const int ech = (E + NSUB - 1) / NSUB;
    const int e0 = s * ech;
    const int e1 = min(E, e0 + ech);
    const int n4 = (e1 - e0) >> 2;
    for (int g = t; g < n4; g += 256) {
        int4 d4 = *reinterpret_cast<const int4*>(dst + e0 + g * 4);
        int4 s4 = *reinterpret_cast<const int4*>(src + e0 + g * 4);
        #pragma unroll
        for (int j = 0; j < 4; ++j) {
            int d = (&d4.x)[j] - base;
            int v = (&s4.x)[j] - base;
            if ((unsigned)d < RSIZE) atomicAdd(&hin[d], 1);
            if ((unsigned)v < RSIZE) atomicAdd(&hout[v], 1);
        }
    }
    for (int e = e0 + n4 * 4 + t; e < e1; e += 256) {
        int d = dst[e] - base, v = src[e] - base;
        if ((unsigned)d < RSIZE) atomicAdd(&hin[d], 1);
        if ((unsigned)v < RSIZE) atomicAdd(&hout[v], 1);
    }
    __syncthreads();
    int* pin  = pcin  + ((size_t)r * NSUB + s) * RSIZE;
    int* pout = pcout + ((size_t)r * NSUB + s) * RSIZE;
    for (int j = t; j < RSIZE; j += 256) { pin[j] = hin[j]; pout[j] = hout[j]; }
}

// ---- stage 2: block-level exclusive scan of in-degree (summed partials) ----
__global__ __launch_bounds__(256)
void scan_blocks(const int* __restrict__ pcin, int* __restrict__ out,
                 int* __restrict__ bsums, int n) {
    const int t = threadIdx.x;
    const int idx = blockIdx.x * 1024 + t * 4;
    int4 v = make_int4(0, 0, 0, 0);
    if (idx + 3 < n) {
        const int r = idx >> RBITS, off = idx & (RSIZE - 1);
        const int* p = pcin + (size_t)r * NSUB * RSIZE + off;
        #pragma unroll
        for (int c = 0; c < NSUB; ++c) {
            int4 u = *reinterpret_cast<const int4*>(p + (size_t)c * RSIZE);
            v.x += u.x; v.y += u.y; v.z += u.z; v.w += u.w;
        }
    } else {
        for (int j = 0; j < 4; ++j) {
            if (idx + j < n) {
                const int r = (idx + j) >> RBITS, off = (idx + j) & (RSIZE - 1);
                int s = 0;
                #pragma unroll
                for (int c = 0; c < NSUB; ++c)
                    s += pcin[(size_t)r * NSUB * RSIZE + (size_t)c * RSIZE + off];
                (&v.x)[j] = s;
            }
        }
    }
    const int s = v.x + v.y + v.z + v.w;
    const int lane = t & 63;
    int incl = s;
    #pragma unroll
    for (int off = 1; off < 64; off <<= 1) {
        int u = __shfl_up(incl, off);
        if (lane >= off) incl += u;
    }
    __shared__ int wsum[4];
    if (lane == 63) wsum[t >> 6] = incl;
    __syncthreads();
    const int w = t >> 6;
    int woff = 0;
    if (w > 0) woff += wsum[0];
    if (w > 1) woff += wsum[1];
    if (w > 2) woff += wsum[2];
    const int excl = woff + incl - s;
    if (idx + 3 < n) {
        *reinterpret_cast<int4*>(out + idx) =
            make_int4(excl, excl + v.x, excl + v.x + v.y, excl + v.x + v.y + v.z);
    } else {
        if (idx     < n) out[idx]     = excl;
        if (idx + 1 < n) out[idx + 1] = excl + v.x;
        if (idx + 2 < n) out[idx + 2] = excl + v.x + v.y;
        if (idx + 3 < n) out[idx + 3] = excl + v.x + v.y + v.z;
    }
    if (t == 255) bsums[blockIdx.x] = woff + incl;
}

__global__ __launch_bounds__(64)
void scan_sums(int* __restrict__ bsums, int nb) {
    const int lane = threadIdx.x & 63;
    int carry = 0;
    for (int base = 0; base < nb; base += 64) {
        int v = (base + lane < nb) ? bsums[base + lane] : 0;
        int incl = v;
        #pragma unroll
        for (int off = 1; off < 64; off <<= 1) {
            int u = __shfl_up(incl, off);
            if (lane >= off) incl += u;
        }
        if (base + lane < nb) bsums[base + lane] = carry + incl - v;
        carry += __shfl(incl, 63);
    }
}

// ---- stage 3: finalize row_ptr, norms, per-subset cursor bases cb ----------
__global__ __launch_bounds__(256)
void node_prep_kernel(const int* __restrict__ pcin, const int* __restrict__ pcout,
                      int* __restrict__ row_ptr, const int* __restrict__ bsums,
                      float* __restrict__ out_norm, float* __restrict__ in_norm,
                      int* __restrict__ cb, int n, int E) {
    int i = blockIdx.x * 256 + threadIdx.x;
    if (i < n) {
        const int r = i >> RBITS, off = i & (RSIZE - 1);
        const int* pi = pcin  + (size_t)r * NSUB * RSIZE + off;
        const int* po = pcout + (size_t)r * NSUB * RSIZE + off;
        int od = 0, id = 0;
        int ia[NSUB];
        #pragma unroll
        for (int c = 0; c < NSUB; ++c) {
            ia[c] = pi[(size_t)c * RSIZE];
            id += ia[c];
            od += po[(size_t)c * RSIZE];
        }
        int rp = row_ptr[i] + bsums[i >> 10];
        row_ptr[i] = rp;
        int cur = rp;
        #pragma unroll
        for (int c = 0; c < NSUB; ++c) { cb[(size_t)c * n + i] = cur; cur += ia[c]; }
        out_norm[i] = rsqrtf((float)max(od, 1));
        in_norm[i]  = rsqrtf((float)max(id, 1));
    }
    if (i == 0) row_ptr[n] = E;
}

// ---- stage 4: scatter via LDS cursors (zero global atomics) ----------------
__global__ __launch_bounds__(256)
void scatter_range(const int* __restrict__ src, const int* __restrict__ dst,
                   const float* __restrict__ ew, const float* __restrict__ out_norm,
                   const int* __restrict__ cb, int2* __restrict__ edges,
                   int E, int N) {
    __shared__ int cur[RSIZE];
    const int s = blockIdx.x;
    const int r = blockIdx.y;
    const int base = r << RBITS;
    const int t = threadIdx.x;
    for (int j = t; j < RSIZE; j += 256)
        if (base + j < N) cur[j] = cb[(size_t)s * N + base + j];
    __syncthreads();

    const int ech = (E + NSUB - 1) / NSUB;
    const int e0 = s * ech;
    const int e1 = min(E, e0 + ech);
    const int n4 = (e1 - e0) >> 2;
    for (int g = t; g < n4; g += 256) {
        int4 d4 = *reinterpret_cast<const int4*>(dst + e0 + g * 4);
        int4 s4 = *reinterpret_cast<const int4*>(src + e0 + g * 4);
        float4 w4 = *reinterpret_cast<const float4*>(ew + e0 + g * 4);
        #pragma unroll
        for (int j = 0; j < 4; ++j) {
            int d = (&d4.x)[j] - base;
            if ((unsigned)d < RSIZE) {
                int sv = (&s4.x)[j];
                int pos = atomicAdd(&cur[d], 1);
                float w = (&w4.x)[j] * out_norm[sv];
                edges[pos] = make_int2(sv, __float_as_int(w));
            }
        }
    }
    for (int e = e0 + n4 * 4 + t; e < e1; e += 256) {
        int d = dst[e] - base;
        if ((unsigned)d < RSIZE) {
            int sv = src[e];
            int pos = atomicAdd(&cur[d], 1);
            float w = ew[e] * out_norm[sv];
            edges[pos] = make_int2(sv, __float_as_int(w));
        }
    }
}

// ---- fp32 GEMM, Nn == 128 exactly (BM=128 BN=128 BK=16, 8x(4+4)/thread) ----
template <int MODE>
__global__ __launch_bounds__(256)
void gemm128_f32(const float* __restrict__ A, const float* __restrict__ B,
                 float* __restrict__ C, int M, int K,
                 const float* __restrict__ rownorm, const float* __restrict__ bias) {
    constexpr int BM = 128, BK = 16;
    __shared__ float As[BK][BM];
    __shared__ float Bs[BK][128];

    const int t = threadIdx.x;
    const int row0 = blockIdx.x * BM;
    const int rowbase = (t >> 4) * 8;
    const int colbase = (t & 15) * 4;
    const int ar  = t >> 1;
    const int akq = (t & 1) * 8;
    const int bk  = t >> 4;
    const int bc8 = (t & 15) * 8;

    float acc0[8][4], acc1[8][4];
    #pragma unroll
    for (int i = 0; i < 8; ++i)
        #pragma unroll
        for (int j = 0; j < 4; ++j) { acc0[i][j] = 0.f; acc1[i][j] = 0.f; }

    for (int k0 = 0; k0 < K; k0 += BK) {
        float4 a0 = make_float4(0.f, 0.f, 0.f, 0.f), a1 = a0;
        if (row0 + ar < M) {
            const float* ap = A + (size_t)(row0 + ar) * K + k0 + akq;
            a0 = *reinterpret_cast<const float4*>(ap);
            a1 = *reinterpret_cast<const float4*>(ap + 4);
        }
        const float* bp = B + (size_t)(k0 + bk) * 128 + bc8;
        float4 b0 = *reinterpret_cast<const float4*>(bp);
        float4 b1 = *reinterpret_cast<const float4*>(bp + 4);
        __syncthreads();
        As[akq + 0][ar] = a0.x; As[akq + 1][ar] = a0.y;
        As[akq + 2][ar] = a0.z; As[akq + 3][ar] = a0.w;
        As[akq + 4][ar] = a1.x; As[akq + 5][ar] = a1.y;
        As[akq + 6][ar] = a1.z; As[akq + 7][ar] = a1.w;
        *reinterpret_cast<float4*>(&Bs[bk][bc8])     = b0;
        *reinterpret_cast<float4*>(&Bs[bk][bc8 + 4]) = b1;
        __syncthreads();

        #pragma unroll
        for (int kk = 0; kk < BK; ++kk) {
            float4 av0 = *reinterpret_cast<const float4*>(&As[kk][rowbase]);
            float4 av1 = *reinterpret_cast<const float4*>(&As[kk][rowbase + 4]);
            float4 bv0 = *reinterpret_cast<const float4*>(&Bs[kk][colbase]);
            float4 bv1 = *reinterpret_cast<const float4*>(&Bs[kk][64 + colbase]);
            float a[8] = {av0.x, av0.y, av0.z, av0.w, av1.x, av1.y, av1.z, av1.w};
            float b0a[4] = {bv0.x, bv0.y, bv0.z, bv0.w};
            float b1a[4] = {bv1.x, bv1.y, bv1.z, bv1.w};
            #pragma unroll
            for (int i = 0; i < 8; ++i) {
                #pragma unroll
                for (int j = 0; j < 4; ++j) {
                    acc0[i][j] = fmaf(a[i], b0a[j], acc0[i][j]);
                    acc1[i][j] = fmaf(a[i], b1a[j], acc1[i][j]);
                }
            }
        }
    }

    float4 bb0 = make_float4(0.f, 0.f, 0.f, 0.f), bb1 = bb0;
    if (MODE == 1) {
        bb0 = *reinterpret_cast<const float4*>(bias + colbase);
        bb1 = *reinterpret_cast<const float4*>(bias + 64 + colbase);
    }
    #pragma unroll
    for (int i = 0; i < 8; ++i) {
        int row = row0 + rowbase + i;
        if (row >= M) break;
        float4 v0 = make_float4(acc0[i][0], acc0[i][1], acc0[i][2], acc0[i][3]);
        float4 v1 = make_float4(acc1[i][0], acc1[i][1], acc1[i][2], acc1[i][3]);
        if (MODE == 1) {
            float rn = rownorm[row];
            v0.x = fmaxf(fmaf(v0.x, rn, bb0.x), 0.f);
            v0.y = fmaxf(fmaf(v0.y, rn, bb0.y), 0.f);
            v0.z = fmaxf(fmaf(v0.z, rn, bb0.z), 0.f);
            v0.w = fmaxf(fmaf(v0.w, rn, bb0.w), 0.f);
            v1.x = fmaxf(fmaf(v1.x, rn, bb1.x), 0.f);
            v1.y = fmaxf(fmaf(v1.y, rn, bb1.y), 0.f);
            v1.z = fmaxf(fmaf(v1.z, rn, bb1.z), 0.f);
            v1.w = fmaxf(fmaf(v1.w, rn, bb1.w), 0.f);
        }
        float* cp = C + (size_t)row * 128 + colbase;
        *reinterpret_cast<float4*>(cp)      = v0;
        *reinterpret_cast<float4*>(cp + 64) = v1;
    }
}

// ---- fp32 tiled GEMM (generic Nn, layer 3; ldc padded): BM=128 BN=64 BK=16
template <int MODE>
__global__ __launch_bounds__(256)
void gemm_f32(const float* __restrict__ A, const float* __restrict__ B,
              float* __restrict__ C, int M, int Nn, int K,
              int lda, int ldb, int ldc,
              const float* __restrict__ rownorm, const float* __restrict__ bias) {
    constexpr int BM = 128, BN = 64, BK = 16;
    __shared__ float As[BK][BM];
    __shared__ float Bs[BK][BN];

    const int t = threadIdx.x;
    const int row0 = blockIdx.x * BM;
    const int col0 = blockIdx.y * BN;
    const int rowbase = (t >> 4) * 8;
    const int colbase = (t & 15) * 4;
    const int ar  = t >> 1;
    const int akq = (t & 1) * 8;
    const int bk  = t >> 4;
    const int bc4 = (t & 15) * 4;

    float acc[8][4];
    #pragma unroll
    for (int i = 0; i < 8; ++i)
        #pragma unroll
        for (int j = 0; j < 4; ++j) acc[i][j] = 0.f;

    for (int k0 = 0; k0 < K; k0 += BK) {
        float4 a0 = make_float4(0.f, 0.f, 0.f, 0.f), a1 = a0;
        if (row0 + ar < M) {
            const float* ap = A + (size_t)(row0 + ar) * lda + k0 + akq;
            a0 = *reinterpret_cast<const float4*>(ap);
            a1 = *reinterpret_cast<const float4*>(ap + 4);
        }
        float4 bv = make_float4(0.f, 0.f, 0.f, 0.f);
        if (col0 + bc4 < Nn) {
            bv = *reinterpret_cast<const float4*>(B + (size_t)(k0 + bk) * ldb + col0 + bc4);
        }
        __syncthreads();
        As[akq + 0][ar] = a0.x; As[akq + 1][ar] = a0.y;
        As[akq + 2][ar] = a0.z; As[akq + 3][ar] = a0.w;
        As[akq + 4][ar] = a1.x; As[akq + 5][ar] = a1.y;
        As[akq + 6][ar] = a1.z; As[akq + 7][ar] = a1.w;
        *reinterpret_cast<float4*>(&Bs[bk][bc4]) = bv;
        __syncthreads();

        #pragma unroll
        for (int kk = 0; kk < BK; ++kk) {
            float4 av0 = *reinterpret_cast<const float4*>(&As[kk][rowbase]);
            float4 av1 = *reinterpret_cast<const float4*>(&As[kk][rowbase + 4]);
            float4 bv2 = *reinterpret_cast<const float4*>(&Bs[kk][colbase]);
            float a[8] = {av0.x, av0.y, av0.z, av0.w, av1.x, av1.y, av1.z, av1.w};
            float b[4] = {bv2.x, bv2.y, bv2.z, bv2.w};
            #pragma unroll
            for (int i = 0; i < 8; ++i)
                #pragma unroll
                for (int j = 0; j < 4; ++j)
                    acc[i][j] = fmaf(a[i], b[j], acc[i][j]);
        }
    }

    if (col0 + colbase >= Nn) return;
    float4 bb = make_float4(0.f, 0.f, 0.f, 0.f);
    if (MODE == 1) bb = *reinterpret_cast<const float4*>(bias + col0 + colbase);
    #pragma unroll
    for (int i = 0; i < 8; ++i) {
        int row = row0 + rowbase + i;
        if (row >= M) break;
        float4 v = make_float4(acc[i][0], acc[i][1], acc[i][2], acc[i][3]);
        if (MODE == 1) {
            float rn = rownorm[row];
            v.x = fmaxf(fmaf(v.x, rn, bb.x), 0.f);
            v.y = fmaxf(fmaf(v.y, rn, bb.y), 0.f);
            v.z = fmaxf(fmaf(v.z, rn, bb.z), 0.f);
            v.w = fmaxf(fmaf(v.w, rn, bb.w), 0.f);
        }
        *reinterpret_cast<float4*>(C + (size_t)row * ldc + col0 + colbase) = v;
    }
}

// ---- SpMM (CSR by dst), 128 features: 4x16-lane edge streams ---------------
template <int EPI>
__global__ __launch_bounds__(256)
void spmm128(const float* __restrict__ H, const int* __restrict__ row_ptr,
             const int2* __restrict__ edges,
             float* __restrict__ out, const float* __restrict__ in_norm,
             const float* __restrict__ bias, int n) {
    int wid  = (blockIdx.x * 256 + threadIdx.x) >> 6;
    int lane = threadIdx.x & 63;
    if (wid >= n) return;
    const int quarter = lane >> 4;
    const int q       = lane & 15;
    int e0 = row_ptr[wid], e1 = row_ptr[wid + 1];
    float4 acc0 = make_float4(0.f, 0.f, 0.f, 0.f);
    float4 acc1 = make_float4(0.f, 0.f, 0.f, 0.f);
    #pragma unroll 2
    for (int e = e0 + quarter; e < e1; e += 4) {
        int2 er = edges[e];
        int   s = er.x;
        float w = __int_as_float(er.y);
        const float* hp = H + (size_t)s * 128 + q * 4;
        float4 v0 = *reinterpret_cast<const float4*>(hp);
        float4 v1 = *reinterpret_cast<const float4*>(hp + 64);
        acc0.x = fmaf(w, v0.x, acc0.x); acc0.y = fmaf(w, v0.y, acc0.y);
        acc0.z = fmaf(w, v0.z, acc0.z); acc0.w = fmaf(w, v0.w, acc0.w);
        acc1.x = fmaf(w, v1.x, acc1.x); acc1.y = fmaf(w, v1.y, acc1.y);
        acc1.z = fmaf(w, v1.z, acc1.z); acc1.w = fmaf(w, v1.w, acc1.w);
    }
    #pragma unroll
    for (int d = 16; d <= 32; d <<= 1) {
        acc0.x += __shfl_xor(acc0.x, d); acc0.y += __shfl_xor(acc0.y, d);
        acc0.z += __shfl_xor(acc0.z, d); acc0.w += __shfl_xor(acc0.w, d);
        acc1.x += __shfl_xor(acc1.x, d); acc1.y += __shfl_xor(acc1.y, d);
        acc1.z += __shfl_xor(acc1.z, d); acc1.w += __shfl_xor(acc1.w, d);
    }
    if (quarter == 0) {
        if (EPI == 1) {
            float nn = in_norm[wid];
            float4 bb0 = *reinterpret_cast<const float4*>(bias + q * 4);
            float4 bb1 = *reinterpret_cast<const float4*>(bias + 64 + q * 4);
            acc0.x = fmaxf(fmaf(acc0.x, nn, bb0.x), 0.f);
            acc0.y = fmaxf(fmaf(acc0.y, nn, bb0.y), 0.f);
            acc0.z = fmaxf(fmaf(acc0.z, nn, bb0.z), 0.f);
            acc0.w = fmaxf(fmaf(acc0.w, nn, bb0.w), 0.f);
            acc1.x = fmaxf(fmaf(acc1.x, nn, bb1.x), 0.f);
            acc1.y = fmaxf(fmaf(acc1.y, nn, bb1.y), 0.f);
            acc1.z = fmaxf(fmaf(acc1.z, nn, bb1.z), 0.f);
            acc1.w = fmaxf(fmaf(acc1.w, nn, bb1.w), 0.f);
        }
        float* op = out + (size_t)wid * 128 + q * 4;
        *reinterpret_cast<float4*>(op)      = acc0;
        *reinterpret_cast<float4*>(op + 64) = acc1;
    }
}

// ---- SpMM final layer: T3 padded to 64 cols; out is N x 40 -----------------
__global__ __launch_bounds__(256)
void spmm40(const float* __restrict__ H, const int* __restrict__ row_ptr,
            const int2* __restrict__ edges,
            float* __restrict__ out, const float* __restrict__ in_norm,
            const float* __restrict__ bias, int n) {
    int wid  = (blockIdx.x * 256 + threadIdx.x) >> 6;
    int lane = threadIdx.x & 63;
    if (wid >= n) return;
    const int quarter = lane >> 4;
    const int q       = lane & 15;
    int e0 = row_ptr[wid], e1 = row_ptr[wid + 1];
    float4 acc = make_float4(0.f, 0.f, 0.f, 0.f);
    #pragma unroll 2
    for (int e = e0 + quarter; e < e1; e += 4) {
        int2 er = edges[e];
        int   s = er.x;
        float w = __int_as_float(er.y);
        float4 v = *reinterpret_cast<const float4*>(H + (size_t)s * 64 + q * 4);
        acc.x = fmaf(w, v.x, acc.x);
        acc.y = fmaf(w, v.y, acc.y);
        acc.z = fmaf(w, v.z, acc.z);
        acc.w = fmaf(w, v.w, acc.w);
    }
    #pragma unroll
    for (int d = 16; d <= 32; d <<= 1) {
        acc.x += __shfl_xor(acc.x, d);
        acc.y += __shfl_xor(acc.y, d);
        acc.z += __shfl_xor(acc.z, d);
        acc.w += __shfl_xor(acc.w, d);
    }
    if (quarter == 0 && q * 4 < CDIM) {
        float nn = in_norm[wid];
        float4 bb = *reinterpret_cast<const float4*>(bias + q * 4);
        acc.x = fmaf(acc.x, nn, bb.x);
        acc.y = fmaf(acc.y, nn, bb.y);
        acc.z = fmaf(acc.z, nn, bb.z);
        acc.w = fmaf(acc.w, nn, bb.w);
        *reinterpret_cast<float4*>(out + (size_t)wid * CDIM + q * 4) = acc;
    }
}

// ---------------------------------------------------------------------------

extern "C" void kernel_launch(void* const* d_in, const int* in_sizes, int n_in,
                              void* d_out, int out_size, void* d_ws, size_t ws_size,
                              hipStream_t stream) {
    const float* features = (const float*)d_in[0];
    const int*   src      = (const int*)d_in[1];
    const int*   dst      = (const int*)d_in[2];
    const float* ew       = (const float*)d_in[3];
    const float* W1       = (const float*)d_in[4];
    const float* b1       = (const float*)d_in[5];
    const float* W2       = (const float*)d_in[6];
    const float* b2       = (const float*)d_in[7];
    const float* W3       = (const float*)d_in[8];
    const float* b3       = (const float*)d_in[9];
    float* out = (float*)d_out;

    const int N = in_sizes[0] / F_IN;   // 50000
    const int E = in_sizes[1];          // 800000
    const int NR = (N + RSIZE - 1) >> RBITS;   // 13 node ranges

    // ---- workspace carve-up ----
    char* ws = (char*)d_ws;
    size_t off = 0;
    auto alloc = [&](size_t bytes) -> void* {
        void* p = ws + off;
        off += (bytes + 255) & ~(size_t)255;
        return p;
    };
    int*   pcin     = (int*)alloc((size_t)NR * NSUB * RSIZE * 4);
    int*   pcout    = (int*)alloc((size_t)NR * NSUB * RSIZE * 4);
    int*   row_ptr  = (int*)alloc((size_t)(N + 1) * 4);
    int*   cb       = (int*)alloc((size_t)NSUB * N * 4);
    float* out_norm = (float*)alloc((size_t)N * 4);
    float* in_norm  = (float*)alloc((size_t)N * 4);
    int2*  edges    = (int2*)alloc((size_t)E * 8);
    float* B0       = (float*)alloc((size_t)N * HDIM * 4);  // T1, later H2
    float* B1       = (float*)alloc((size_t)N * HDIM * 4);  // H1, later padded T3
    float* B2       = (float*)alloc((size_t)N * HDIM * 4);  // A2
    const int nb    = (N + 1023) / 1024;
    int*   bsums    = (int*)alloc((size_t)nb * 4);
    (void)ws_size;

    // ---- preprocessing (no global atomics) ----
    {
        dim3 grid(NSUB, NR);
        histo_range<<<grid, 256, 0, stream>>>(src, dst, pcin, pcout, E);
    }
    scan_blocks<<<nb, 256, 0, stream>>>(pcin, row_ptr, bsums, N);
    scan_sums<<<1, 64, 0, stream>>>(bsums, nb);
    int ngrid = (N + 255) / 256;
    node_prep_kernel<<<ngrid, 256, 0, stream>>>(pcin, pcout, row_ptr, bsums,
                                                out_norm, in_norm, cb, N, E);
    {
        dim3 grid(NSUB, NR);
        scatter_range<<<grid, 256, 0, stream>>>(src, dst, ew, out_norm, cb,
                                                edges, E, N);
    }

    const int spmm_grid = (N + 3) / 4;   // one wave per node, 4 waves/block

    // ---- layer 1: T1 = X @ W1 ; H1 = relu(SpMM(T1)*in_norm + b1) ----
    {
        dim3 grid((N + 127) / 128);
        gemm128_f32<0><<<grid, 256, 0, stream>>>(features, W1, B0, N, F_IN,
                                                 nullptr, nullptr);
    }
    spmm128<1><<<spmm_grid, 256, 0, stream>>>(B0, row_ptr, edges, B1, in_norm, b1, N);

    // ---- layer 2: A2 = SpMM(H1) ; H2 = relu((A2 @ W2)*in_norm + b2) ----
    spmm128<0><<<spmm_grid, 256, 0, stream>>>(B1, row_ptr, edges, B2, nullptr, nullptr, N);
    {
        dim3 grid((N + 127) / 128);
        gemm128_f32<1><<<grid, 256, 0, stream>>>(B2, W2, B0, N, HDIM, in_norm, b2);
    }

    // ---- layer 3: T3 = H2 @ W3 (ldc=64 padded) ; OUT = SpMM(T3)*in_norm+b3 -
    {
        dim3 grid((N + 127) / 128, 1);
        gemm_f32<0><<<grid, 256, 0, stream>>>(B0, W3, B1, N, CDIM, HDIM,
                                              HDIM, CDIM, 64, nullptr, nullptr);
    }
    spmm40<<<spmm_grid, 256, 0, stream>>>(B1, row_ptr, edges, out, in_norm, b3, N);
}

// Round 9
// 288.779 us; speedup vs baseline: 1.9692x; 1.1086x over previous
//
#include <hip/hip_runtime.h>
#include <hip/hip_bf16.h>
#include <cstdint>

// ---------------------------------------------------------------------------
// GCN 3-layer forward. fp32, CSR-by-dst SpMM. Zero global atomics.
// Round 9: preprocessing geometry fix — NSUB=64 (448 blocks, was 208),
// RSIZE=8192 (NR=7, was 13 -> half the redundant edge reads), packed
// in/out counts (one 32KB LDS array, one partial-counter stream).
// pc aliases B0, cb aliases B1 (dead before the layers write them).
// ---------------------------------------------------------------------------

#define F_IN 256
#define HDIM 128
#define CDIM 40
#define RBITS 13
#define RSIZE 8192          // nodes per range (32KB LDS of packed int)
#define NSUB 64             // edge-chunk subsets

// ---- stage 1: per-(range,subset) LDS histogram, packed in|out --------------
__global__ __launch_bounds__(256)
void histo_range(const int* __restrict__ src, const int* __restrict__ dst,
                 int* __restrict__ pc, int E) {
    __shared__ int h[RSIZE];
    const int s = blockIdx.x;          // subset
    const int r = blockIdx.y;          // node range
    const int base = r << RBITS;
    const int t = threadIdx.x;
    int4* h4 = reinterpret_cast<int4*>(h);
    for (int j = t; j < RSIZE / 4; j += 256) h4[j] = make_int4(0, 0, 0, 0);
    __syncthreads();

    const int ech = (E + NSUB - 1) / NSUB;
    const int e0 = s * ech;
    const int e1 = min(E, e0 + ech);
    const int n4 = (e1 - e0) >> 2;
    for (int g = t; g < n4; g += 256) {
        int4 d4 = *reinterpret_cast<const int4*>(dst + e0 + g * 4);
        int4 s4 = *reinterpret_cast<const int4*>(src + e0 + g * 4);
        #pragma unroll
        for (int j = 0; j < 4; ++j) {
            int d = (&d4.x)[j] - base;
            int v = (&s4.x)[j] - base;
            if ((unsigned)d < RSIZE) atomicAdd(&h[d], 1);          // in: low 16
            if ((unsigned)v < RSIZE) atomicAdd(&h[v], 0x10000);    // out: high 16
        }
    }
    for (int e = e0 + n4 * 4 + t; e < e1; e += 256) {
        int d = dst[e] - base, v = src[e] - base;
        if ((unsigned)d < RSIZE) atomicAdd(&h[d], 1);
        if ((unsigned)v < RSIZE) atomicAdd(&h[v], 0x10000);
    }
    __syncthreads();
    int* p = pc + ((size_t)r * NSUB + s) * RSIZE;
    for (int j = t; j < RSIZE; j += 256) p[j] = h[j];
}

// ---- stage 2: block-level exclusive scan of in-degree (summed partials) ----
__global__ __launch_bounds__(256)
void scan_blocks(const int* __restrict__ pc, int* __restrict__ out,
                 int* __restrict__ bsums, int n) {
    const int t = threadIdx.x;
    const int idx = blockIdx.x * 1024 + t * 4;
    int4 v = make_int4(0, 0, 0, 0);
    if (idx + 3 < n) {
        const int r = idx >> RBITS, off = idx & (RSIZE - 1);
        const int* p = pc + (size_t)r * NSUB * RSIZE + off;
        #pragma unroll 8
        for (int c = 0; c < NSUB; ++c) {
            int4 u = *reinterpret_cast<const int4*>(p + (size_t)c * RSIZE);
            v.x += u.x & 0xffff; v.y += u.y & 0xffff;
            v.z += u.z & 0xffff; v.w += u.w & 0xffff;
        }
    } else {
        for (int j = 0; j < 4; ++j) {
            if (idx + j < n) {
                const int r = (idx + j) >> RBITS, off = (idx + j) & (RSIZE - 1);
                int s = 0;
                for (int c = 0; c < NSUB; ++c)
                    s += pc[(size_t)r * NSUB * RSIZE + (size_t)c * RSIZE + off] & 0xffff;
                (&v.x)[j] = s;
            }
        }
    }
    const int s = v.x + v.y + v.z + v.w;
    const int lane = t & 63;
    int incl = s;
    #pragma unroll
    for (int off = 1; off < 64; off <<= 1) {
        int u = __shfl_up(incl, off);
        if (lane >= off) incl += u;
    }
    __shared__ int wsum[4];
    if (lane == 63) wsum[t >> 6] = incl;
    __syncthreads();
    const int w = t >> 6;
    int woff = 0;
    if (w > 0) woff += wsum[0];
    if (w > 1) woff += wsum[1];
    if (w > 2) woff += wsum[2];
    const int excl = woff + incl - s;
    if (idx + 3 < n) {
        *reinterpret_cast<int4*>(out + idx) =
            make_int4(excl, excl + v.x, excl + v.x + v.y, excl + v.x + v.y + v.z);
    } else {
        if (idx     < n) out[idx]     = excl;
        if (idx + 1 < n) out[idx + 1] = excl + v.x;
        if (idx + 2 < n) out[idx + 2] = excl + v.x + v.y;
        if (idx + 3 < n) out[idx + 3] = excl + v.x + v.y + v.z;
    }
    if (t == 255) bsums[blockIdx.x] = woff + incl;
}

__global__ __launch_bounds__(64)
void scan_sums(int* __restrict__ bsums, int nb) {
    const int lane = threadIdx.x & 63;
    int carry = 0;
    for (int base = 0; base < nb; base += 64) {
        int v = (base + lane < nb) ? bsums[base + lane] : 0;
        int incl = v;
        #pragma unroll
        for (int off = 1; off < 64; off <<= 1) {
            int u = __shfl_up(incl, off);
            if (lane >= off) incl += u;
        }
        if (base + lane < nb) bsums[base + lane] = carry + incl - v;
        carry += __shfl(incl, 63);
    }
}

// ---- stage 3: finalize row_ptr, norms, per-subset cursor bases cb ----------
__global__ __launch_bounds__(256)
void node_prep_kernel(const int* __restrict__ pc,
                      int* __restrict__ row_ptr, const int* __restrict__ bsums,
                      float* __restrict__ out_norm, float* __restrict__ in_norm,
                      int* __restrict__ cb, int n, int E) {
    int i = blockIdx.x * 256 + threadIdx.x;
    if (i < n) {
        const int r = i >> RBITS, off = i & (RSIZE - 1);
        const int* p = pc + (size_t)r * NSUB * RSIZE + off;
        int rp = row_ptr[i] + bsums[i >> 10];
        row_ptr[i] = rp;
        int cur = rp;
        int od = 0;
        #pragma unroll 8
        for (int c = 0; c < NSUB; ++c) {
            unsigned pv = (unsigned)p[(size_t)c * RSIZE];
            cb[(size_t)c * n + i] = cur;
            cur += (int)(pv & 0xffffu);
            od  += (int)(pv >> 16);
        }
        int id = cur - rp;
        out_norm[i] = rsqrtf((float)max(od, 1));
        in_norm[i]  = rsqrtf((float)max(id, 1));
    }
    if (i == 0) row_ptr[n] = E;
}

// ---- stage 4: scatter via LDS cursors (zero global atomics) ----------------
__global__ __launch_bounds__(256)
void scatter_range(const int* __restrict__ src, const int* __restrict__ dst,
                   const float* __restrict__ ew, const float* __restrict__ out_norm,
                   const int* __restrict__ cb, int2* __restrict__ edges,
                   int E, int N) {
    __shared__ int cur[RSIZE];
    const int s = blockIdx.x;
    const int r = blockIdx.y;
    const int base = r << RBITS;
    const int t = threadIdx.x;
    for (int j = t; j < RSIZE; j += 256)
        if (base + j < N) cur[j] = cb[(size_t)s * N + base + j];
    __syncthreads();

    const int ech = (E + NSUB - 1) / NSUB;
    const int e0 = s * ech;
    const int e1 = min(E, e0 + ech);
    const int n4 = (e1 - e0) >> 2;
    for (int g = t; g < n4; g += 256) {
        int4 d4 = *reinterpret_cast<const int4*>(dst + e0 + g * 4);
        int4 s4 = *reinterpret_cast<const int4*>(src + e0 + g * 4);
        float4 w4 = *reinterpret_cast<const float4*>(ew + e0 + g * 4);
        #pragma unroll
        for (int j = 0; j < 4; ++j) {
            int d = (&d4.x)[j] - base;
            if ((unsigned)d < RSIZE) {
                int sv = (&s4.x)[j];
                int pos = atomicAdd(&cur[d], 1);
                float w = (&w4.x)[j] * out_norm[sv];
                edges[pos] = make_int2(sv, __float_as_int(w));
            }
        }
    }
    for (int e = e0 + n4 * 4 + t; e < e1; e += 256) {
        int d = dst[e] - base;
        if ((unsigned)d < RSIZE) {
            int sv = src[e];
            int pos = atomicAdd(&cur[d], 1);
            float w = ew[e] * out_norm[sv];
            edges[pos] = make_int2(sv, __float_as_int(w));
        }
    }
}

// ---- fp32 GEMM, Nn == 128 exactly (BM=128 BN=128 BK=16, 8x(4+4)/thread) ----
template <int MODE>
__global__ __launch_bounds__(256)
void gemm128_f32(const float* __restrict__ A, const float* __restrict__ B,
                 float* __restrict__ C, int M, int K,
                 const float* __restrict__ rownorm, const float* __restrict__ bias) {
    constexpr int BM = 128, BK = 16;
    __shared__ float As[BK][BM];
    __shared__ float Bs[BK][128];

    const int t = threadIdx.x;
    const int row0 = blockIdx.x * BM;
    const int rowbase = (t >> 4) * 8;
    const int colbase = (t & 15) * 4;
    const int ar  = t >> 1;
    const int akq = (t & 1) * 8;
    const int bk  = t >> 4;
    const int bc8 = (t & 15) * 8;

    float acc0[8][4], acc1[8][4];
    #pragma unroll
    for (int i = 0; i < 8; ++i)
        #pragma unroll
        for (int j = 0; j < 4; ++j) { acc0[i][j] = 0.f; acc1[i][j] = 0.f; }

    for (int k0 = 0; k0 < K; k0 += BK) {
        float4 a0 = make_float4(0.f, 0.f, 0.f, 0.f), a1 = a0;
        if (row0 + ar < M) {
            const float* ap = A + (size_t)(row0 + ar) * K + k0 + akq;
            a0 = *reinterpret_cast<const float4*>(ap);
            a1 = *reinterpret_cast<const float4*>(ap + 4);
        }
        const float* bp = B + (size_t)(k0 + bk) * 128 + bc8;
        float4 b0 = *reinterpret_cast<const float4*>(bp);
        float4 b1 = *reinterpret_cast<const float4*>(bp + 4);
        __syncthreads();
        As[akq + 0][ar] = a0.x; As[akq + 1][ar] = a0.y;
        As[akq + 2][ar] = a0.z; As[akq + 3][ar] = a0.w;
        As[akq + 4][ar] = a1.x; As[akq + 5][ar] = a1.y;
        As[akq + 6][ar] = a1.z; As[akq + 7][ar] = a1.w;
        *reinterpret_cast<float4*>(&Bs[bk][bc8])     = b0;
        *reinterpret_cast<float4*>(&Bs[bk][bc8 + 4]) = b1;
        __syncthreads();

        #pragma unroll
        for (int kk = 0; kk < BK; ++kk) {
            float4 av0 = *reinterpret_cast<const float4*>(&As[kk][rowbase]);
            float4 av1 = *reinterpret_cast<const float4*>(&As[kk][rowbase + 4]);
            float4 bv0 = *reinterpret_cast<const float4*>(&Bs[kk][colbase]);
            float4 bv1 = *reinterpret_cast<const float4*>(&Bs[kk][64 + colbase]);
            float a[8] = {av0.x, av0.y, av0.z, av0.w, av1.x, av1.y, av1.z, av1.w};
            float b0a[4] = {bv0.x, bv0.y, bv0.z, bv0.w};
            float b1a[4] = {bv1.x, bv1.y, bv1.z, bv1.w};
            #pragma unroll
            for (int i = 0; i < 8; ++i) {
                #pragma unroll
                for (int j = 0; j < 4; ++j) {
                    acc0[i][j] = fmaf(a[i], b0a[j], acc0[i][j]);
                    acc1[i][j] = fmaf(a[i], b1a[j], acc1[i][j]);
                }
            }
        }
    }

    float4 bb0 = make_float4(0.f, 0.f, 0.f, 0.f), bb1 = bb0;
    if (MODE == 1) {
        bb0 = *reinterpret_cast<const float4*>(bias + colbase);
        bb1 = *reinterpret_cast<const float4*>(bias + 64 + colbase);
    }
    #pragma unroll
    for (int i = 0; i < 8; ++i) {
        int row = row0 + rowbase + i;
        if (row >= M) break;
        float4 v0 = make_float4(acc0[i][0], acc0[i][1], acc0[i][2], acc0[i][3]);
        float4 v1 = make_float4(acc1[i][0], acc1[i][1], acc1[i][2], acc1[i][3]);
        if (MODE == 1) {
            float rn = rownorm[row];
            v0.x = fmaxf(fmaf(v0.x, rn, bb0.x), 0.f);
            v0.y = fmaxf(fmaf(v0.y, rn, bb0.y), 0.f);
            v0.z = fmaxf(fmaf(v0.z, rn, bb0.z), 0.f);
            v0.w = fmaxf(fmaf(v0.w, rn, bb0.w), 0.f);
            v1.x = fmaxf(fmaf(v1.x, rn, bb1.x), 0.f);
            v1.y = fmaxf(fmaf(v1.y, rn, bb1.y), 0.f);
            v1.z = fmaxf(fmaf(v1.z, rn, bb1.z), 0.f);
            v1.w = fmaxf(fmaf(v1.w, rn, bb1.w), 0.f);
        }
        float* cp = C + (size_t)row * 128 + colbase;
        *reinterpret_cast<float4*>(cp)      = v0;
        *reinterpret_cast<float4*>(cp + 64) = v1;
    }
}

// ---- fp32 tiled GEMM (generic Nn, layer 3; ldc padded): BM=128 BN=64 BK=16
template <int MODE>
__global__ __launch_bounds__(256)
void gemm_f32(const float* __restrict__ A, const float* __restrict__ B,
              float* __restrict__ C, int M, int Nn, int K,
              int lda, int ldb, int ldc,
              const float* __restrict__ rownorm, const float* __restrict__ bias) {
    constexpr int BM = 128, BN = 64, BK = 16;
    __shared__ float As[BK][BM];
    __shared__ float Bs[BK][BN];

    const int t = threadIdx.x;
    const int row0 = blockIdx.x * BM;
    const int col0 = blockIdx.y * BN;
    const int rowbase = (t >> 4) * 8;
    const int colbase = (t & 15) * 4;
    const int ar  = t >> 1;
    const int akq = (t & 1) * 8;
    const int bk  = t >> 4;
    const int bc4 = (t & 15) * 4;

    float acc[8][4];
    #pragma unroll
    for (int i = 0; i < 8; ++i)
        #pragma unroll
        for (int j = 0; j < 4; ++j) acc[i][j] = 0.f;

    for (int k0 = 0; k0 < K; k0 += BK) {
        float4 a0 = make_float4(0.f, 0.f, 0.f, 0.f), a1 = a0;
        if (row0 + ar < M) {
            const float* ap = A + (size_t)(row0 + ar) * lda + k0 + akq;
            a0 = *reinterpret_cast<const float4*>(ap);
            a1 = *reinterpret_cast<const float4*>(ap + 4);
        }
        float4 bv = make_float4(0.f, 0.f, 0.f, 0.f);
        if (col0 + bc4 < Nn) {
            bv = *reinterpret_cast<const float4*>(B + (size_t)(k0 + bk) * ldb + col0 + bc4);
        }
        __syncthreads();
        As[akq + 0][ar] = a0.x; As[akq + 1][ar] = a0.y;
        As[akq + 2][ar] = a0.z; As[akq + 3][ar] = a0.w;
        As[akq + 4][ar] = a1.x; As[akq + 5][ar] = a1.y;
        As[akq + 6][ar] = a1.z; As[akq + 7][ar] = a1.w;
        *reinterpret_cast<float4*>(&Bs[bk][bc4]) = bv;
        __syncthreads();

        #pragma unroll
        for (int kk = 0; kk < BK; ++kk) {
            float4 av0 = *reinterpret_cast<const float4*>(&As[kk][rowbase]);
            float4 av1 = *reinterpret_cast<const float4*>(&As[kk][rowbase + 4]);
            float4 bv2 = *reinterpret_cast<const float4*>(&Bs[kk][colbase]);
            float a[8] = {av0.x, av0.y, av0.z, av0.w, av1.x, av1.y, av1.z, av1.w};
            float b[4] = {bv2.x, bv2.y, bv2.z, bv2.w};
            #pragma unroll
            for (int i = 0; i < 8; ++i)
                #pragma unroll
                for (int j = 0; j < 4; ++j)
                    acc[i][j] = fmaf(a[i], b[j], acc[i][j]);
        }
    }

    if (col0 + colbase >= Nn) return;
    float4 bb = make_float4(0.f, 0.f, 0.f, 0.f);
    if (MODE == 1) bb = *reinterpret_cast<const float4*>(bias + col0 + colbase);
    #pragma unroll
    for (int i = 0; i < 8; ++i) {
        int row = row0 + rowbase + i;
        if (row >= M) break;
        float4 v = make_float4(acc[i][0], acc[i][1], acc[i][2], acc[i][3]);
        if (MODE == 1) {
            float rn = rownorm[row];
            v.x = fmaxf(fmaf(v.x, rn, bb.x), 0.f);
            v.y = fmaxf(fmaf(v.y, rn, bb.y), 0.f);
            v.z = fmaxf(fmaf(v.z, rn, bb.z), 0.f);
            v.w = fmaxf(fmaf(v.w, rn, bb.w), 0.f);
        }
        *reinterpret_cast<float4*>(C + (size_t)row * ldc + col0 + colbase) = v;
    }
}

// ---- SpMM (CSR by dst), 128 features: 4x16-lane edge streams ---------------
template <int EPI>
__global__ __launch_bounds__(256)
void spmm128(const float* __restrict__ H, const int* __restrict__ row_ptr,
             const int2* __restrict__ edges,
             float* __restrict__ out, const float* __restrict__ in_norm,
             const float* __restrict__ bias, int n) {
    int wid  = (blockIdx.x * 256 + threadIdx.x) >> 6;
    int lane = threadIdx.x & 63;
    if (wid >= n) return;
    const int quarter = lane >> 4;
    const int q       = lane & 15;
    int e0 = row_ptr[wid], e1 = row_ptr[wid + 1];
    float4 acc0 = make_float4(0.f, 0.f, 0.f, 0.f);
    float4 acc1 = make_float4(0.f, 0.f, 0.f, 0.f);
    #pragma unroll 2
    for (int e = e0 + quarter; e < e1; e += 4) {
        int2 er = edges[e];
        int   s = er.x;
        float w = __int_as_float(er.y);
        const float* hp = H + (size_t)s * 128 + q * 4;
        float4 v0 = *reinterpret_cast<const float4*>(hp);
        float4 v1 = *reinterpret_cast<const float4*>(hp + 64);
        acc0.x = fmaf(w, v0.x, acc0.x); acc0.y = fmaf(w, v0.y, acc0.y);
        acc0.z = fmaf(w, v0.z, acc0.z); acc0.w = fmaf(w, v0.w, acc0.w);
        acc1.x = fmaf(w, v1.x, acc1.x); acc1.y = fmaf(w, v1.y, acc1.y);
        acc1.z = fmaf(w, v1.z, acc1.z); acc1.w = fmaf(w, v1.w, acc1.w);
    }
    #pragma unroll
    for (int d = 16; d <= 32; d <<= 1) {
        acc0.x += __shfl_xor(acc0.x, d); acc0.y += __shfl_xor(acc0.y, d);
        acc0.z += __shfl_xor(acc0.z, d); acc0.w += __shfl_xor(acc0.w, d);
        acc1.x += __shfl_xor(acc1.x, d); acc1.y += __shfl_xor(acc1.y, d);
        acc1.z += __shfl_xor(acc1.z, d); acc1.w += __shfl_xor(acc1.w, d);
    }
    if (quarter == 0) {
        if (EPI == 1) {
            float nn = in_norm[wid];
            float4 bb0 = *reinterpret_cast<const float4*>(bias + q * 4);
            float4 bb1 = *reinterpret_cast<const float4*>(bias + 64 + q * 4);
            acc0.x = fmaxf(fmaf(acc0.x, nn, bb0.x), 0.f);
            acc0.y = fmaxf(fmaf(acc0.y, nn, bb0.y), 0.f);
            acc0.z = fmaxf(fmaf(acc0.z, nn, bb0.z), 0.f);
            acc0.w = fmaxf(fmaf(acc0.w, nn, bb0.w), 0.f);
            acc1.x = fmaxf(fmaf(acc1.x, nn, bb1.x), 0.f);
            acc1.y = fmaxf(fmaf(acc1.y, nn, bb1.y), 0.f);
            acc1.z = fmaxf(fmaf(acc1.z, nn, bb1.z), 0.f);
            acc1.w = fmaxf(fmaf(acc1.w, nn, bb1.w), 0.f);
        }
        float* op = out + (size_t)wid * 128 + q * 4;
        *reinterpret_cast<float4*>(op)      = acc0;
        *reinterpret_cast<float4*>(op + 64) = acc1;
    }
}

// ---- SpMM final layer: T3 padded to 64 cols; out is N x 40 -----------------
__global__ __launch_bounds__(256)
void spmm40(const float* __restrict__ H, const int* __restrict__ row_ptr,
            const int2* __restrict__ edges,
            float* __restrict__ out, const float* __restrict__ in_norm,
            const float* __restrict__ bias, int n) {
    int wid  = (blockIdx.x * 256 + threadIdx.x) >> 6;
    int lane = threadIdx.x & 63;
    if (wid >= n) return;
    const int quarter = lane >> 4;
    const int q       = lane & 15;
    int e0 = row_ptr[wid], e1 = row_ptr[wid + 1];
    float4 acc = make_float4(0.f, 0.f, 0.f, 0.f);
    #pragma unroll 2
    for (int e = e0 + quarter; e < e1; e += 4) {
        int2 er = edges[e];
        int   s = er.x;
        float w = __int_as_float(er.y);
        float4 v = *reinterpret_cast<const float4*>(H + (size_t)s * 64 + q * 4);
        acc.x = fmaf(w, v.x, acc.x);
        acc.y = fmaf(w, v.y, acc.y);
        acc.z = fmaf(w, v.z, acc.z);
        acc.w = fmaf(w, v.w, acc.w);
    }
    #pragma unroll
    for (int d = 16; d <= 32; d <<= 1) {
        acc.x += __shfl_xor(acc.x, d);
        acc.y += __shfl_xor(acc.y, d);
        acc.z += __shfl_xor(acc.z, d);
        acc.w += __shfl_xor(acc.w, d);
    }
    if (quarter == 0 && q * 4 < CDIM) {
        float nn = in_norm[wid];
        float4 bb = *reinterpret_cast<const float4*>(bias + q * 4);
        acc.x = fmaf(acc.x, nn, bb.x);
        acc.y = fmaf(acc.y, nn, bb.y);
        acc.z = fmaf(acc.z, nn, bb.z);
        acc.w = fmaf(acc.w, nn, bb.w);
        *reinterpret_cast<float4*>(out + (size_t)wid * CDIM + q * 4) = acc;
    }
}

// ---------------------------------------------------------------------------

extern "C" void kernel_launch(void* const* d_in, const int* in_sizes, int n_in,
                              void* d_out, int out_size, void* d_ws, size_t ws_size,
                              hipStream_t stream) {
    const float* features = (const float*)d_in[0];
    const int*   src      = (const int*)d_in[1];
    const int*   dst      = (const int*)d_in[2];
    const float* ew       = (const float*)d_in[3];
    const float* W1       = (const float*)d_in[4];
    const float* b1       = (const float*)d_in[5];
    const float* W2       = (const float*)d_in[6];
    const float* b2       = (const float*)d_in[7];
    const float* W3       = (const float*)d_in[8];
    const float* b3       = (const float*)d_in[9];
    float* out = (float*)d_out;

    const int N = in_sizes[0] / F_IN;   // 50000
    const int E = in_sizes[1];          // 800000
    const int NR = (N + RSIZE - 1) >> RBITS;   // 7 node ranges

    // ---- workspace carve-up ----
    char* ws = (char*)d_ws;
    size_t off = 0;
    auto alloc = [&](size_t bytes) -> void* {
        void* p = ws + off;
        off += (bytes + 255) & ~(size_t)255;
        return p;
    };
    int*   row_ptr  = (int*)alloc((size_t)(N + 1) * 4);
    float* out_norm = (float*)alloc((size_t)N * 4);
    float* in_norm  = (float*)alloc((size_t)N * 4);
    int2*  edges    = (int2*)alloc((size_t)E * 8);
    float* B0       = (float*)alloc((size_t)N * HDIM * 4);  // T1, later H2
    float* B1       = (float*)alloc((size_t)N * HDIM * 4);  // H1, later padded T3
    float* B2       = (float*)alloc((size_t)N * HDIM * 4);  // A2
    const int nb    = (N + 1023) / 1024;
    int*   bsums    = (int*)alloc((size_t)nb * 4);
    // preprocessing scratch ALIASES the layer buffers (dead before layers):
    int*   pc       = (int*)B0;   // NR*NSUB*RSIZE*4 = 14.7MB < 25.6MB
    int*   cb       = (int*)B1;   // NSUB*N*4       = 12.8MB < 25.6MB
    (void)ws_size;

    // ---- preprocessing (no global atomics) ----
    {
        dim3 grid(NSUB, NR);
        histo_range<<<grid, 256, 0, stream>>>(src, dst, pc, E);
    }
    scan_blocks<<<nb, 256, 0, stream>>>(pc, row_ptr, bsums, N);
    scan_sums<<<1, 64, 0, stream>>>(bsums, nb);
    int ngrid = (N + 255) / 256;
    node_prep_kernel<<<ngrid, 256, 0, stream>>>(pc, row_ptr, bsums,
                                                out_norm, in_norm, cb, N, E);
    {
        dim3 grid(NSUB, NR);
        scatter_range<<<grid, 256, 0, stream>>>(src, dst, ew, out_norm, cb,
                                                edges, E, N);
    }

    const int spmm_grid = (N + 3) / 4;   // one wave per node, 4 waves/block

    // ---- layer 1: T1 = X @ W1 ; H1 = relu(SpMM(T1)*in_norm + b1) ----
    {
        dim3 grid((N + 127) / 128);
        gemm128_f32<0><<<grid, 256, 0, stream>>>(features, W1, B0, N, F_IN,
                                                 nullptr, nullptr);
    }
    spmm128<1><<<spmm_grid, 256, 0, stream>>>(B0, row_ptr, edges, B1, in_norm, b1, N);

    // ---- layer 2: A2 = SpMM(H1) ; H2 = relu((A2 @ W2)*in_norm + b2) ----
    spmm128<0><<<spmm_grid, 256, 0, stream>>>(B1, row_ptr, edges, B2, nullptr, nullptr, N);
    {
        dim3 grid((N + 127) / 128);
        gemm128_f32<1><<<grid, 256, 0, stream>>>(B2, W2, B0, N, HDIM, in_norm, b2);
    }

    // ---- layer 3: T3 = H2 @ W3 (ldc=64 padded) ; OUT = SpMM(T3)*in_norm+b3 -
    {
        dim3 grid((N + 127) / 128, 1);
        gemm_f32<0><<<grid, 256, 0, stream>>>(B0, W3, B1, N, CDIM, HDIM,
                                              HDIM, CDIM, 64, nullptr, nullptr);
    }
    spmm40<<<spmm_grid, 256, 0, stream>>>(B1, row_ptr, edges, out, in_norm, b3, N);
}

// Round 10
// 286.798 us; speedup vs baseline: 1.9828x; 1.0069x over previous
//
#include <hip/hip_runtime.h>
#include <hip/hip_bf16.h>
#include <cstdint>

// ---------------------------------------------------------------------------
// GCN 3-layer forward. fp32, CSR-by-dst SpMM. Zero global atomics.
// Round 10: GEMM register prefetch (load tile k+1 into regs before computing
// tile k -> HBM latency hidden under FMA; was barrier-exposed at 12% occ),
// Bs stage-in split 4+4 (kills residual 4-way write conflicts).
// ---------------------------------------------------------------------------

#define F_IN 256
#define HDIM 128
#define CDIM 40
#define RBITS 13
#define RSIZE 8192          // nodes per range (32KB LDS of packed int)
#define NSUB 64             // edge-chunk subsets

// ---- stage 1: per-(range,subset) LDS histogram, packed in|out --------------
__global__ __launch_bounds__(256)
void histo_range(const int* __restrict__ src, const int* __restrict__ dst,
                 int* __restrict__ pc, int E) {
    __shared__ int h[RSIZE];
    const int s = blockIdx.x;          // subset
    const int r = blockIdx.y;          // node range
    const int base = r << RBITS;
    const int t = threadIdx.x;
    int4* h4 = reinterpret_cast<int4*>(h);
    for (int j = t; j < RSIZE / 4; j += 256) h4[j] = make_int4(0, 0, 0, 0);
    __syncthreads();

    const int ech = (E + NSUB - 1) / NSUB;
    const int e0 = s * ech;
    const int e1 = min(E, e0 + ech);
    const int n4 = (e1 - e0) >> 2;
    for (int g = t; g < n4; g += 256) {
        int4 d4 = *reinterpret_cast<const int4*>(dst + e0 + g * 4);
        int4 s4 = *reinterpret_cast<const int4*>(src + e0 + g * 4);
        #pragma unroll
        for (int j = 0; j < 4; ++j) {
            int d = (&d4.x)[j] - base;
            int v = (&s4.x)[j] - base;
            if ((unsigned)d < RSIZE) atomicAdd(&h[d], 1);          // in: low 16
            if ((unsigned)v < RSIZE) atomicAdd(&h[v], 0x10000);    // out: high 16
        }
    }
    for (int e = e0 + n4 * 4 + t; e < e1; e += 256) {
        int d = dst[e] - base, v = src[e] - base;
        if ((unsigned)d < RSIZE) atomicAdd(&h[d], 1);
        if ((unsigned)v < RSIZE) atomicAdd(&h[v], 0x10000);
    }
    __syncthreads();
    int* p = pc + ((size_t)r * NSUB + s) * RSIZE;
    for (int j = t; j < RSIZE; j += 256) p[j] = h[j];
}

// ---- stage 2: block-level exclusive scan of in-degree (summed partials) ----
__global__ __launch_bounds__(256)
void scan_blocks(const int* __restrict__ pc, int* __restrict__ out,
                 int* __restrict__ bsums, int n) {
    const int t = threadIdx.x;
    const int idx = blockIdx.x * 1024 + t * 4;
    int4 v = make_int4(0, 0, 0, 0);
    if (idx + 3 < n) {
        const int r = idx >> RBITS, off = idx & (RSIZE - 1);
        const int* p = pc + (size_t)r * NSUB * RSIZE + off;
        #pragma unroll 8
        for (int c = 0; c < NSUB; ++c) {
            int4 u = *reinterpret_cast<const int4*>(p + (size_t)c * RSIZE);
            v.x += u.x & 0xffff; v.y += u.y & 0xffff;
            v.z += u.z & 0xffff; v.w += u.w & 0xffff;
        }
    } else {
        for (int j = 0; j < 4; ++j) {
            if (idx + j < n) {
                const int r = (idx + j) >> RBITS, off = (idx + j) & (RSIZE - 1);
                int s = 0;
                for (int c = 0; c < NSUB; ++c)
                    s += pc[(size_t)r * NSUB * RSIZE + (size_t)c * RSIZE + off] & 0xffff;
                (&v.x)[j] = s;
            }
        }
    }
    const int s = v.x + v.y + v.z + v.w;
    const int lane = t & 63;
    int incl = s;
    #pragma unroll
    for (int off = 1; off < 64; off <<= 1) {
        int u = __shfl_up(incl, off);
        if (lane >= off) incl += u;
    }
    __shared__ int wsum[4];
    if (lane == 63) wsum[t >> 6] = incl;
    __syncthreads();
    const int w = t >> 6;
    int woff = 0;
    if (w > 0) woff += wsum[0];
    if (w > 1) woff += wsum[1];
    if (w > 2) woff += wsum[2];
    const int excl = woff + incl - s;
    if (idx + 3 < n) {
        *reinterpret_cast<int4*>(out + idx) =
            make_int4(excl, excl + v.x, excl + v.x + v.y, excl + v.x + v.y + v.z);
    } else {
        if (idx     < n) out[idx]     = excl;
        if (idx + 1 < n) out[idx + 1] = excl + v.x;
        if (idx + 2 < n) out[idx + 2] = excl + v.x + v.y;
        if (idx + 3 < n) out[idx + 3] = excl + v.x + v.y + v.z;
    }
    if (t == 255) bsums[blockIdx.x] = woff + incl;
}

__global__ __launch_bounds__(64)
void scan_sums(int* __restrict__ bsums, int nb) {
    const int lane = threadIdx.x & 63;
    int carry = 0;
    for (int base = 0; base < nb; base += 64) {
        int v = (base + lane < nb) ? bsums[base + lane] : 0;
        int incl = v;
        #pragma unroll
        for (int off = 1; off < 64; off <<= 1) {
            int u = __shfl_up(incl, off);
            if (lane >= off) incl += u;
        }
        if (base + lane < nb) bsums[base + lane] = carry + incl - v;
        carry += __shfl(incl, 63);
    }
}

// ---- stage 3: finalize row_ptr, norms, per-subset cursor bases cb ----------
__global__ __launch_bounds__(256)
void node_prep_kernel(const int* __restrict__ pc,
                      int* __restrict__ row_ptr, const int* __restrict__ bsums,
                      float* __restrict__ out_norm, float* __restrict__ in_norm,
                      int* __restrict__ cb, int n, int E) {
    int i = blockIdx.x * 256 + threadIdx.x;
    if (i < n) {
        const int r = i >> RBITS, off = i & (RSIZE - 1);
        const int* p = pc + (size_t)r * NSUB * RSIZE + off;
        int rp = row_ptr[i] + bsums[i >> 10];
        row_ptr[i] = rp;
        int cur = rp;
        int od = 0;
        #pragma unroll 8
        for (int c = 0; c < NSUB; ++c) {
            unsigned pv = (unsigned)p[(size_t)c * RSIZE];
            cb[(size_t)c * n + i] = cur;
            cur += (int)(pv & 0xffffu);
            od  += (int)(pv >> 16);
        }
        int id = cur - rp;
        out_norm[i] = rsqrtf((float)max(od, 1));
        in_norm[i]  = rsqrtf((float)max(id, 1));
    }
    if (i == 0) row_ptr[n] = E;
}

// ---- stage 4: scatter via LDS cursors (zero global atomics) ----------------
__global__ __launch_bounds__(256)
void scatter_range(const int* __restrict__ src, const int* __restrict__ dst,
                   const float* __restrict__ ew, const float* __restrict__ out_norm,
                   const int* __restrict__ cb, int2* __restrict__ edges,
                   int E, int N) {
    __shared__ int cur[RSIZE];
    const int s = blockIdx.x;
    const int r = blockIdx.y;
    const int base = r << RBITS;
    const int t = threadIdx.x;
    for (int j = t; j < RSIZE; j += 256)
        if (base + j < N) cur[j] = cb[(size_t)s * N + base + j];
    __syncthreads();

    const int ech = (E + NSUB - 1) / NSUB;
    const int e0 = s * ech;
    const int e1 = min(E, e0 + ech);
    const int n4 = (e1 - e0) >> 2;
    for (int g = t; g < n4; g += 256) {
        int4 d4 = *reinterpret_cast<const int4*>(dst + e0 + g * 4);
        int4 s4 = *reinterpret_cast<const int4*>(src + e0 + g * 4);
        float4 w4 = *reinterpret_cast<const float4*>(ew + e0 + g * 4);
        #pragma unroll
        for (int j = 0; j < 4; ++j) {
            int d = (&d4.x)[j] - base;
            if ((unsigned)d < RSIZE) {
                int sv = (&s4.x)[j];
                int pos = atomicAdd(&cur[d], 1);
                float w = (&w4.x)[j] * out_norm[sv];
                edges[pos] = make_int2(sv, __float_as_int(w));
            }
        }
    }
    for (int e = e0 + n4 * 4 + t; e < e1; e += 256) {
        int d = dst[e] - base;
        if ((unsigned)d < RSIZE) {
            int sv = src[e];
            int pos = atomicAdd(&cur[d], 1);
            float w = ew[e] * out_norm[sv];
            edges[pos] = make_int2(sv, __float_as_int(w));
        }
    }
}

// ---- fp32 GEMM, Nn == 128 exactly (BM=128 BN=128 BK=16, 8x(4+4)/thread) ----
// Register-prefetched: tile k+1 loaded into regs before computing tile k.
template <int MODE>
__global__ __launch_bounds__(256)
void gemm128_f32(const float* __restrict__ A, const float* __restrict__ B,
                 float* __restrict__ C, int M, int K,
                 const float* __restrict__ rownorm, const float* __restrict__ bias) {
    constexpr int BM = 128, BK = 16;
    __shared__ float As[BK][BM];
    __shared__ float Bs[BK][128];

    const int t = threadIdx.x;
    const int row0 = blockIdx.x * BM;
    const int rowbase = (t >> 4) * 8;
    const int colbase = (t & 15) * 4;
    const int ar  = t >> 1;
    const int akq = (t & 1) * 8;
    const int bk  = t >> 4;
    const int bc4 = (t & 15) * 4;     // Bs stage: two float4 at bc4, 64+bc4

    float acc0[8][4], acc1[8][4];
    #pragma unroll
    for (int i = 0; i < 8; ++i)
        #pragma unroll
        for (int j = 0; j < 4; ++j) { acc0[i][j] = 0.f; acc1[i][j] = 0.f; }

    const bool arow_ok = (row0 + ar < M);
    const float* ap = A + (size_t)(row0 + ar) * K + akq;

    // prologue: load tile 0 into regs
    float4 a0 = make_float4(0.f, 0.f, 0.f, 0.f), a1 = a0;
    if (arow_ok) {
        a0 = *reinterpret_cast<const float4*>(ap);
        a1 = *reinterpret_cast<const float4*>(ap + 4);
    }
    const float* bp = B + (size_t)bk * 128;
    float4 b0 = *reinterpret_cast<const float4*>(bp + bc4);
    float4 b1 = *reinterpret_cast<const float4*>(bp + 64 + bc4);

    for (int k0 = 0; k0 < K; k0 += BK) {
        __syncthreads();   // previous iter done reading LDS
        As[akq + 0][ar] = a0.x; As[akq + 1][ar] = a0.y;
        As[akq + 2][ar] = a0.z; As[akq + 3][ar] = a0.w;
        As[akq + 4][ar] = a1.x; As[akq + 5][ar] = a1.y;
        As[akq + 6][ar] = a1.z; As[akq + 7][ar] = a1.w;
        *reinterpret_cast<float4*>(&Bs[bk][bc4])      = b0;
        *reinterpret_cast<float4*>(&Bs[bk][64 + bc4]) = b1;
        __syncthreads();

        // prefetch tile k0+BK (issued before compute; latency hidden)
        if (k0 + BK < K) {
            if (arow_ok) {
                a0 = *reinterpret_cast<const float4*>(ap + k0 + BK);
                a1 = *reinterpret_cast<const float4*>(ap + k0 + BK + 4);
            }
            const float* bp2 = B + (size_t)(k0 + BK + bk) * 128;
            b0 = *reinterpret_cast<const float4*>(bp2 + bc4);
            b1 = *reinterpret_cast<const float4*>(bp2 + 64 + bc4);
        }

        #pragma unroll
        for (int kk = 0; kk < BK; ++kk) {
            float4 av0 = *reinterpret_cast<const float4*>(&As[kk][rowbase]);
            float4 av1 = *reinterpret_cast<const float4*>(&As[kk][rowbase + 4]);
            float4 bv0 = *reinterpret_cast<const float4*>(&Bs[kk][colbase]);
            float4 bv1 = *reinterpret_cast<const float4*>(&Bs[kk][64 + colbase]);
            float a[8] = {av0.x, av0.y, av0.z, av0.w, av1.x, av1.y, av1.z, av1.w};
            float b0a[4] = {bv0.x, bv0.y, bv0.z, bv0.w};
            float b1a[4] = {bv1.x, bv1.y, bv1.z, bv1.w};
            #pragma unroll
            for (int i = 0; i < 8; ++i) {
                #pragma unroll
                for (int j = 0; j < 4; ++j) {
                    acc0[i][j] = fmaf(a[i], b0a[j], acc0[i][j]);
                    acc1[i][j] = fmaf(a[i], b1a[j], acc1[i][j]);
                }
            }
        }
    }

    float4 bb0 = make_float4(0.f, 0.f, 0.f, 0.f), bb1 = bb0;
    if (MODE == 1) {
        bb0 = *reinterpret_cast<const float4*>(bias + colbase);
        bb1 = *reinterpret_cast<const float4*>(bias + 64 + colbase);
    }
    #pragma unroll
    for (int i = 0; i < 8; ++i) {
        int row = row0 + rowbase + i;
        if (row >= M) break;
        float4 v0 = make_float4(acc0[i][0], acc0[i][1], acc0[i][2], acc0[i][3]);
        float4 v1 = make_float4(acc1[i][0], acc1[i][1], acc1[i][2], acc1[i][3]);
        if (MODE == 1) {
            float rn = rownorm[row];
            v0.x = fmaxf(fmaf(v0.x, rn, bb0.x), 0.f);
            v0.y = fmaxf(fmaf(v0.y, rn, bb0.y), 0.f);
            v0.z = fmaxf(fmaf(v0.z, rn, bb0.z), 0.f);
            v0.w = fmaxf(fmaf(v0.w, rn, bb0.w), 0.f);
            v1.x = fmaxf(fmaf(v1.x, rn, bb1.x), 0.f);
            v1.y = fmaxf(fmaf(v1.y, rn, bb1.y), 0.f);
            v1.z = fmaxf(fmaf(v1.z, rn, bb1.z), 0.f);
            v1.w = fmaxf(fmaf(v1.w, rn, bb1.w), 0.f);
        }
        float* cp = C + (size_t)row * 128 + colbase;
        *reinterpret_cast<float4*>(cp)      = v0;
        *reinterpret_cast<float4*>(cp + 64) = v1;
    }
}

// ---- fp32 tiled GEMM (generic Nn, layer 3; ldc padded), prefetched --------
template <int MODE>
__global__ __launch_bounds__(256)
void gemm_f32(const float* __restrict__ A, const float* __restrict__ B,
              float* __restrict__ C, int M, int Nn, int K,
              int lda, int ldb, int ldc,
              const float* __restrict__ rownorm, const float* __restrict__ bias) {
    constexpr int BM = 128, BN = 64, BK = 16;
    __shared__ float As[BK][BM];
    __shared__ float Bs[BK][BN];

    const int t = threadIdx.x;
    const int row0 = blockIdx.x * BM;
    const int col0 = blockIdx.y * BN;
    const int rowbase = (t >> 4) * 8;
    const int colbase = (t & 15) * 4;
    const int ar  = t >> 1;
    const int akq = (t & 1) * 8;
    const int bk  = t >> 4;
    const int bc4 = (t & 15) * 4;

    float acc[8][4];
    #pragma unroll
    for (int i = 0; i < 8; ++i)
        #pragma unroll
        for (int j = 0; j < 4; ++j) acc[i][j] = 0.f;

    const bool arow_ok = (row0 + ar < M);
    const bool bcol_ok = (col0 + bc4 < Nn);
    const float* ap = A + (size_t)(row0 + ar) * lda + akq;

    float4 a0 = make_float4(0.f, 0.f, 0.f, 0.f), a1 = a0, bv = a0;
    if (arow_ok) {
        a0 = *reinterpret_cast<const float4*>(ap);
        a1 = *reinterpret_cast<const float4*>(ap + 4);
    }
    if (bcol_ok)
        bv = *reinterpret_cast<const float4*>(B + (size_t)bk * ldb + col0 + bc4);

    for (int k0 = 0; k0 < K; k0 += BK) {
        __syncthreads();
        As[akq + 0][ar] = a0.x; As[akq + 1][ar] = a0.y;
        As[akq + 2][ar] = a0.z; As[akq + 3][ar] = a0.w;
        As[akq + 4][ar] = a1.x; As[akq + 5][ar] = a1.y;
        As[akq + 6][ar] = a1.z; As[akq + 7][ar] = a1.w;
        *reinterpret_cast<float4*>(&Bs[bk][bc4]) = bv;
        __syncthreads();

        if (k0 + BK < K) {
            if (arow_ok) {
                a0 = *reinterpret_cast<const float4*>(ap + k0 + BK);
                a1 = *reinterpret_cast<const float4*>(ap + k0 + BK + 4);
            }
            if (bcol_ok)
                bv = *reinterpret_cast<const float4*>(B + (size_t)(k0 + BK + bk) * ldb + col0 + bc4);
        }

        #pragma unroll
        for (int kk = 0; kk < BK; ++kk) {
            float4 av0 = *reinterpret_cast<const float4*>(&As[kk][rowbase]);
            float4 av1 = *reinterpret_cast<const float4*>(&As[kk][rowbase + 4]);
            float4 bv2 = *reinterpret_cast<const float4*>(&Bs[kk][colbase]);
            float a[8] = {av0.x, av0.y, av0.z, av0.w, av1.x, av1.y, av1.z, av1.w};
            float b[4] = {bv2.x, bv2.y, bv2.z, bv2.w};
            #pragma unroll
            for (int i = 0; i < 8; ++i)
                #pragma unroll
                for (int j = 0; j < 4; ++j)
                    acc[i][j] = fmaf(a[i], b[j], acc[i][j]);
        }
    }

    if (col0 + colbase >= Nn) return;
    float4 bb = make_float4(0.f, 0.f, 0.f, 0.f);
    if (MODE == 1) bb = *reinterpret_cast<const float4*>(bias + col0 + colbase);
    #pragma unroll
    for (int i = 0; i < 8; ++i) {
        int row = row0 + rowbase + i;
        if (row >= M) break;
        float4 v = make_float4(acc[i][0], acc[i][1], acc[i][2], acc[i][3]);
        if (MODE == 1) {
            float rn = rownorm[row];
            v.x = fmaxf(fmaf(v.x, rn, bb.x), 0.f);
            v.y = fmaxf(fmaf(v.y, rn, bb.y), 0.f);
            v.z = fmaxf(fmaf(v.z, rn, bb.z), 0.f);
            v.w = fmaxf(fmaf(v.w, rn, bb.w), 0.f);
        }
        *reinterpret_cast<float4*>(C + (size_t)row * ldc + col0 + colbase) = v;
    }
}

// ---- SpMM (CSR by dst), 128 features: 4x16-lane edge streams ---------------
template <int EPI>
__global__ __launch_bounds__(256)
void spmm128(const float* __restrict__ H, const int* __restrict__ row_ptr,
             const int2* __restrict__ edges,
             float* __restrict__ out, const float* __restrict__ in_norm,
             const float* __restrict__ bias, int n) {
    int wid  = (blockIdx.x * 256 + threadIdx.x) >> 6;
    int lane = threadIdx.x & 63;
    if (wid >= n) return;
    const int quarter = lane >> 4;
    const int q       = lane & 15;
    int e0 = row_ptr[wid], e1 = row_ptr[wid + 1];
    float4 acc0 = make_float4(0.f, 0.f, 0.f, 0.f);
    float4 acc1 = make_float4(0.f, 0.f, 0.f, 0.f);
    #pragma unroll 2
    for (int e = e0 + quarter; e < e1; e += 4) {
        int2 er = edges[e];
        int   s = er.x;
        float w = __int_as_float(er.y);
        const float* hp = H + (size_t)s * 128 + q * 4;
        float4 v0 = *reinterpret_cast<const float4*>(hp);
        float4 v1 = *reinterpret_cast<const float4*>(hp + 64);
        acc0.x = fmaf(w, v0.x, acc0.x); acc0.y = fmaf(w, v0.y, acc0.y);
        acc0.z = fmaf(w, v0.z, acc0.z); acc0.w = fmaf(w, v0.w, acc0.w);
        acc1.x = fmaf(w, v1.x, acc1.x); acc1.y = fmaf(w, v1.y, acc1.y);
        acc1.z = fmaf(w, v1.z, acc1.z); acc1.w = fmaf(w, v1.w, acc1.w);
    }
    #pragma unroll
    for (int d = 16; d <= 32; d <<= 1) {
        acc0.x += __shfl_xor(acc0.x, d); acc0.y += __shfl_xor(acc0.y, d);
        acc0.z += __shfl_xor(acc0.z, d); acc0.w += __shfl_xor(acc0.w, d);
        acc1.x += __shfl_xor(acc1.x, d); acc1.y += __shfl_xor(acc1.y, d);
        acc1.z += __shfl_xor(acc1.z, d); acc1.w += __shfl_xor(acc1.w, d);
    }
    if (quarter == 0) {
        if (EPI == 1) {
            float nn = in_norm[wid];
            float4 bb0 = *reinterpret_cast<const float4*>(bias + q * 4);
            float4 bb1 = *reinterpret_cast<const float4*>(bias + 64 + q * 4);
            acc0.x = fmaxf(fmaf(acc0.x, nn, bb0.x), 0.f);
            acc0.y = fmaxf(fmaf(acc0.y, nn, bb0.y), 0.f);
            acc0.z = fmaxf(fmaf(acc0.z, nn, bb0.z), 0.f);
            acc0.w = fmaxf(fmaf(acc0.w, nn, bb0.w), 0.f);
            acc1.x = fmaxf(fmaf(acc1.x, nn, bb1.x), 0.f);
            acc1.y = fmaxf(fmaf(acc1.y, nn, bb1.y), 0.f);
            acc1.z = fmaxf(fmaf(acc1.z, nn, bb1.z), 0.f);
            acc1.w = fmaxf(fmaf(acc1.w, nn, bb1.w), 0.f);
        }
        float* op = out + (size_t)wid * 128 + q * 4;
        *reinterpret_cast<float4*>(op)      = acc0;
        *reinterpret_cast<float4*>(op + 64) = acc1;
    }
}

// ---- SpMM final layer: T3 padded to 64 cols; out is N x 40 -----------------
__global__ __launch_bounds__(256)
void spmm40(const float* __restrict__ H, const int* __restrict__ row_ptr,
            const int2* __restrict__ edges,
            float* __restrict__ out, const float* __restrict__ in_norm,
            const float* __restrict__ bias, int n) {
    int wid  = (blockIdx.x * 256 + threadIdx.x) >> 6;
    int lane = threadIdx.x & 63;
    if (wid >= n) return;
    const int quarter = lane >> 4;
    const int q       = lane & 15;
    int e0 = row_ptr[wid], e1 = row_ptr[wid + 1];
    float4 acc = make_float4(0.f, 0.f, 0.f, 0.f);
    #pragma unroll 2
    for (int e = e0 + quarter; e < e1; e += 4) {
        int2 er = edges[e];
        int   s = er.x;
        float w = __int_as_float(er.y);
        float4 v = *reinterpret_cast<const float4*>(H + (size_t)s * 64 + q * 4);
        acc.x = fmaf(w, v.x, acc.x);
        acc.y = fmaf(w, v.y, acc.y);
        acc.z = fmaf(w, v.z, acc.z);
        acc.w = fmaf(w, v.w, acc.w);
    }
    #pragma unroll
    for (int d = 16; d <= 32; d <<= 1) {
        acc.x += __shfl_xor(acc.x, d);
        acc.y += __shfl_xor(acc.y, d);
        acc.z += __shfl_xor(acc.z, d);
        acc.w += __shfl_xor(acc.w, d);
    }
    if (quarter == 0 && q * 4 < CDIM) {
        float nn = in_norm[wid];
        float4 bb = *reinterpret_cast<const float4*>(bias + q * 4);
        acc.x = fmaf(acc.x, nn, bb.x);
        acc.y = fmaf(acc.y, nn, bb.y);
        acc.z = fmaf(acc.z, nn, bb.z);
        acc.w = fmaf(acc.w, nn, bb.w);
        *reinterpret_cast<float4*>(out + (size_t)wid * CDIM + q * 4) = acc;
    }
}

// ---------------------------------------------------------------------------

extern "C" void kernel_launch(void* const* d_in, const int* in_sizes, int n_in,
                              void* d_out, int out_size, void* d_ws, size_t ws_size,
                              hipStream_t stream) {
    const float* features = (const float*)d_in[0];
    const int*   src      = (const int*)d_in[1];
    const int*   dst      = (const int*)d_in[2];
    const float* ew       = (const float*)d_in[3];
    const float* W1       = (const float*)d_in[4];
    const float* b1       = (const float*)d_in[5];
    const float* W2       = (const float*)d_in[6];
    const float* b2       = (const float*)d_in[7];
    const float* W3       = (const float*)d_in[8];
    const float* b3       = (const float*)d_in[9];
    float* out = (float*)d_out;

    const int N = in_sizes[0] / F_IN;   // 50000
    const int E = in_sizes[1];          // 800000
    const int NR = (N + RSIZE - 1) >> RBITS;   // 7 node ranges

    // ---- workspace carve-up ----
    char* ws = (char*)d_ws;
    size_t off = 0;
    auto alloc = [&](size_t bytes) -> void* {
        void* p = ws + off;
        off += (bytes + 255) & ~(size_t)255;
        return p;
    };
    int*   row_ptr  = (int*)alloc((size_t)(N + 1) * 4);
    float* out_norm = (float*)alloc((size_t)N * 4);
    float* in_norm  = (float*)alloc((size_t)N * 4);
    int2*  edges    = (int2*)alloc((size_t)E * 8);
    float* B0       = (float*)alloc((size_t)N * HDIM * 4);  // T1, later H2
    float* B1       = (float*)alloc((size_t)N * HDIM * 4);  // H1, later padded T3
    float* B2       = (float*)alloc((size_t)N * HDIM * 4);  // A2
    const int nb    = (N + 1023) / 1024;
    int*   bsums    = (int*)alloc((size_t)nb * 4);
    // preprocessing scratch ALIASES the layer buffers (dead before layers):
    int*   pc       = (int*)B0;   // NR*NSUB*RSIZE*4 = 14.7MB < 25.6MB
    int*   cb       = (int*)B1;   // NSUB*N*4       = 12.8MB < 25.6MB
    (void)ws_size;

    // ---- preprocessing (no global atomics) ----
    {
        dim3 grid(NSUB, NR);
        histo_range<<<grid, 256, 0, stream>>>(src, dst, pc, E);
    }
    scan_blocks<<<nb, 256, 0, stream>>>(pc, row_ptr, bsums, N);
    scan_sums<<<1, 64, 0, stream>>>(bsums, nb);
    int ngrid = (N + 255) / 256;
    node_prep_kernel<<<ngrid, 256, 0, stream>>>(pc, row_ptr, bsums,
                                                out_norm, in_norm, cb, N, E);
    {
        dim3 grid(NSUB, NR);
        scatter_range<<<grid, 256, 0, stream>>>(src, dst, ew, out_norm, cb,
                                                edges, E, N);
    }

    const int spmm_grid = (N + 3) / 4;   // one wave per node, 4 waves/block

    // ---- layer 1: T1 = X @ W1 ; H1 = relu(SpMM(T1)*in_norm + b1) ----
    {
        dim3 grid((N + 127) / 128);
        gemm128_f32<0><<<grid, 256, 0, stream>>>(features, W1, B0, N, F_IN,
                                                 nullptr, nullptr);
    }
    spmm128<1><<<spmm_grid, 256, 0, stream>>>(B0, row_ptr, edges, B1, in_norm, b1, N);

    // ---- layer 2: A2 = SpMM(H1) ; H2 = relu((A2 @ W2)*in_norm + b2) ----
    spmm128<0><<<spmm_grid, 256, 0, stream>>>(B1, row_ptr, edges, B2, nullptr, nullptr, N);
    {
        dim3 grid((N + 127) / 128);
        gemm128_f32<1><<<grid, 256, 0, stream>>>(B2, W2, B0, N, HDIM, in_norm, b2);
    }

    // ---- layer 3: T3 = H2 @ W3 (ldc=64 padded) ; OUT = SpMM(T3)*in_norm+b3 -
    {
        dim3 grid((N + 127) / 128, 1);
        gemm_f32<0><<<grid, 256, 0, stream>>>(B0, W3, B1, N, CDIM, HDIM,
                                              HDIM, CDIM, 64, nullptr, nullptr);
    }
    spmm40<<<spmm_grid, 256, 0, stream>>>(B1, row_ptr, edges, out, in_norm, b3, N);
}